// Round 17
// 726.342 us; speedup vs baseline: 3.6178x; 1.0311x over previous
//
#include <hip/hip_runtime.h>
#include <math.h>

#define NN      8000
#define PP      32
#define EG      128000
#define ES_TOT  131072     // P * 4096
#define ES_P    4096
#define PN      256000     // P * NN
#define DI      16
#define DD      128
#define KK1     6400
#define KK2     5120
#define KK3     4096
#define RB      64
#define BPG     (NN / RB)

typedef __attribute__((ext_vector_type(8))) short short8;
typedef __attribute__((ext_vector_type(4))) float f32x4;

static __device__ __forceinline__ unsigned fkey(float f) {
    unsigned u = __float_as_uint(f);
    return (u & 0x80000000u) ? ~u : (u | 0x80000000u);
}
static __device__ __forceinline__ float fkey_inv(unsigned k) {
    unsigned u = (k & 0x80000000u) ? (k & 0x7FFFFFFFu) : ~k;
    return __uint_as_float(u);
}
static __device__ __forceinline__ unsigned short f2bf(float f) {
    unsigned u = __float_as_uint(f);
    u += 0x7FFFu + ((u >> 16) & 1u);   // RNE
    return (unsigned short)(u >> 16);
}
static __device__ __forceinline__ float bf2f(unsigned short b) {
    return __uint_as_float((unsigned)b << 16);
}

// ---------------- CSR build ----------------
__global__ void k_hist(const int* __restrict__ dst, int* __restrict__ cnt, int ne) {
    int e = blockIdx.x * 256 + threadIdx.x;
    if (e < ne) atomicAdd(&cnt[dst[e]], 1);
}

__global__ __launch_bounds__(1024) void k_scanA(const int* __restrict__ cnt,
                                                int* __restrict__ part,
                                                int* __restrict__ bsum, int n) {
    __shared__ int sh[1024];
    int t = threadIdx.x;
    int i = blockIdx.x * 1024 + t;
    int v = (i < n) ? cnt[i] : 0;
    sh[t] = v; __syncthreads();
    for (int off = 1; off < 1024; off <<= 1) {
        int u = (t >= off) ? sh[t - off] : 0;
        __syncthreads();
        sh[t] += u;
        __syncthreads();
    }
    if (i < n) part[i] = sh[t] - v;
    if (t == 1023) bsum[blockIdx.x] = sh[1023];
}

__global__ __launch_bounds__(1024) void k_scanB(int* __restrict__ bsum, int nb) {
    __shared__ int sh[1024];
    int t = threadIdx.x;
    int v = (t < nb) ? bsum[t] : 0;
    sh[t] = v; __syncthreads();
    for (int off = 1; off < 1024; off <<= 1) {
        int u = (t >= off) ? sh[t - off] : 0;
        __syncthreads();
        sh[t] += u;
        __syncthreads();
    }
    if (t < nb) bsum[t] = sh[t] - v;
}

__global__ void k_scanC(const int* __restrict__ part, const int* __restrict__ bsum,
                        int* __restrict__ rowptr, int* __restrict__ cursor, int n, int total) {
    int i = blockIdx.x * 256 + threadIdx.x;
    if (i < n) {
        int v = part[i] + bsum[i >> 10];
        rowptr[i] = v;
        cursor[i] = v;
    }
    if (i == 0) rowptr[n] = total;
}

__global__ void k_scatter(const int* __restrict__ src, const int* __restrict__ dst,
                          int* __restrict__ cursor, int* __restrict__ col, int ne) {
    int e = blockIdx.x * 256 + threadIdx.x;
    if (e >= ne) return;
    int pos = atomicAdd(&cursor[dst[e]], 1);
    col[pos] = src[e];
}

// ---------------- stage-1 layer a ----------------
__global__ __launch_bounds__(256) void k_agg16(const float* __restrict__ h,
                                               const int* __restrict__ rowptr,
                                               const int* __restrict__ col,
                                               float* __restrict__ agg, float* __restrict__ deg,
                                               int nrows) {
    int i = blockIdx.x * 256 + threadIdx.x;
    int r = i >> 4, j = i & 15;
    if (r >= nrows) return;
    int b = rowptr[r], e = rowptr[r + 1];
    float a = h[r * 16 + j];
    for (int q = b; q < e; ++q) a += h[col[q] * 16 + j];
    agg[r * 16 + j] = a;
    if (j == 0) deg[r] = 1.0f + (float)(e - b);
}

__global__ __launch_bounds__(256) void k_sage16(
    const float* __restrict__ h, const float* __restrict__ agg, const float* __restrict__ deg,
    const float* __restrict__ Wl, const float* __restrict__ Wr, const float* __restrict__ bl,
    float* __restrict__ y, int nrows)
{
    __shared__ float WlS[16][128], WrS[16][128];
    int tid = threadIdx.x;
    for (int i = tid; i < 16 * 128; i += 256) {
        WlS[i >> 7][i & 127] = Wl[i];
        WrS[i >> 7][i & 127] = Wr[i];
    }
    __syncthreads();
    long long o = (long long)blockIdx.x * 256 + tid;
    int row = (int)(o >> 7);
    if (row >= nrows) return;
    int d = (int)o & 127;
    float invd = 1.0f / fmaxf(deg[row], 1.0f);
    float s = bl[d];
    #pragma unroll
    for (int k = 0; k < 16; ++k)
        s += agg[row * 16 + k] * invd * WlS[k][d] + h[row * 16 + k] * WrS[k][d];
    y[(long long)row * 128 + d] = tanhf(s);
}

// ---------------- stage-1 CSR gather-aggregate (fp32 out) ----------------
__global__ __launch_bounds__(256) void k_aggf0(
    const float* __restrict__ x,
    const int* __restrict__ rowptr, const int* __restrict__ col,
    float* __restrict__ AGG, int nrowsC)
{
    int tid = threadIdx.x;
    int r = blockIdx.x * 8 + (tid >> 5);
    if (r >= nrowsC) return;
    int lane = tid & 31;
    int b = rowptr[r], e = rowptr[r + 1];
    float4 a = *reinterpret_cast<const float4*>(x + (long long)r * 128 + lane * 4);
    float dsum = 1.0f + (float)(e - b);
    for (int q = b; q < e; ++q) {
        int s = col[q];
        float4 v = *reinterpret_cast<const float4*>(x + (long long)s * 128 + lane * 4);
        a.x += v.x; a.y += v.y; a.z += v.z; a.w += v.w;
    }
    float invds = 1.0f / fmaxf(dsum, 1.0f);
    a.x *= invds; a.y *= invds; a.z *= invds; a.w *= invds;
    *reinterpret_cast<float4*>(AGG + (long long)r * 128 + lane * 4) = a;
}

// ---------------- stage-2 CSR gather-aggregate (bf16 in/out, alive-compacted) ----------------
__global__ __launch_bounds__(256) void k_aggf2(
    const unsigned short* __restrict__ x,
    const int* __restrict__ rowptr, const int* __restrict__ col,
    const int* __restrict__ aliveIdx, const float* __restrict__ nal, const float* __restrict__ fvec,
    int rowbase,
    unsigned short* __restrict__ AGGb, int nrowsC)
{
    int tid = threadIdx.x;
    int r = blockIdx.x * 8 + (tid >> 5);
    if (r >= nrowsC) return;
    int lane = tid & 31;
    int orig = aliveIdx[r];
    int grow = rowbase + orig;
    int b = rowptr[grow], e = rowptr[grow + 1];
    float4 a = make_float4(0.0f, 0.0f, 0.0f, 0.0f);
    float dsum = 0.0f;
    for (int q = b; q < e; ++q) {
        int fr = col[q] - rowbase;
        if (nal[fr] == 0.0f) continue;
        dsum += 1.0f;
        float fw = fvec[fr];
        if (fw == 0.0f) continue;
        ushort4 v = *reinterpret_cast<const ushort4*>(x + (long long)fr * 128 + lane * 4);
        a.x += bf2f(v.x) * fw; a.y += bf2f(v.y) * fw;
        a.z += bf2f(v.z) * fw; a.w += bf2f(v.w) * fw;
    }
    float invds = 1.0f / fmaxf(dsum, 1.0f);
    ushort4 o;
    o.x = f2bf(a.x * invds); o.y = f2bf(a.y * invds);
    o.z = f2bf(a.z * invds); o.w = f2bf(a.w * invds);
    *reinterpret_cast<ushort4*>(AGGb + (long long)r * 128 + lane * 4) = o;
}

// ---------------- dense SAGE GEMM (fp32 v2 tile) — stage-1 only ----------------
__global__ __launch_bounds__(256) void k_sage_d(
    const float* __restrict__ AGG, const float* __restrict__ xsrc,
    const float* __restrict__ Wl, const float* __restrict__ Wr, const float* __restrict__ bl,
    float* __restrict__ y, int nrowsC,
    const float* __restrict__ gw, float* __restrict__ gdot)
{
    __shared__ float Ws[32 * 128];
    __shared__ float Is[32][68];
    __shared__ float gwS[128];
    int tid = threadIdx.x;
    long long row0 = (long long)blockIdx.x * 64;
    if (tid < 128 && gw) gwS[tid] = gw[tid];
    __syncthreads();
    int tx = tid & 31, ty = tid >> 5;
    float gg4[4] = {0,0,0,0};
    if (gw) { gg4[0]=gwS[tx*4]; gg4[1]=gwS[tx*4+1]; gg4[2]=gwS[tx*4+2]; gg4[3]=gwS[tx*4+3]; }
    int srow = tid & 63;
    int koff = (tid >> 6) * 8;
    long long crow = row0 + srow;
    if (crow >= nrowsC) crow = nrowsC - 1;
    const float* selfp = xsrc + crow * 128;
    const float* aggp = AGG + crow * 128;

    float acc[8][4] = {};
    for (int kb = 0; kb < 8; ++kb) {
        __syncthreads();
        bool isAgg = (kb < 4);
        const float* Wsrc = isAgg ? (Wl + kb * 32 * 128) : (Wr + (kb - 4) * 32 * 128);
        #pragma unroll
        for (int j = 0; j < 4; ++j) {
            int fl = j * 1024 + tid * 4;
            *reinterpret_cast<float4*>(&Ws[fl]) = *reinterpret_cast<const float4*>(&Wsrc[fl]);
        }
        {
            const float* sp = (isAgg ? (aggp + kb * 32) : (selfp + (kb - 4) * 32)) + koff;
            float4 v0 = *reinterpret_cast<const float4*>(sp);
            float4 v1 = *reinterpret_cast<const float4*>(sp + 4);
            Is[koff + 0][srow] = v0.x; Is[koff + 1][srow] = v0.y;
            Is[koff + 2][srow] = v0.z; Is[koff + 3][srow] = v0.w;
            Is[koff + 4][srow] = v1.x; Is[koff + 5][srow] = v1.y;
            Is[koff + 6][srow] = v1.z; Is[koff + 7][srow] = v1.w;
        }
        __syncthreads();
        #pragma unroll
        for (int kk = 0; kk < 32; ++kk) {
            float4 wv = *reinterpret_cast<const float4*>(&Ws[kk * 128 + tx * 4]);
            float4 i0 = *reinterpret_cast<const float4*>(&Is[kk][ty * 8]);
            float4 i1 = *reinterpret_cast<const float4*>(&Is[kk][ty * 8 + 4]);
            float ia[8] = {i0.x, i0.y, i0.z, i0.w, i1.x, i1.y, i1.z, i1.w};
            float wa[4] = {wv.x, wv.y, wv.z, wv.w};
            #pragma unroll
            for (int i = 0; i < 8; ++i)
                #pragma unroll
                for (int j = 0; j < 4; ++j)
                    acc[i][j] += ia[i] * wa[j];
        }
    }
    float4 bl0 = *reinterpret_cast<const float4*>(&bl[tx * 4]);
    float br[4] = {bl0.x, bl0.y, bl0.z, bl0.w};
    #pragma unroll
    for (int i = 0; i < 8; ++i) {
        long long row = row0 + ty * 8 + i;
        bool valid = (row < nrowsC);
        float yv[4];
        #pragma unroll
        for (int j = 0; j < 4; ++j) yv[j] = tanhf(acc[i][j] + br[j]);
        if (valid)
            *reinterpret_cast<float4*>(&y[row * 128 + tx * 4]) = make_float4(yv[0], yv[1], yv[2], yv[3]);
        float gp = 0.0f;
        #pragma unroll
        for (int j = 0; j < 4; ++j) if (gdot) gp += yv[j] * gg4[j];
        #pragma unroll
        for (int m = 16; m >= 1; m >>= 1) if (gdot) gp += __shfl_xor(gp, m, 32);
        if (tx == 0 && valid && gdot) gdot[row] = gp;
    }
}

// ---------------- bf16 weight pack ----------------
__global__ void k_packW(const float* __restrict__ Wl, const float* __restrict__ Wr,
                        short* __restrict__ Wb) {
    int i = blockIdx.x * 256 + threadIdx.x;
    if (i >= 32768) return;
    int kt = i >> 12, rem = i & 4095;
    int ct = rem >> 9; rem &= 511;
    int lane = rem >> 3, e = rem & 7;
    int k = kt * 32 + (lane >> 4) * 8 + e;
    int c = ct * 16 + (lane & 15);
    float v = (k < 128) ? Wl[k * 128 + c] : Wr[(k - 128) * 128 + c];
    Wb[i] = (short)f2bf(v);
}

// ---------------- MFMA SAGE GEMM (stage-2 L1/L2): all-bf16 inputs, fp32 accum ----------------
// y (bf16) at orig rows; X is bf16.
__global__ __launch_bounds__(256) void k_sage_m(
    const unsigned short* __restrict__ AGGb, const unsigned short* __restrict__ X,
    const int* __restrict__ aliveIdx, const float* __restrict__ fvec,
    const short* __restrict__ Wb, const float* __restrict__ bl,
    unsigned short* __restrict__ y, int nrowsC,
    const float* __restrict__ wrel, const float* __restrict__ wroot, const float* __restrict__ gw,
    float* __restrict__ tbuf, float* __restrict__ rootd, float* __restrict__ gdot)
{
    __shared__ short8 lB[2048];
    int tid = threadIdx.x;
    int lane = tid & 63;
    int wv = tid >> 6;
    long long rows0 = (long long)blockIdx.x * 128 + wv * 32;
    int arow = lane & 15;
    int ksl = (lane >> 4) * 8;

    int growA[2], origA[2];
    float fsA[2];
    #pragma unroll
    for (int rt = 0; rt < 2; ++rt) {
        growA[rt] = (int)(rows0 + rt * 16 + arow);
        origA[rt] = aliveIdx[growA[rt]];
        fsA[rt] = fvec[origA[rt]];
    }

    f32x4 acc[2][8] = {};
    const short8* Wbv = (const short8*)Wb;

    for (int half = 0; half < 2; ++half) {
        __syncthreads();
        #pragma unroll
        for (int i = 0; i < 8; ++i) {
            int idx = i * 256 + tid;
            lB[idx] = Wbv[half * 2048 + idx];
        }
        __syncthreads();
        #pragma unroll
        for (int ktl = 0; ktl < 4; ++ktl) {
            int kt = half * 4 + ktl;
            short8 bfr[8];
            #pragma unroll
            for (int ct = 0; ct < 8; ++ct)
                bfr[ct] = lB[(ktl * 8 + ct) * 64 + lane];
            #pragma unroll
            for (int rt = 0; rt < 2; ++rt) {
                short8 afr;
                if (kt < 4) {
                    afr = *reinterpret_cast<const short8*>(AGGb + (long long)growA[rt] * 128 + kt * 32 + ksl);
                } else {
                    short8 xv = *reinterpret_cast<const short8*>(X + (long long)origA[rt] * 128 + (kt - 4) * 32 + ksl);
                    float m = fsA[rt];
                    #pragma unroll
                    for (int e = 0; e < 8; ++e)
                        afr[e] = (short)f2bf(bf2f((unsigned short)xv[e]) * m);
                }
                #pragma unroll
                for (int ct = 0; ct < 8; ++ct)
                    acc[rt][ct] = __builtin_amdgcn_mfma_f32_16x16x32_bf16(afr, bfr[ct], acc[rt][ct], 0, 0, 0);
            }
        }
    }

    int ocol = lane & 15;
    float blv[8], wrv[8], wov[8], ggv[8];
    #pragma unroll
    for (int ct = 0; ct < 8; ++ct) {
        int c = ct * 16 + ocol;
        blv[ct] = bl[c];
        wrv[ct] = wrel[c];
        wov[ct] = wroot[c];
        ggv[ct] = gw[c];
    }
    #pragma unroll
    for (int rt = 0; rt < 2; ++rt) {
        #pragma unroll
        for (int j = 0; j < 4; ++j) {
            int rloc = (lane >> 4) * 4 + j;
            long long grow = rows0 + rt * 16 + rloc;
            int orig = aliveIdx[grow];
            float tp = 0.0f, rp = 0.0f, gp = 0.0f;
            #pragma unroll
            for (int ct = 0; ct < 8; ++ct) {
                float v = tanhf(acc[rt][ct][j] + blv[ct]);
                y[(long long)orig * 128 + ct * 16 + ocol] = f2bf(v);
                tp += v * wrv[ct]; rp += v * wov[ct]; gp += v * ggv[ct];
            }
            #pragma unroll
            for (int mm = 8; mm >= 1; mm >>= 1) {
                tp += __shfl_xor(tp, mm, 16);
                rp += __shfl_xor(rp, mm, 16);
                gp += __shfl_xor(gp, mm, 16);
            }
            if (ocol == 0) { tbuf[orig] = tp; rootd[orig] = rp; gdot[orig] = gp; }
        }
    }
}

// ---------------- plain GEMM: y = x@W (+ b), v2 tile ----------------
__global__ __launch_bounds__(256) void k_gemm_self(
    const float* __restrict__ x, const float* __restrict__ W, const float* __restrict__ b,
    float* __restrict__ y, int nrows)
{
    __shared__ float Ws[32 * 128];
    __shared__ float Is[32][68];
    int tid = threadIdx.x;
    long long row0 = (long long)blockIdx.x * 64;
    int tx = tid & 31, ty = tid >> 5;
    int srow = tid & 63;
    int koff = (tid >> 6) * 8;
    long long lrow = row0 + srow;
    if (lrow >= nrows) lrow = nrows - 1;
    const float* xrow = x + lrow * 128;
    float acc[8][4] = {};
    for (int kb = 0; kb < 4; ++kb) {
        __syncthreads();
        const float* Wsrc = W + kb * 32 * 128;
        #pragma unroll
        for (int j = 0; j < 4; ++j) {
            int fl = j * 1024 + tid * 4;
            *reinterpret_cast<float4*>(&Ws[fl]) = *reinterpret_cast<const float4*>(&Wsrc[fl]);
        }
        {
            const float* sp = xrow + kb * 32 + koff;
            float4 v0 = *reinterpret_cast<const float4*>(sp);
            float4 v1 = *reinterpret_cast<const float4*>(sp + 4);
            Is[koff + 0][srow] = v0.x; Is[koff + 1][srow] = v0.y;
            Is[koff + 2][srow] = v0.z; Is[koff + 3][srow] = v0.w;
            Is[koff + 4][srow] = v1.x; Is[koff + 5][srow] = v1.y;
            Is[koff + 6][srow] = v1.z; Is[koff + 7][srow] = v1.w;
        }
        __syncthreads();
        #pragma unroll
        for (int kk = 0; kk < 32; ++kk) {
            float4 wv = *reinterpret_cast<const float4*>(&Ws[kk * 128 + tx * 4]);
            float4 i0 = *reinterpret_cast<const float4*>(&Is[kk][ty * 8]);
            float4 i1 = *reinterpret_cast<const float4*>(&Is[kk][ty * 8 + 4]);
            float ia[8] = {i0.x, i0.y, i0.z, i0.w, i1.x, i1.y, i1.z, i1.w};
            float wa[4] = {wv.x, wv.y, wv.z, wv.w};
            #pragma unroll
            for (int i = 0; i < 8; ++i)
                #pragma unroll
                for (int j = 0; j < 4; ++j)
                    acc[i][j] += ia[i] * wa[j];
        }
    }
    float4 b0 = b ? *reinterpret_cast<const float4*>(&b[tx * 4]) : make_float4(0.f, 0.f, 0.f, 0.f);
    #pragma unroll
    for (int i = 0; i < 8; ++i) {
        long long row = row0 + ty * 8 + i;
        if (row >= nrows) continue;
        *reinterpret_cast<float4*>(&y[row * 128 + tx * 4]) =
            make_float4(acc[i][0] + b0.x, acc[i][1] + b0.y, acc[i][2] + b0.z, acc[i][3] + b0.w);
    }
}

// ---------------- stage-2 L0 combine (bf16 X out) ----------------
__global__ __launch_bounds__(256) void k_l0comb(
    const float* __restrict__ ZL0, const float* __restrict__ zself,
    const int* __restrict__ rowptr, const int* __restrict__ col, int rowbase,
    const float* __restrict__ wrel, const float* __restrict__ wroot, const float* __restrict__ gw,
    unsigned short* __restrict__ y, float* __restrict__ tbuf, float* __restrict__ rootd, float* __restrict__ gdot,
    int nrowsC)
{
    __shared__ float wrelS[128], wrootS[128], gwS[128];
    int tid = threadIdx.x;
    if (tid < 128) {
        wrelS[tid]  = wrel[tid];
        wrootS[tid] = wroot[tid];
        gwS[tid]    = gw[tid];
    }
    __syncthreads();
    int r = blockIdx.x * 8 + (tid >> 5);
    if (r >= nrowsC) return;
    int lane = tid & 31;
    int grow = rowbase + r;
    int b = rowptr[grow], e = rowptr[grow + 1];
    float4 a = make_float4(0.0f, 0.0f, 0.0f, 0.0f);
    for (int q = b; q < e; ++q) {
        int fr = col[q] % NN;
        float4 v = *reinterpret_cast<const float4*>(ZL0 + (long long)fr * 128 + lane * 4);
        a.x += v.x; a.y += v.y; a.z += v.z; a.w += v.w;
    }
    float invds = 1.0f / fmaxf((float)(e - b), 1.0f);
    const float4 z = *reinterpret_cast<const float4*>(zself + (long long)(r % NN) * 128 + lane * 4);
    float yv[4];
    yv[0] = tanhf(a.x * invds + z.x);
    yv[1] = tanhf(a.y * invds + z.y);
    yv[2] = tanhf(a.z * invds + z.z);
    yv[3] = tanhf(a.w * invds + z.w);
    ushort4 o;
    o.x = f2bf(yv[0]); o.y = f2bf(yv[1]); o.z = f2bf(yv[2]); o.w = f2bf(yv[3]);
    *reinterpret_cast<ushort4*>(y + (long long)r * 128 + lane * 4) = o;
    float tp = 0.0f, rp = 0.0f, gp = 0.0f;
    #pragma unroll
    for (int j = 0; j < 4; ++j) {
        tp += yv[j] * wrelS[lane*4 + j];
        rp += yv[j] * wrootS[lane*4 + j];
        gp += yv[j] * gwS[lane*4 + j];
    }
    #pragma unroll
    for (int m = 16; m >= 1; m >>= 1) {
        tp += __shfl_xor(tp, m, 32);
        rp += __shfl_xor(rp, m, 32);
        gp += __shfl_xor(gp, m, 32);
    }
    if (lane == 0) {
        tbuf[r]  = tp;
        rootd[r] = rp;
        gdot[r]  = gp;
    }
}

// ---------------- stage-1 readout pieces ----------------
__global__ __launch_bounds__(256) void k_gate(
    const float* __restrict__ X, const float* __restrict__ gw,
    float* __restrict__ g, int nrows)
{
    __shared__ float wS[128];
    if (threadIdx.x < 128) wS[threadIdx.x] = gw[threadIdx.x];
    __syncthreads();
    int i = blockIdx.x * 256 + threadIdx.x;
    if (i >= nrows) return;
    const float4* xrp = reinterpret_cast<const float4*>(X + (long long)i * 128);
    float s = 0.0f;
    #pragma unroll
    for (int k = 0; k < 32; ++k) {
        float4 v = xrp[k];
        s += v.x * wS[4*k] + v.y * wS[4*k+1] + v.z * wS[4*k+2] + v.w * wS[4*k+3];
    }
    g[i] = s;
}

__global__ __launch_bounds__(1024) void k_smstats(float* __restrict__ g, float* __restrict__ invp) {
    __shared__ float red[1024];
    int p = blockIdx.x, tid = threadIdx.x;
    float* gp = g + (long long)p * NN;
    float lmax = -INFINITY;
    for (int n = tid; n < NN; n += 1024) lmax = fmaxf(lmax, gp[n]);
    red[tid] = lmax; __syncthreads();
    for (int s = 512; s > 0; s >>= 1) { if (tid < s) red[tid] = fmaxf(red[tid], red[tid + s]); __syncthreads(); }
    float mx = red[0]; __syncthreads();
    float ls = 0.0f;
    for (int n = tid; n < NN; n += 1024) { float e = expf(gp[n] - mx); gp[n] = e; ls += e; }
    red[tid] = ls; __syncthreads();
    for (int s = 512; s > 0; s >>= 1) { if (tid < s) red[tid] += red[tid + s]; __syncthreads(); }
    if (tid == 0) invp[p] = 1.0f / red[0];
}

__global__ __launch_bounds__(128) void k_wsum(
    const float* __restrict__ X, const float* __restrict__ a,
    const float* __restrict__ invp, float* __restrict__ ro, int rowbase, int colOff)
{
    int p = blockIdx.x / BPG;
    int chunk = blockIdx.x % BPG;
    int d = threadIdx.x;
    long long base = (long long)p * NN;
    int r0 = chunk * RB, r1 = r0 + RB;
    float s = 0.0f;
    for (int n = r0; n < r1; ++n) {
        float w = a[base + n];
        if (w != 0.0f) s += w * X[(base + n) * 128 + d];
    }
    atomicAdd(&ro[(long long)(rowbase + p) * 384 + colOff + d], s * invp[p]);
}

// stage-2 weighted sum over alive rows only (bf16 X)
__global__ __launch_bounds__(128) void k_wsum_c(
    const unsigned short* __restrict__ X, const float* __restrict__ gbuf, const float* __restrict__ fvec,
    const float* __restrict__ invp, const int* __restrict__ aliveIdx, int k,
    float* __restrict__ ro, int rowbaseRo, int colOff)
{
    int bpp = k / RB;
    int p = blockIdx.x / bpp;
    int chunk = blockIdx.x % bpp;
    int d = threadIdx.x;
    const int* ai = aliveIdx + (long long)p * k + chunk * RB;
    float s = 0.0f;
    for (int j = 0; j < RB; ++j) {
        int row = ai[j];
        float w = gbuf[row] * fvec[row];
        s += w * bf2f(X[(long long)row * 128 + d]);
    }
    atomicAdd(&ro[(long long)(rowbaseRo + p) * 384 + colOff + d], s * invp[p]);
}

// ---------------- GraphNorm ----------------
__global__ void k_colstat(const float* __restrict__ x, float* __restrict__ musum,
                          float* __restrict__ sqsum, int nrows) {
    int d = threadIdx.x;
    int r0 = blockIdx.x * 64;
    int r1 = min(r0 + 64, nrows);
    float s = 0.0f, q = 0.0f;
    for (int r = r0; r < r1; ++r) { float v = x[(long long)r * 128 + d]; s += v; q += v * v; }
    atomicAdd(&musum[d], s);
    atomicAdd(&sqsum[d], q);
}

__global__ void k_gnorm_apply(const float* __restrict__ x, float* __restrict__ y,
                              const float* __restrict__ musum, const float* __restrict__ sqsum,
                              const float* __restrict__ w, const float* __restrict__ b,
                              const float* __restrict__ ms, int nrows) {
    long long i = (long long)blockIdx.x * 256 + threadIdx.x;
    if (i >= (long long)nrows * 128) return;
    int d = (int)(i & 127);
    float inv_n = 1.0f / (float)nrows;
    float mu = musum[d] * inv_n;
    float c = mu * ms[d];
    float var = sqsum[d] * inv_n - 2.0f * c * mu + c * c;
    y[i] = w[d] * (x[i] - c) * rsqrtf(var + 1e-5f) + b[d];
}

// ---------------- mega top-k (1024 threads, parallel bucket select) ----------------
#define TCH 8
__global__ __launch_bounds__(1024) void k_topk2(
    const int* __restrict__ rowptr, const int* __restrict__ col, int rowbase,
    const float* __restrict__ tb, const float* __restrict__ rootd,
    const float* __restrict__ gdot, const float* __restrict__ brelp, int bi, int allAlive,
    float* __restrict__ nalive, float* __restrict__ fvec, float* __restrict__ gbuf,
    float* __restrict__ invp, int* __restrict__ aliveIdx, int k)
{
    __shared__ unsigned keys[NN];
    __shared__ int hist[256];
    __shared__ int scan[1024];
    __shared__ float redf[1024];
    __shared__ unsigned sh_pref;
    __shared__ int sh_kneed;
    int p = blockIdx.x, tid = threadIdx.x;
    float brel = brelp[bi];
    long long pbase = (long long)p * NN;
    for (int n = tid; n < NN; n += 1024) {
        long long gl = pbase + n;
        int grow = rowbase + (int)gl;
        float s = brel + rootd[gl];
        int b = rowptr[grow], e = rowptr[grow + 1];
        for (int q = b; q < e; ++q) {
            int sl = col[q] - rowbase;
            s += allAlive ? tb[sl] : (tb[sl] * nalive[sl]);
        }
        bool alive = allAlive || (nalive[gl] > 0.5f);
        keys[n] = alive ? fkey(s) : 0u;
    }
    if (tid == 0) { sh_pref = 0u; sh_kneed = k; }
    __syncthreads();
    for (int lvl = 3; lvl >= 0; --lvl) {
        int sh = lvl * 8;
        if (tid < 256) hist[tid] = 0;
        unsigned pref = sh_pref; int kneed = sh_kneed;
        unsigned pmask = (lvl == 3) ? 0u : (0xFFFFFFFFu << (8 * (lvl + 1)));
        __syncthreads();
        for (int n = tid; n < NN; n += 1024) {
            unsigned kv = keys[n];
            if ((kv & pmask) == pref) atomicAdd(&hist[(kv >> sh) & 255], 1);
        }
        __syncthreads();
        if (tid < 256) scan[tid] = hist[tid];
        __syncthreads();
        for (int off = 1; off < 256; off <<= 1) {
            int v = 0;
            if (tid < 256 && tid + off < 256) v = scan[tid + off];
            __syncthreads();
            if (tid < 256) scan[tid] += v;
            __syncthreads();
        }
        if (tid < 256) {
            int c = scan[tid];
            int cex = c - hist[tid];
            if (c >= kneed && cex < kneed) {
                sh_pref = pref | ((unsigned)tid << sh);
                sh_kneed = kneed - cex;
            }
        }
        __syncthreads();
    }
    unsigned V = sh_pref;
    int seleq = sh_kneed;
    int c0 = tid * TCH, c1 = min(c0 + TCH, NN);
    int ceq = 0;
    for (int n = c0; n < c1; ++n) ceq += (keys[n] == V) ? 1 : 0;
    scan[tid] = ceq; __syncthreads();
    for (int off = 1; off < 1024; off <<= 1) {
        int u = (tid >= off) ? scan[tid - off] : 0;
        __syncthreads();
        scan[tid] += u;
        __syncthreads();
    }
    int rank = scan[tid] - ceq;
    unsigned selmask = 0u;
    int nsel = 0;
    float lmax = -INFINITY;
    for (int n = c0; n < c1; ++n) {
        unsigned kk = keys[n];
        bool sel = (kk > V) || (kk == V && rank < seleq);
        if (kk == V) rank++;
        long long gl = pbase + n;
        nalive[gl] = sel ? 1.0f : 0.0f;
        float f = 0.0f;
        if (sel) {
            f = tanhf(fkey_inv(kk));
            lmax = fmaxf(lmax, f * gdot[gl]);
            selmask |= (1u << (n - c0));
            ++nsel;
        }
        fvec[gl] = f;
    }
    redf[tid] = lmax; __syncthreads();
    for (int s = 512; s > 0; s >>= 1) { if (tid < s) redf[tid] = fmaxf(redf[tid], redf[tid + s]); __syncthreads(); }
    float mx = redf[0]; __syncthreads();
    scan[tid] = nsel; __syncthreads();
    for (int off = 1; off < 1024; off <<= 1) {
        int u = (tid >= off) ? scan[tid - off] : 0;
        __syncthreads();
        scan[tid] += u;
        __syncthreads();
    }
    int pos = scan[tid] - nsel;
    float lsum = 0.0f;
    for (int n = c0; n < c1; ++n) {
        if (selmask & (1u << (n - c0))) {
            long long gl = pbase + n;
            float e = expf(fvec[gl] * gdot[gl] - mx);
            gbuf[gl] = e;
            lsum += e;
            aliveIdx[(long long)p * k + pos] = (int)gl;
            ++pos;
        }
    }
    redf[tid] = lsum; __syncthreads();
    for (int s = 512; s > 0; s >>= 1) { if (tid < s) redf[tid] += redf[tid + s]; __syncthreads(); }
    if (tid == 0) invp[p] = 1.0f / redf[0];
}

// ---------------- head ----------------
__global__ __launch_bounds__(64) void k_head(
    const float* __restrict__ ro, const float* __restrict__ lin_w, const float* __restrict__ lin_b,
    const float* __restrict__ m1w, const float* __restrict__ m1b,
    const float* __restrict__ m2w, const float* __restrict__ m2b,
    const float* __restrict__ m3w, const float* __restrict__ m3b, float* __restrict__ out)
{
    __shared__ float v[33], h1[48], h2[16];
    int t = threadIdx.x;
    if (t < 33) {
        float s = lin_b[0];
        for (int k = 0; k < 384; ++k) s += ro[t * 384 + k] * lin_w[k];
        v[t] = tanhf(s);
    }
    __syncthreads();
    if (t < 48) {
        float s = m1b[t];
        for (int i = 0; i < 33; ++i) s += v[i] * m1w[i * 48 + t];
        h1[t] = tanhf(s);
    }
    __syncthreads();
    if (t < 16) {
        float s = m2b[t];
        for (int i = 0; i < 48; ++i) s += h1[i] * m2w[i * 16 + t];
        h2[t] = tanhf(s);
    }
    __syncthreads();
    if (t == 0) {
        float s = m3b[0];
        for (int i = 0; i < 16; ++i) s += h2[i] * m3w[i];
        float s1 = 1.0f / (1.0f + expf(-s));
        out[0] = 1.0f / (1.0f + expf(-s1));
    }
}

static inline int cdiv(long long a, long long b) { return (int)((a + b - 1) / b); }

extern "C" void kernel_launch(void* const* d_in, const int* in_sizes, int n_in,
                              void* d_out, int out_size, void* d_ws, size_t ws_size,
                              hipStream_t stream)
{
    (void)in_sizes; (void)n_in; (void)out_size;
    const float* h     = (const float*)d_in[0];
    const int*   eidx  = (const int*)d_in[1];
    const int*   seidx = (const int*)d_in[2];
    const float* Wl_a  = (const float*)d_in[3];
    const float* Wr_a  = (const float*)d_in[4];
    const float* bl_a  = (const float*)d_in[5];
    const float* Wl_s  = (const float*)d_in[6];
    const float* Wr_s  = (const float*)d_in[7];
    const float* bl_s  = (const float*)d_in[8];
    const float* gate_w = (const float*)d_in[9];
    const float* p_wrel = (const float*)d_in[11];
    const float* p_brel = (const float*)d_in[12];
    const float* p_wroot= (const float*)d_in[13];
    const float* nw    = (const float*)d_in[14];
    const float* nb    = (const float*)d_in[15];
    const float* nms   = (const float*)d_in[16];
    const float* lin_w = (const float*)d_in[17];
    const float* lin_b = (const float*)d_in[18];
    const float* m1w   = (const float*)d_in[19];
    const float* m1b   = (const float*)d_in[20];
    const float* m2w   = (const float*)d_in[21];
    const float* m2b   = (const float*)d_in[22];
    const float* m3w   = (const float*)d_in[23];
    const float* m3b   = (const float*)d_in[24];
    float* out = (float*)d_out;

    const int* esrc = eidx;
    const int* edst = eidx + EG;
    const int* ssrc = seidx;
    const int* sdst = seidx + ES_TOT;

    auto need_bytes = [](int chp) -> size_t {
        long long chn = (long long)chp * NN;
        long long f = chn * 64                       // XAb (bf16)
                    + (long long)chp * KK1 * 64      // AGGb (bf16)
                    + 2LL * NN * 128                 // ZL0, zself
                    + 5 * chn
                    + 64 + 33 * 384
                    + (long long)chp * KK1
                    + (PN + 1) + ES_TOT
                    + 2 * 16384
                    + 64 * 24;
        return (size_t)f * 4;
    };
    int chp = 8;
    if (ws_size >= need_bytes(32)) chp = 32;
    else if (ws_size >= need_bytes(16)) chp = 16;
    int nch = PP / chp;
    long long ch_n = (long long)chp * NN;

    float* W = (float*)d_ws;
    size_t off = 0;
    auto alloc = [&](size_t nf) { float* p = W + off; off += (nf + 63) & ~(size_t)63; return p; };
    unsigned short* XAb = (unsigned short*)alloc((size_t)ch_n * 64);   // bf16 X
    unsigned short* AGGb = (unsigned short*)alloc((size_t)chp * KK1 * 64);
    float* ZL0   = alloc((size_t)NN * DD);
    float* zself = alloc((size_t)NN * DD);
    float* tbuf  = alloc(ch_n);
    float* rootd = alloc(ch_n);
    float* nal   = alloc(ch_n);
    float* fvec  = alloc(ch_n);
    float* gdot  = alloc(ch_n);
    float* invp  = alloc(64);
    float* ro    = alloc(33 * 384);
    int* aliveIdx = (int*)alloc((size_t)chp * KK1);
    int* s2rp    = (int*)alloc(PN + 1);
    int* s2col   = (int*)alloc(ES_TOT);
    short* Wb1   = (short*)alloc(16384);
    short* Wb2   = (short*)alloc(16384);
    float* gbuf = tbuf;

    // overlay: stage-1-only + CSR build temps live inside XAb (dead before XAb's first write)
    float* XO = (float*)XAb;
    size_t ooff = 0;
    auto oalloc = [&](size_t nf) { float* p = XO + ooff; ooff += (nf + 63) & ~(size_t)63; return p; };
    float* xa    = oalloc((size_t)NN * DD);
    float* xb    = oalloc((size_t)NN * DD);
    float* AGGs  = oalloc((size_t)NN * DD);
    float* agg1  = oalloc((size_t)NN * 16);
    float* deg1  = oalloc(NN);
    float* musum = oalloc(128);
    float* sqsum = oalloc(128);
    int* s1cnt  = (int*)oalloc(NN);
    int* s1rp   = (int*)oalloc(NN + 1);
    int* s1cur  = (int*)oalloc(NN);
    int* s1col  = (int*)oalloc(EG);
    int* s1part = (int*)oalloc(NN);
    int* s1bsum = (int*)oalloc(1024);
    int* s2cnt  = (int*)oalloc(PN);
    int* s2cur  = (int*)oalloc(PN);
    int* s2part = (int*)oalloc(PN);
    int* s2bsum = (int*)oalloc(1024);

    // ---------- CSR builds ----------
    int nb1 = cdiv(NN, 1024), nb2 = cdiv(PN, 1024);
    hipMemsetAsync(s1cnt, 0, NN * sizeof(int), stream);
    k_hist<<<cdiv(EG,256),256,0,stream>>>(edst, s1cnt, EG);
    k_scanA<<<nb1,1024,0,stream>>>(s1cnt, s1part, s1bsum, NN);
    k_scanB<<<1,1024,0,stream>>>(s1bsum, nb1);
    k_scanC<<<cdiv(NN,256),256,0,stream>>>(s1part, s1bsum, s1rp, s1cur, NN, EG);
    k_scatter<<<cdiv(EG,256),256,0,stream>>>(esrc, edst, s1cur, s1col, EG);

    hipMemsetAsync(s2cnt, 0, (size_t)PN * sizeof(int), stream);
    k_hist<<<cdiv(ES_TOT,256),256,0,stream>>>(sdst, s2cnt, ES_TOT);
    k_scanA<<<nb2,1024,0,stream>>>(s2cnt, s2part, s2bsum, PN);
    k_scanB<<<1,1024,0,stream>>>(s2bsum, nb2);
    k_scanC<<<cdiv(PN,256),256,0,stream>>>(s2part, s2bsum, s2rp, s2cur, PN, ES_TOT);
    k_scatter<<<cdiv(ES_TOT,256),256,0,stream>>>(ssrc, sdst, s2cur, s2col, ES_TOT);

    hipMemsetAsync(ro, 0, 33 * 384 * sizeof(float), stream);

    // bf16 weight packs
    k_packW<<<128,256,0,stream>>>(Wl_s + 3*16384, Wr_s + 3*16384, Wb1);
    k_packW<<<128,256,0,stream>>>(Wl_s + 4*16384, Wr_s + 4*16384, Wb2);

    // ---------- stage 1 ----------
    k_agg16<<<cdiv((long long)NN*16,256),256,0,stream>>>(h, s1rp, s1col, agg1, deg1, NN);
    k_sage16<<<cdiv((long long)NN*DD,256),256,0,stream>>>(h, agg1, deg1, Wl_a, Wr_a, bl_a, xa, NN);
    k_gate<<<cdiv(NN,256),256,0,stream>>>(xa, gate_w + 0*DD, gbuf, NN);
    k_smstats<<<1,1024,0,stream>>>(gbuf, invp);
    k_wsum<<<BPG,128,0,stream>>>(xa, gbuf, invp, ro, 0, 0);

    hipMemsetAsync(musum, 0, 128*sizeof(float), stream);
    hipMemsetAsync(sqsum, 0, 128*sizeof(float), stream);
    k_colstat<<<cdiv(NN,64),128,0,stream>>>(xa, musum, sqsum, NN);
    k_gnorm_apply<<<cdiv((long long)NN*DD,256),256,0,stream>>>(xa, xb, musum, sqsum, nw, nb, nms, NN);

    k_aggf0<<<cdiv(NN,8),256,0,stream>>>(xb, s1rp, s1col, AGGs, NN);
    k_sage_d<<<cdiv(NN,64),256,0,stream>>>(AGGs, xb,
        Wl_s + 0*16384, Wr_s + 0*16384, bl_s + 0*128, xa, NN,
        gate_w + 1*DD, gbuf);
    k_smstats<<<1,1024,0,stream>>>(gbuf, invp);
    k_wsum<<<BPG,128,0,stream>>>(xa, gbuf, invp, ro, 0, 128);

    hipMemsetAsync(musum, 0, 128*sizeof(float), stream);
    hipMemsetAsync(sqsum, 0, 128*sizeof(float), stream);
    k_colstat<<<cdiv(NN,64),128,0,stream>>>(xa, musum, sqsum, NN);
    k_gnorm_apply<<<cdiv((long long)NN*DD,256),256,0,stream>>>(xa, xb, musum, sqsum, nw, nb, nms, NN);

    k_aggf0<<<cdiv(NN,8),256,0,stream>>>(xb, s1rp, s1col, AGGs, NN);
    k_sage_d<<<cdiv(NN,64),256,0,stream>>>(AGGs, xb,
        Wl_s + 1*16384, Wr_s + 1*16384, bl_s + 1*128, xa, NN,
        gate_w + 2*DD, gbuf);
    k_smstats<<<1,1024,0,stream>>>(gbuf, invp);
    k_wsum<<<BPG,128,0,stream>>>(xa, gbuf, invp, ro, 0, 256);

    // ---------- stage 2 ----------
    k_gemm_self<<<cdiv(NN,64),256,0,stream>>>(xa, Wl_s + 2*16384, nullptr, ZL0, NN);
    k_gemm_self<<<cdiv(NN,64),256,0,stream>>>(xa, Wr_s + 2*16384, bl_s + 2*128, zself, NN);

    for (int c = 0; c < nch; ++c) {
        int nbase = (int)(c * ch_n);

        // ---- layer 0: gather-mean of ZL0 + zself ----
        k_l0comb<<<(int)(ch_n/8),256,0,stream>>>(ZL0, zself, s2rp, s2col, nbase,
            p_wrel + 0*DD, p_wroot + 0*DD, gate_w + 3*DD,
            XAb, tbuf, rootd, gdot, (int)ch_n);
        k_topk2<<<chp,1024,0,stream>>>(s2rp, s2col, nbase, tbuf, rootd, gdot, p_brel, 0, 1,
                                       nal, fvec, gbuf, invp, aliveIdx, KK1);
        k_wsum_c<<<chp*(KK1/RB),128,0,stream>>>(XAb, gbuf, fvec, invp, aliveIdx, KK1, ro, 1 + c*chp, 0);

        // ---- layer 1: alive K1 rows (bf16 in-place on XAb) ----
        k_aggf2<<<chp*(KK1/8),256,0,stream>>>(XAb, s2rp, s2col, aliveIdx, nal, fvec, nbase, AGGb, chp*KK1);
        k_sage_m<<<chp*KK1/128,256,0,stream>>>(AGGb, XAb, aliveIdx, fvec, Wb1, bl_s + 3*128, XAb, chp*KK1,
            p_wrel + 1*DD, p_wroot + 1*DD, gate_w + 4*DD, tbuf, rootd, gdot);
        k_topk2<<<chp,1024,0,stream>>>(s2rp, s2col, nbase, tbuf, rootd, gdot, p_brel, 1, 0,
                                       nal, fvec, gbuf, invp, aliveIdx, KK2);
        k_wsum_c<<<chp*(KK2/RB),128,0,stream>>>(XAb, gbuf, fvec, invp, aliveIdx, KK2, ro, 1 + c*chp, 128);

        // ---- layer 2: alive K2 rows (bf16 in-place on XAb) ----
        k_aggf2<<<chp*(KK2/8),256,0,stream>>>(XAb, s2rp, s2col, aliveIdx, nal, fvec, nbase, AGGb, chp*KK2);
        k_sage_m<<<chp*KK2/128,256,0,stream>>>(AGGb, XAb, aliveIdx, fvec, Wb2, bl_s + 4*128, XAb, chp*KK2,
            p_wrel + 2*DD, p_wroot + 2*DD, gate_w + 5*DD, tbuf, rootd, gdot);
        k_topk2<<<chp,1024,0,stream>>>(s2rp, s2col, nbase, tbuf, rootd, gdot, p_brel, 2, 0,
                                       nal, fvec, gbuf, invp, aliveIdx, KK3);
        k_wsum_c<<<chp*(KK3/RB),128,0,stream>>>(XAb, gbuf, fvec, invp, aliveIdx, KK3, ro, 1 + c*chp, 256);
    }

    // ---------- head ----------
    k_head<<<1,64,0,stream>>>(ro, lin_w, lin_b, m1w, m1b, m2w, m2b, m3w, m3b, out);
}

// Round 18
// 710.285 us; speedup vs baseline: 3.6996x; 1.0226x over previous
//
#include <hip/hip_runtime.h>
#include <math.h>

#define NN      8000
#define PP      32
#define EG      128000
#define ES_TOT  131072     // P * 4096
#define ES_P    4096
#define PN      256000     // P * NN
#define DI      16
#define DD      128
#define KK1     6400
#define KK2     5120
#define KK3     4096
#define RB      64
#define BPG     (NN / RB)

typedef __attribute__((ext_vector_type(8))) short short8;
typedef __attribute__((ext_vector_type(4))) float f32x4;

static __device__ __forceinline__ unsigned fkey(float f) {
    unsigned u = __float_as_uint(f);
    return (u & 0x80000000u) ? ~u : (u | 0x80000000u);
}
static __device__ __forceinline__ float fkey_inv(unsigned k) {
    unsigned u = (k & 0x80000000u) ? (k & 0x7FFFFFFFu) : ~k;
    return __uint_as_float(u);
}
static __device__ __forceinline__ unsigned short f2bf(float f) {
    unsigned u = __float_as_uint(f);
    u += 0x7FFFu + ((u >> 16) & 1u);   // RNE
    return (unsigned short)(u >> 16);
}
static __device__ __forceinline__ float bf2f(unsigned short b) {
    return __uint_as_float((unsigned)b << 16);
}

// ---------------- CSR build ----------------
__global__ void k_hist(const int* __restrict__ dst, int* __restrict__ cnt, int ne) {
    int e = blockIdx.x * 256 + threadIdx.x;
    if (e < ne) atomicAdd(&cnt[dst[e]], 1);
}

__global__ __launch_bounds__(1024) void k_scanA(const int* __restrict__ cnt,
                                                int* __restrict__ part,
                                                int* __restrict__ bsum, int n) {
    __shared__ int sh[1024];
    int t = threadIdx.x;
    int i = blockIdx.x * 1024 + t;
    int v = (i < n) ? cnt[i] : 0;
    sh[t] = v; __syncthreads();
    for (int off = 1; off < 1024; off <<= 1) {
        int u = (t >= off) ? sh[t - off] : 0;
        __syncthreads();
        sh[t] += u;
        __syncthreads();
    }
    if (i < n) part[i] = sh[t] - v;
    if (t == 1023) bsum[blockIdx.x] = sh[1023];
}

__global__ __launch_bounds__(1024) void k_scanB(int* __restrict__ bsum, int nb) {
    __shared__ int sh[1024];
    int t = threadIdx.x;
    int v = (t < nb) ? bsum[t] : 0;
    sh[t] = v; __syncthreads();
    for (int off = 1; off < 1024; off <<= 1) {
        int u = (t >= off) ? sh[t - off] : 0;
        __syncthreads();
        sh[t] += u;
        __syncthreads();
    }
    if (t < nb) bsum[t] = sh[t] - v;
}

__global__ void k_scanC(const int* __restrict__ part, const int* __restrict__ bsum,
                        int* __restrict__ rowptr, int* __restrict__ cursor, int n, int total) {
    int i = blockIdx.x * 256 + threadIdx.x;
    if (i < n) {
        int v = part[i] + bsum[i >> 10];
        rowptr[i] = v;
        cursor[i] = v;
    }
    if (i == 0) rowptr[n] = total;
}

__global__ void k_scatter(const int* __restrict__ src, const int* __restrict__ dst,
                          int* __restrict__ cursor, int* __restrict__ col, int ne) {
    int e = blockIdx.x * 256 + threadIdx.x;
    if (e >= ne) return;
    int pos = atomicAdd(&cursor[dst[e]], 1);
    col[pos] = src[e];
}

// ---------------- stage-1 layer a ----------------
__global__ __launch_bounds__(256) void k_agg16(const float* __restrict__ h,
                                               const int* __restrict__ rowptr,
                                               const int* __restrict__ col,
                                               float* __restrict__ agg, float* __restrict__ deg,
                                               int nrows) {
    int i = blockIdx.x * 256 + threadIdx.x;
    int r = i >> 4, j = i & 15;
    if (r >= nrows) return;
    int b = rowptr[r], e = rowptr[r + 1];
    float a = h[r * 16 + j];
    for (int q = b; q < e; ++q) a += h[col[q] * 16 + j];
    agg[r * 16 + j] = a;
    if (j == 0) deg[r] = 1.0f + (float)(e - b);
}

__global__ __launch_bounds__(256) void k_sage16(
    const float* __restrict__ h, const float* __restrict__ agg, const float* __restrict__ deg,
    const float* __restrict__ Wl, const float* __restrict__ Wr, const float* __restrict__ bl,
    float* __restrict__ y, int nrows)
{
    __shared__ float WlS[16][128], WrS[16][128];
    int tid = threadIdx.x;
    for (int i = tid; i < 16 * 128; i += 256) {
        WlS[i >> 7][i & 127] = Wl[i];
        WrS[i >> 7][i & 127] = Wr[i];
    }
    __syncthreads();
    long long o = (long long)blockIdx.x * 256 + tid;
    int row = (int)(o >> 7);
    if (row >= nrows) return;
    int d = (int)o & 127;
    float invd = 1.0f / fmaxf(deg[row], 1.0f);
    float s = bl[d];
    #pragma unroll
    for (int k = 0; k < 16; ++k)
        s += agg[row * 16 + k] * invd * WlS[k][d] + h[row * 16 + k] * WrS[k][d];
    y[(long long)row * 128 + d] = tanhf(s);
}

// ---------------- stage-1 CSR gather-aggregate (fp32 out) ----------------
__global__ __launch_bounds__(256) void k_aggf0(
    const float* __restrict__ x,
    const int* __restrict__ rowptr, const int* __restrict__ col,
    float* __restrict__ AGG, int nrowsC)
{
    int tid = threadIdx.x;
    int r = blockIdx.x * 8 + (tid >> 5);
    if (r >= nrowsC) return;
    int lane = tid & 31;
    int b = rowptr[r], e = rowptr[r + 1];
    float4 a = *reinterpret_cast<const float4*>(x + (long long)r * 128 + lane * 4);
    float dsum = 1.0f + (float)(e - b);
    for (int q = b; q < e; ++q) {
        int s = col[q];
        float4 v = *reinterpret_cast<const float4*>(x + (long long)s * 128 + lane * 4);
        a.x += v.x; a.y += v.y; a.z += v.z; a.w += v.w;
    }
    float invds = 1.0f / fmaxf(dsum, 1.0f);
    a.x *= invds; a.y *= invds; a.z *= invds; a.w *= invds;
    *reinterpret_cast<float4*>(AGG + (long long)r * 128 + lane * 4) = a;
}

// ---------------- stage-2 CSR gather-aggregate (bf16 in/out, alive-compacted) ----------------
__global__ __launch_bounds__(256) void k_aggf2(
    const unsigned short* __restrict__ x,
    const int* __restrict__ rowptr, const int* __restrict__ col,
    const int* __restrict__ aliveIdx, const float* __restrict__ nal, const float* __restrict__ fvec,
    int rowbase,
    unsigned short* __restrict__ AGGb, int nrowsC)
{
    int tid = threadIdx.x;
    int r = blockIdx.x * 8 + (tid >> 5);
    if (r >= nrowsC) return;
    int lane = tid & 31;
    int orig = aliveIdx[r];
    int grow = rowbase + orig;
    int b = rowptr[grow], e = rowptr[grow + 1];
    float4 a = make_float4(0.0f, 0.0f, 0.0f, 0.0f);
    float dsum = 0.0f;
    for (int q = b; q < e; ++q) {
        int fr = col[q] - rowbase;
        if (nal[fr] == 0.0f) continue;
        dsum += 1.0f;
        float fw = fvec[fr];
        if (fw == 0.0f) continue;
        ushort4 v = *reinterpret_cast<const ushort4*>(x + (long long)fr * 128 + lane * 4);
        a.x += bf2f(v.x) * fw; a.y += bf2f(v.y) * fw;
        a.z += bf2f(v.z) * fw; a.w += bf2f(v.w) * fw;
    }
    float invds = 1.0f / fmaxf(dsum, 1.0f);
    ushort4 o;
    o.x = f2bf(a.x * invds); o.y = f2bf(a.y * invds);
    o.z = f2bf(a.z * invds); o.w = f2bf(a.w * invds);
    *reinterpret_cast<ushort4*>(AGGb + (long long)r * 128 + lane * 4) = o;
}

// ---------------- dense SAGE GEMM (fp32 v2 tile) — stage-1 only ----------------
__global__ __launch_bounds__(256) void k_sage_d(
    const float* __restrict__ AGG, const float* __restrict__ xsrc,
    const float* __restrict__ Wl, const float* __restrict__ Wr, const float* __restrict__ bl,
    float* __restrict__ y, int nrowsC,
    const float* __restrict__ gw, float* __restrict__ gdot)
{
    __shared__ float Ws[32 * 128];
    __shared__ float Is[32][68];
    __shared__ float gwS[128];
    int tid = threadIdx.x;
    long long row0 = (long long)blockIdx.x * 64;
    if (tid < 128 && gw) gwS[tid] = gw[tid];
    __syncthreads();
    int tx = tid & 31, ty = tid >> 5;
    float gg4[4] = {0,0,0,0};
    if (gw) { gg4[0]=gwS[tx*4]; gg4[1]=gwS[tx*4+1]; gg4[2]=gwS[tx*4+2]; gg4[3]=gwS[tx*4+3]; }
    int srow = tid & 63;
    int koff = (tid >> 6) * 8;
    long long crow = row0 + srow;
    if (crow >= nrowsC) crow = nrowsC - 1;
    const float* selfp = xsrc + crow * 128;
    const float* aggp = AGG + crow * 128;

    float acc[8][4] = {};
    for (int kb = 0; kb < 8; ++kb) {
        __syncthreads();
        bool isAgg = (kb < 4);
        const float* Wsrc = isAgg ? (Wl + kb * 32 * 128) : (Wr + (kb - 4) * 32 * 128);
        #pragma unroll
        for (int j = 0; j < 4; ++j) {
            int fl = j * 1024 + tid * 4;
            *reinterpret_cast<float4*>(&Ws[fl]) = *reinterpret_cast<const float4*>(&Wsrc[fl]);
        }
        {
            const float* sp = (isAgg ? (aggp + kb * 32) : (selfp + (kb - 4) * 32)) + koff;
            float4 v0 = *reinterpret_cast<const float4*>(sp);
            float4 v1 = *reinterpret_cast<const float4*>(sp + 4);
            Is[koff + 0][srow] = v0.x; Is[koff + 1][srow] = v0.y;
            Is[koff + 2][srow] = v0.z; Is[koff + 3][srow] = v0.w;
            Is[koff + 4][srow] = v1.x; Is[koff + 5][srow] = v1.y;
            Is[koff + 6][srow] = v1.z; Is[koff + 7][srow] = v1.w;
        }
        __syncthreads();
        #pragma unroll
        for (int kk = 0; kk < 32; ++kk) {
            float4 wv = *reinterpret_cast<const float4*>(&Ws[kk * 128 + tx * 4]);
            float4 i0 = *reinterpret_cast<const float4*>(&Is[kk][ty * 8]);
            float4 i1 = *reinterpret_cast<const float4*>(&Is[kk][ty * 8 + 4]);
            float ia[8] = {i0.x, i0.y, i0.z, i0.w, i1.x, i1.y, i1.z, i1.w};
            float wa[4] = {wv.x, wv.y, wv.z, wv.w};
            #pragma unroll
            for (int i = 0; i < 8; ++i)
                #pragma unroll
                for (int j = 0; j < 4; ++j)
                    acc[i][j] += ia[i] * wa[j];
        }
    }
    float4 bl0 = *reinterpret_cast<const float4*>(&bl[tx * 4]);
    float br[4] = {bl0.x, bl0.y, bl0.z, bl0.w};
    #pragma unroll
    for (int i = 0; i < 8; ++i) {
        long long row = row0 + ty * 8 + i;
        bool valid = (row < nrowsC);
        float yv[4];
        #pragma unroll
        for (int j = 0; j < 4; ++j) yv[j] = tanhf(acc[i][j] + br[j]);
        if (valid)
            *reinterpret_cast<float4*>(&y[row * 128 + tx * 4]) = make_float4(yv[0], yv[1], yv[2], yv[3]);
        float gp = 0.0f;
        #pragma unroll
        for (int j = 0; j < 4; ++j) if (gdot) gp += yv[j] * gg4[j];
        #pragma unroll
        for (int m = 16; m >= 1; m >>= 1) if (gdot) gp += __shfl_xor(gp, m, 32);
        if (tx == 0 && valid && gdot) gdot[row] = gp;
    }
}

// ---------------- bf16 weight pack ----------------
__global__ void k_packW(const float* __restrict__ Wl, const float* __restrict__ Wr,
                        short* __restrict__ Wb) {
    int i = blockIdx.x * 256 + threadIdx.x;
    if (i >= 32768) return;
    int kt = i >> 12, rem = i & 4095;
    int ct = rem >> 9; rem &= 511;
    int lane = rem >> 3, e = rem & 7;
    int k = kt * 32 + (lane >> 4) * 8 + e;
    int c = ct * 16 + (lane & 15);
    float v = (k < 128) ? Wl[k * 128 + c] : Wr[(k - 128) * 128 + c];
    Wb[i] = (short)f2bf(v);
}

// ---------------- MFMA SAGE GEMM (stage-2 L1/L2): 16 rows/wave, 64 rows/block ----------------
__global__ __launch_bounds__(256) void k_sage_m(
    const unsigned short* __restrict__ AGGb, const unsigned short* __restrict__ X,
    const int* __restrict__ aliveIdx, const float* __restrict__ fvec,
    const short* __restrict__ Wb, const float* __restrict__ bl,
    unsigned short* __restrict__ y, int nrowsC,
    const float* __restrict__ wrel, const float* __restrict__ wroot, const float* __restrict__ gw,
    float* __restrict__ tbuf, float* __restrict__ rootd, float* __restrict__ gdot)
{
    __shared__ short8 lB[2048];
    int tid = threadIdx.x;
    int lane = tid & 63;
    int wv = tid >> 6;
    long long rows0 = (long long)blockIdx.x * 64 + wv * 16;
    int arow = lane & 15;
    int ksl = (lane >> 4) * 8;

    int growA = (int)(rows0 + arow);
    int origA = aliveIdx[growA];
    float fsA = fvec[origA];

    f32x4 acc[8] = {};
    const short8* Wbv = (const short8*)Wb;

    for (int half = 0; half < 2; ++half) {
        __syncthreads();
        #pragma unroll
        for (int i = 0; i < 8; ++i) {
            int idx = i * 256 + tid;
            lB[idx] = Wbv[half * 2048 + idx];
        }
        __syncthreads();
        #pragma unroll
        for (int ktl = 0; ktl < 4; ++ktl) {
            int kt = half * 4 + ktl;
            short8 afr;
            if (kt < 4) {
                afr = *reinterpret_cast<const short8*>(AGGb + (long long)growA * 128 + kt * 32 + ksl);
            } else {
                short8 xv = *reinterpret_cast<const short8*>(X + (long long)origA * 128 + (kt - 4) * 32 + ksl);
                #pragma unroll
                for (int e = 0; e < 8; ++e)
                    afr[e] = (short)f2bf(bf2f((unsigned short)xv[e]) * fsA);
            }
            #pragma unroll
            for (int ct = 0; ct < 8; ++ct) {
                short8 bfr = lB[(ktl * 8 + ct) * 64 + lane];
                acc[ct] = __builtin_amdgcn_mfma_f32_16x16x32_bf16(afr, bfr, acc[ct], 0, 0, 0);
            }
        }
    }

    int ocol = lane & 15;
    float blv[8], wrv[8], wov[8], ggv[8];
    #pragma unroll
    for (int ct = 0; ct < 8; ++ct) {
        int c = ct * 16 + ocol;
        blv[ct] = bl[c];
        wrv[ct] = wrel[c];
        wov[ct] = wroot[c];
        ggv[ct] = gw[c];
    }
    #pragma unroll
    for (int j = 0; j < 4; ++j) {
        int rloc = (lane >> 4) * 4 + j;
        long long grow = rows0 + rloc;
        int orig = aliveIdx[grow];
        float tp = 0.0f, rp = 0.0f, gp = 0.0f;
        #pragma unroll
        for (int ct = 0; ct < 8; ++ct) {
            float v = tanhf(acc[ct][j] + blv[ct]);
            y[(long long)orig * 128 + ct * 16 + ocol] = f2bf(v);
            tp += v * wrv[ct]; rp += v * wov[ct]; gp += v * ggv[ct];
        }
        #pragma unroll
        for (int mm = 8; mm >= 1; mm >>= 1) {
            tp += __shfl_xor(tp, mm, 16);
            rp += __shfl_xor(rp, mm, 16);
            gp += __shfl_xor(gp, mm, 16);
        }
        if (ocol == 0) { tbuf[orig] = tp; rootd[orig] = rp; gdot[orig] = gp; }
    }
}

// ---------------- plain GEMM: y = x@W (+ b), v2 tile ----------------
__global__ __launch_bounds__(256) void k_gemm_self(
    const float* __restrict__ x, const float* __restrict__ W, const float* __restrict__ b,
    float* __restrict__ y, int nrows)
{
    __shared__ float Ws[32 * 128];
    __shared__ float Is[32][68];
    int tid = threadIdx.x;
    long long row0 = (long long)blockIdx.x * 64;
    int tx = tid & 31, ty = tid >> 5;
    int srow = tid & 63;
    int koff = (tid >> 6) * 8;
    long long lrow = row0 + srow;
    if (lrow >= nrows) lrow = nrows - 1;
    const float* xrow = x + lrow * 128;
    float acc[8][4] = {};
    for (int kb = 0; kb < 4; ++kb) {
        __syncthreads();
        const float* Wsrc = W + kb * 32 * 128;
        #pragma unroll
        for (int j = 0; j < 4; ++j) {
            int fl = j * 1024 + tid * 4;
            *reinterpret_cast<float4*>(&Ws[fl]) = *reinterpret_cast<const float4*>(&Wsrc[fl]);
        }
        {
            const float* sp = xrow + kb * 32 + koff;
            float4 v0 = *reinterpret_cast<const float4*>(sp);
            float4 v1 = *reinterpret_cast<const float4*>(sp + 4);
            Is[koff + 0][srow] = v0.x; Is[koff + 1][srow] = v0.y;
            Is[koff + 2][srow] = v0.z; Is[koff + 3][srow] = v0.w;
            Is[koff + 4][srow] = v1.x; Is[koff + 5][srow] = v1.y;
            Is[koff + 6][srow] = v1.z; Is[koff + 7][srow] = v1.w;
        }
        __syncthreads();
        #pragma unroll
        for (int kk = 0; kk < 32; ++kk) {
            float4 wv = *reinterpret_cast<const float4*>(&Ws[kk * 128 + tx * 4]);
            float4 i0 = *reinterpret_cast<const float4*>(&Is[kk][ty * 8]);
            float4 i1 = *reinterpret_cast<const float4*>(&Is[kk][ty * 8 + 4]);
            float ia[8] = {i0.x, i0.y, i0.z, i0.w, i1.x, i1.y, i1.z, i1.w};
            float wa[4] = {wv.x, wv.y, wv.z, wv.w};
            #pragma unroll
            for (int i = 0; i < 8; ++i)
                #pragma unroll
                for (int j = 0; j < 4; ++j)
                    acc[i][j] += ia[i] * wa[j];
        }
    }
    float4 b0 = b ? *reinterpret_cast<const float4*>(&b[tx * 4]) : make_float4(0.f, 0.f, 0.f, 0.f);
    #pragma unroll
    for (int i = 0; i < 8; ++i) {
        long long row = row0 + ty * 8 + i;
        if (row >= nrows) continue;
        *reinterpret_cast<float4*>(&y[row * 128 + tx * 4]) =
            make_float4(acc[i][0] + b0.x, acc[i][1] + b0.y, acc[i][2] + b0.z, acc[i][3] + b0.w);
    }
}

// ---------------- stage-2 L0 combine (bf16 X out) ----------------
__global__ __launch_bounds__(256) void k_l0comb(
    const float* __restrict__ ZL0, const float* __restrict__ zself,
    const int* __restrict__ rowptr, const int* __restrict__ col, int rowbase,
    const float* __restrict__ wrel, const float* __restrict__ wroot, const float* __restrict__ gw,
    unsigned short* __restrict__ y, float* __restrict__ tbuf, float* __restrict__ rootd, float* __restrict__ gdot,
    int nrowsC)
{
    __shared__ float wrelS[128], wrootS[128], gwS[128];
    int tid = threadIdx.x;
    if (tid < 128) {
        wrelS[tid]  = wrel[tid];
        wrootS[tid] = wroot[tid];
        gwS[tid]    = gw[tid];
    }
    __syncthreads();
    int r = blockIdx.x * 8 + (tid >> 5);
    if (r >= nrowsC) return;
    int lane = tid & 31;
    int grow = rowbase + r;
    int b = rowptr[grow], e = rowptr[grow + 1];
    float4 a = make_float4(0.0f, 0.0f, 0.0f, 0.0f);
    for (int q = b; q < e; ++q) {
        int fr = col[q] % NN;
        float4 v = *reinterpret_cast<const float4*>(ZL0 + (long long)fr * 128 + lane * 4);
        a.x += v.x; a.y += v.y; a.z += v.z; a.w += v.w;
    }
    float invds = 1.0f / fmaxf((float)(e - b), 1.0f);
    const float4 z = *reinterpret_cast<const float4*>(zself + (long long)(r % NN) * 128 + lane * 4);
    float yv[4];
    yv[0] = tanhf(a.x * invds + z.x);
    yv[1] = tanhf(a.y * invds + z.y);
    yv[2] = tanhf(a.z * invds + z.z);
    yv[3] = tanhf(a.w * invds + z.w);
    ushort4 o;
    o.x = f2bf(yv[0]); o.y = f2bf(yv[1]); o.z = f2bf(yv[2]); o.w = f2bf(yv[3]);
    *reinterpret_cast<ushort4*>(y + (long long)r * 128 + lane * 4) = o;
    float tp = 0.0f, rp = 0.0f, gp = 0.0f;
    #pragma unroll
    for (int j = 0; j < 4; ++j) {
        tp += yv[j] * wrelS[lane*4 + j];
        rp += yv[j] * wrootS[lane*4 + j];
        gp += yv[j] * gwS[lane*4 + j];
    }
    #pragma unroll
    for (int m = 16; m >= 1; m >>= 1) {
        tp += __shfl_xor(tp, m, 32);
        rp += __shfl_xor(rp, m, 32);
        gp += __shfl_xor(gp, m, 32);
    }
    if (lane == 0) {
        tbuf[r]  = tp;
        rootd[r] = rp;
        gdot[r]  = gp;
    }
}

// ---------------- stage-1 readout pieces ----------------
__global__ __launch_bounds__(256) void k_gate(
    const float* __restrict__ X, const float* __restrict__ gw,
    float* __restrict__ g, int nrows)
{
    __shared__ float wS[128];
    if (threadIdx.x < 128) wS[threadIdx.x] = gw[threadIdx.x];
    __syncthreads();
    int i = blockIdx.x * 256 + threadIdx.x;
    if (i >= nrows) return;
    const float4* xrp = reinterpret_cast<const float4*>(X + (long long)i * 128);
    float s = 0.0f;
    #pragma unroll
    for (int k = 0; k < 32; ++k) {
        float4 v = xrp[k];
        s += v.x * wS[4*k] + v.y * wS[4*k+1] + v.z * wS[4*k+2] + v.w * wS[4*k+3];
    }
    g[i] = s;
}

__global__ __launch_bounds__(1024) void k_smstats(float* __restrict__ g, float* __restrict__ invp) {
    __shared__ float red[1024];
    int p = blockIdx.x, tid = threadIdx.x;
    float* gp = g + (long long)p * NN;
    float lmax = -INFINITY;
    for (int n = tid; n < NN; n += 1024) lmax = fmaxf(lmax, gp[n]);
    red[tid] = lmax; __syncthreads();
    for (int s = 512; s > 0; s >>= 1) { if (tid < s) red[tid] = fmaxf(red[tid], red[tid + s]); __syncthreads(); }
    float mx = red[0]; __syncthreads();
    float ls = 0.0f;
    for (int n = tid; n < NN; n += 1024) { float e = expf(gp[n] - mx); gp[n] = e; ls += e; }
    red[tid] = ls; __syncthreads();
    for (int s = 512; s > 0; s >>= 1) { if (tid < s) red[tid] += red[tid + s]; __syncthreads(); }
    if (tid == 0) invp[p] = 1.0f / red[0];
}

__global__ __launch_bounds__(128) void k_wsum(
    const float* __restrict__ X, const float* __restrict__ a,
    const float* __restrict__ invp, float* __restrict__ ro, int rowbase, int colOff)
{
    int p = blockIdx.x / BPG;
    int chunk = blockIdx.x % BPG;
    int d = threadIdx.x;
    long long base = (long long)p * NN;
    int r0 = chunk * RB, r1 = r0 + RB;
    float s = 0.0f;
    for (int n = r0; n < r1; ++n) {
        float w = a[base + n];
        if (w != 0.0f) s += w * X[(base + n) * 128 + d];
    }
    atomicAdd(&ro[(long long)(rowbase + p) * 384 + colOff + d], s * invp[p]);
}

// stage-2 weighted sum over alive rows only (bf16 X)
__global__ __launch_bounds__(128) void k_wsum_c(
    const unsigned short* __restrict__ X, const float* __restrict__ gbuf, const float* __restrict__ fvec,
    const float* __restrict__ invp, const int* __restrict__ aliveIdx, int k,
    float* __restrict__ ro, int rowbaseRo, int colOff)
{
    int bpp = k / RB;
    int p = blockIdx.x / bpp;
    int chunk = blockIdx.x % bpp;
    int d = threadIdx.x;
    const int* ai = aliveIdx + (long long)p * k + chunk * RB;
    float s = 0.0f;
    for (int j = 0; j < RB; ++j) {
        int row = ai[j];
        float w = gbuf[row] * fvec[row];
        s += w * bf2f(X[(long long)row * 128 + d]);
    }
    atomicAdd(&ro[(long long)(rowbaseRo + p) * 384 + colOff + d], s * invp[p]);
}

// ---------------- GraphNorm ----------------
__global__ void k_colstat(const float* __restrict__ x, float* __restrict__ musum,
                          float* __restrict__ sqsum, int nrows) {
    int d = threadIdx.x;
    int r0 = blockIdx.x * 64;
    int r1 = min(r0 + 64, nrows);
    float s = 0.0f, q = 0.0f;
    for (int r = r0; r < r1; ++r) { float v = x[(long long)r * 128 + d]; s += v; q += v * v; }
    atomicAdd(&musum[d], s);
    atomicAdd(&sqsum[d], q);
}

__global__ void k_gnorm_apply(const float* __restrict__ x, float* __restrict__ y,
                              const float* __restrict__ musum, const float* __restrict__ sqsum,
                              const float* __restrict__ w, const float* __restrict__ b,
                              const float* __restrict__ ms, int nrows) {
    long long i = (long long)blockIdx.x * 256 + threadIdx.x;
    if (i >= (long long)nrows * 128) return;
    int d = (int)(i & 127);
    float inv_n = 1.0f / (float)nrows;
    float mu = musum[d] * inv_n;
    float c = mu * ms[d];
    float var = sqsum[d] * inv_n - 2.0f * c * mu + c * c;
    y[i] = w[d] * (x[i] - c) * rsqrtf(var + 1e-5f) + b[d];
}

// ---------------- mega top-k (1024 threads, parallel bucket select) ----------------
#define TCH 8
__global__ __launch_bounds__(1024) void k_topk2(
    const int* __restrict__ rowptr, const int* __restrict__ col, int rowbase,
    const float* __restrict__ tb, const float* __restrict__ rootd,
    const float* __restrict__ gdot, const float* __restrict__ brelp, int bi, int allAlive,
    float* __restrict__ nalive, float* __restrict__ fvec, float* __restrict__ gbuf,
    float* __restrict__ invp, int* __restrict__ aliveIdx, int k)
{
    __shared__ unsigned keys[NN];
    __shared__ int hist[256];
    __shared__ int scan[1024];
    __shared__ float redf[1024];
    __shared__ unsigned sh_pref;
    __shared__ int sh_kneed;
    int p = blockIdx.x, tid = threadIdx.x;
    float brel = brelp[bi];
    long long pbase = (long long)p * NN;
    for (int n = tid; n < NN; n += 1024) {
        long long gl = pbase + n;
        int grow = rowbase + (int)gl;
        float s = brel + rootd[gl];
        int b = rowptr[grow], e = rowptr[grow + 1];
        for (int q = b; q < e; ++q) {
            int sl = col[q] - rowbase;
            s += allAlive ? tb[sl] : (tb[sl] * nalive[sl]);
        }
        bool alive = allAlive || (nalive[gl] > 0.5f);
        keys[n] = alive ? fkey(s) : 0u;
    }
    if (tid == 0) { sh_pref = 0u; sh_kneed = k; }
    __syncthreads();
    for (int lvl = 3; lvl >= 0; --lvl) {
        int sh = lvl * 8;
        if (tid < 256) hist[tid] = 0;
        unsigned pref = sh_pref; int kneed = sh_kneed;
        unsigned pmask = (lvl == 3) ? 0u : (0xFFFFFFFFu << (8 * (lvl + 1)));
        __syncthreads();
        for (int n = tid; n < NN; n += 1024) {
            unsigned kv = keys[n];
            if ((kv & pmask) == pref) atomicAdd(&hist[(kv >> sh) & 255], 1);
        }
        __syncthreads();
        if (tid < 256) scan[tid] = hist[tid];
        __syncthreads();
        for (int off = 1; off < 256; off <<= 1) {
            int v = 0;
            if (tid < 256 && tid + off < 256) v = scan[tid + off];
            __syncthreads();
            if (tid < 256) scan[tid] += v;
            __syncthreads();
        }
        if (tid < 256) {
            int c = scan[tid];
            int cex = c - hist[tid];
            if (c >= kneed && cex < kneed) {
                sh_pref = pref | ((unsigned)tid << sh);
                sh_kneed = kneed - cex;
            }
        }
        __syncthreads();
    }
    unsigned V = sh_pref;
    int seleq = sh_kneed;
    int c0 = tid * TCH, c1 = min(c0 + TCH, NN);
    int ceq = 0;
    for (int n = c0; n < c1; ++n) ceq += (keys[n] == V) ? 1 : 0;
    scan[tid] = ceq; __syncthreads();
    for (int off = 1; off < 1024; off <<= 1) {
        int u = (tid >= off) ? scan[tid - off] : 0;
        __syncthreads();
        scan[tid] += u;
        __syncthreads();
    }
    int rank = scan[tid] - ceq;
    unsigned selmask = 0u;
    int nsel = 0;
    float lmax = -INFINITY;
    for (int n = c0; n < c1; ++n) {
        unsigned kk = keys[n];
        bool sel = (kk > V) || (kk == V && rank < seleq);
        if (kk == V) rank++;
        long long gl = pbase + n;
        nalive[gl] = sel ? 1.0f : 0.0f;
        float f = 0.0f;
        if (sel) {
            f = tanhf(fkey_inv(kk));
            lmax = fmaxf(lmax, f * gdot[gl]);
            selmask |= (1u << (n - c0));
            ++nsel;
        }
        fvec[gl] = f;
    }
    redf[tid] = lmax; __syncthreads();
    for (int s = 512; s > 0; s >>= 1) { if (tid < s) redf[tid] = fmaxf(redf[tid], redf[tid + s]); __syncthreads(); }
    float mx = redf[0]; __syncthreads();
    scan[tid] = nsel; __syncthreads();
    for (int off = 1; off < 1024; off <<= 1) {
        int u = (tid >= off) ? scan[tid - off] : 0;
        __syncthreads();
        scan[tid] += u;
        __syncthreads();
    }
    int pos = scan[tid] - nsel;
    float lsum = 0.0f;
    for (int n = c0; n < c1; ++n) {
        if (selmask & (1u << (n - c0))) {
            long long gl = pbase + n;
            float e = expf(fvec[gl] * gdot[gl] - mx);
            gbuf[gl] = e;
            lsum += e;
            aliveIdx[(long long)p * k + pos] = (int)gl;
            ++pos;
        }
    }
    redf[tid] = lsum; __syncthreads();
    for (int s = 512; s > 0; s >>= 1) { if (tid < s) redf[tid] += redf[tid + s]; __syncthreads(); }
    if (tid == 0) invp[p] = 1.0f / redf[0];
}

// ---------------- head ----------------
__global__ __launch_bounds__(64) void k_head(
    const float* __restrict__ ro, const float* __restrict__ lin_w, const float* __restrict__ lin_b,
    const float* __restrict__ m1w, const float* __restrict__ m1b,
    const float* __restrict__ m2w, const float* __restrict__ m2b,
    const float* __restrict__ m3w, const float* __restrict__ m3b, float* __restrict__ out)
{
    __shared__ float v[33], h1[48], h2[16];
    int t = threadIdx.x;
    if (t < 33) {
        float s = lin_b[0];
        for (int k = 0; k < 384; ++k) s += ro[t * 384 + k] * lin_w[k];
        v[t] = tanhf(s);
    }
    __syncthreads();
    if (t < 48) {
        float s = m1b[t];
        for (int i = 0; i < 33; ++i) s += v[i] * m1w[i * 48 + t];
        h1[t] = tanhf(s);
    }
    __syncthreads();
    if (t < 16) {
        float s = m2b[t];
        for (int i = 0; i < 48; ++i) s += h1[i] * m2w[i * 16 + t];
        h2[t] = tanhf(s);
    }
    __syncthreads();
    if (t == 0) {
        float s = m3b[0];
        for (int i = 0; i < 16; ++i) s += h2[i] * m3w[i];
        float s1 = 1.0f / (1.0f + expf(-s));
        out[0] = 1.0f / (1.0f + expf(-s1));
    }
}

static inline int cdiv(long long a, long long b) { return (int)((a + b - 1) / b); }

extern "C" void kernel_launch(void* const* d_in, const int* in_sizes, int n_in,
                              void* d_out, int out_size, void* d_ws, size_t ws_size,
                              hipStream_t stream)
{
    (void)in_sizes; (void)n_in; (void)out_size;
    const float* h     = (const float*)d_in[0];
    const int*   eidx  = (const int*)d_in[1];
    const int*   seidx = (const int*)d_in[2];
    const float* Wl_a  = (const float*)d_in[3];
    const float* Wr_a  = (const float*)d_in[4];
    const float* bl_a  = (const float*)d_in[5];
    const float* Wl_s  = (const float*)d_in[6];
    const float* Wr_s  = (const float*)d_in[7];
    const float* bl_s  = (const float*)d_in[8];
    const float* gate_w = (const float*)d_in[9];
    const float* p_wrel = (const float*)d_in[11];
    const float* p_brel = (const float*)d_in[12];
    const float* p_wroot= (const float*)d_in[13];
    const float* nw    = (const float*)d_in[14];
    const float* nb    = (const float*)d_in[15];
    const float* nms   = (const float*)d_in[16];
    const float* lin_w = (const float*)d_in[17];
    const float* lin_b = (const float*)d_in[18];
    const float* m1w   = (const float*)d_in[19];
    const float* m1b   = (const float*)d_in[20];
    const float* m2w   = (const float*)d_in[21];
    const float* m2b   = (const float*)d_in[22];
    const float* m3w   = (const float*)d_in[23];
    const float* m3b   = (const float*)d_in[24];
    float* out = (float*)d_out;

    const int* esrc = eidx;
    const int* edst = eidx + EG;
    const int* ssrc = seidx;
    const int* sdst = seidx + ES_TOT;

    auto need_bytes = [](int chp) -> size_t {
        long long chn = (long long)chp * NN;
        long long f = chn * 64
                    + (long long)chp * KK1 * 64
                    + 2LL * NN * 128
                    + 5 * chn
                    + 64 + 33 * 384
                    + (long long)chp * KK1
                    + (PN + 1) + ES_TOT
                    + 2 * 16384
                    + 64 * 24;
        return (size_t)f * 4;
    };
    int chp = 8;
    if (ws_size >= need_bytes(32)) chp = 32;
    else if (ws_size >= need_bytes(16)) chp = 16;
    int nch = PP / chp;
    long long ch_n = (long long)chp * NN;

    float* W = (float*)d_ws;
    size_t off = 0;
    auto alloc = [&](size_t nf) { float* p = W + off; off += (nf + 63) & ~(size_t)63; return p; };
    unsigned short* XAb = (unsigned short*)alloc((size_t)ch_n * 64);
    unsigned short* AGGb = (unsigned short*)alloc((size_t)chp * KK1 * 64);
    float* ZL0   = alloc((size_t)NN * DD);
    float* zself = alloc((size_t)NN * DD);
    float* tbuf  = alloc(ch_n);
    float* rootd = alloc(ch_n);
    float* nal   = alloc(ch_n);
    float* fvec  = alloc(ch_n);
    float* gdot  = alloc(ch_n);
    float* invp  = alloc(64);
    float* ro    = alloc(33 * 384);
    int* aliveIdx = (int*)alloc((size_t)chp * KK1);
    int* s2rp    = (int*)alloc(PN + 1);
    int* s2col   = (int*)alloc(ES_TOT);
    short* Wb1   = (short*)alloc(16384);
    short* Wb2   = (short*)alloc(16384);
    float* gbuf = tbuf;

    // overlay inside XAb (dead before XAb's first write)
    float* XO = (float*)XAb;
    size_t ooff = 0;
    auto oalloc = [&](size_t nf) { float* p = XO + ooff; ooff += (nf + 63) & ~(size_t)63; return p; };
    float* xa    = oalloc((size_t)NN * DD);
    float* xb    = oalloc((size_t)NN * DD);
    float* AGGs  = oalloc((size_t)NN * DD);
    float* agg1  = oalloc((size_t)NN * 16);
    float* deg1  = oalloc(NN);
    float* musum = oalloc(128);
    float* sqsum = oalloc(128);
    int* s1cnt  = (int*)oalloc(NN);
    int* s1rp   = (int*)oalloc(NN + 1);
    int* s1cur  = (int*)oalloc(NN);
    int* s1col  = (int*)oalloc(EG);
    int* s1part = (int*)oalloc(NN);
    int* s1bsum = (int*)oalloc(1024);
    int* s2cnt  = (int*)oalloc(PN);
    int* s2cur  = (int*)oalloc(PN);
    int* s2part = (int*)oalloc(PN);
    int* s2bsum = (int*)oalloc(1024);

    // ---------- CSR builds ----------
    int nb1 = cdiv(NN, 1024), nb2 = cdiv(PN, 1024);
    hipMemsetAsync(s1cnt, 0, NN * sizeof(int), stream);
    k_hist<<<cdiv(EG,256),256,0,stream>>>(edst, s1cnt, EG);
    k_scanA<<<nb1,1024,0,stream>>>(s1cnt, s1part, s1bsum, NN);
    k_scanB<<<1,1024,0,stream>>>(s1bsum, nb1);
    k_scanC<<<cdiv(NN,256),256,0,stream>>>(s1part, s1bsum, s1rp, s1cur, NN, EG);
    k_scatter<<<cdiv(EG,256),256,0,stream>>>(esrc, edst, s1cur, s1col, EG);

    hipMemsetAsync(s2cnt, 0, (size_t)PN * sizeof(int), stream);
    k_hist<<<cdiv(ES_TOT,256),256,0,stream>>>(sdst, s2cnt, ES_TOT);
    k_scanA<<<nb2,1024,0,stream>>>(s2cnt, s2part, s2bsum, PN);
    k_scanB<<<1,1024,0,stream>>>(s2bsum, nb2);
    k_scanC<<<cdiv(PN,256),256,0,stream>>>(s2part, s2bsum, s2rp, s2cur, PN, ES_TOT);
    k_scatter<<<cdiv(ES_TOT,256),256,0,stream>>>(ssrc, sdst, s2cur, s2col, ES_TOT);

    hipMemsetAsync(ro, 0, 33 * 384 * sizeof(float), stream);

    k_packW<<<128,256,0,stream>>>(Wl_s + 3*16384, Wr_s + 3*16384, Wb1);
    k_packW<<<128,256,0,stream>>>(Wl_s + 4*16384, Wr_s + 4*16384, Wb2);

    // ---------- stage 1 ----------
    k_agg16<<<cdiv((long long)NN*16,256),256,0,stream>>>(h, s1rp, s1col, agg1, deg1, NN);
    k_sage16<<<cdiv((long long)NN*DD,256),256,0,stream>>>(h, agg1, deg1, Wl_a, Wr_a, bl_a, xa, NN);
    k_gate<<<cdiv(NN,256),256,0,stream>>>(xa, gate_w + 0*DD, gbuf, NN);
    k_smstats<<<1,1024,0,stream>>>(gbuf, invp);
    k_wsum<<<BPG,128,0,stream>>>(xa, gbuf, invp, ro, 0, 0);

    hipMemsetAsync(musum, 0, 128*sizeof(float), stream);
    hipMemsetAsync(sqsum, 0, 128*sizeof(float), stream);
    k_colstat<<<cdiv(NN,64),128,0,stream>>>(xa, musum, sqsum, NN);
    k_gnorm_apply<<<cdiv((long long)NN*DD,256),256,0,stream>>>(xa, xb, musum, sqsum, nw, nb, nms, NN);

    k_aggf0<<<cdiv(NN,8),256,0,stream>>>(xb, s1rp, s1col, AGGs, NN);
    k_sage_d<<<cdiv(NN,64),256,0,stream>>>(AGGs, xb,
        Wl_s + 0*16384, Wr_s + 0*16384, bl_s + 0*128, xa, NN,
        gate_w + 1*DD, gbuf);
    k_smstats<<<1,1024,0,stream>>>(gbuf, invp);
    k_wsum<<<BPG,128,0,stream>>>(xa, gbuf, invp, ro, 0, 128);

    hipMemsetAsync(musum, 0, 128*sizeof(float), stream);
    hipMemsetAsync(sqsum, 0, 128*sizeof(float), stream);
    k_colstat<<<cdiv(NN,64),128,0,stream>>>(xa, musum, sqsum, NN);
    k_gnorm_apply<<<cdiv((long long)NN*DD,256),256,0,stream>>>(xa, xb, musum, sqsum, nw, nb, nms, NN);

    k_aggf0<<<cdiv(NN,8),256,0,stream>>>(xb, s1rp, s1col, AGGs, NN);
    k_sage_d<<<cdiv(NN,64),256,0,stream>>>(AGGs, xb,
        Wl_s + 1*16384, Wr_s + 1*16384, bl_s + 1*128, xa, NN,
        gate_w + 2*DD, gbuf);
    k_smstats<<<1,1024,0,stream>>>(gbuf, invp);
    k_wsum<<<BPG,128,0,stream>>>(xa, gbuf, invp, ro, 0, 256);

    // ---------- stage 2 ----------
    k_gemm_self<<<cdiv(NN,64),256,0,stream>>>(xa, Wl_s + 2*16384, nullptr, ZL0, NN);
    k_gemm_self<<<cdiv(NN,64),256,0,stream>>>(xa, Wr_s + 2*16384, bl_s + 2*128, zself, NN);

    for (int c = 0; c < nch; ++c) {
        int nbase = (int)(c * ch_n);

        k_l0comb<<<(int)(ch_n/8),256,0,stream>>>(ZL0, zself, s2rp, s2col, nbase,
            p_wrel + 0*DD, p_wroot + 0*DD, gate_w + 3*DD,
            XAb, tbuf, rootd, gdot, (int)ch_n);
        k_topk2<<<chp,1024,0,stream>>>(s2rp, s2col, nbase, tbuf, rootd, gdot, p_brel, 0, 1,
                                       nal, fvec, gbuf, invp, aliveIdx, KK1);
        k_wsum_c<<<chp*(KK1/RB),128,0,stream>>>(XAb, gbuf, fvec, invp, aliveIdx, KK1, ro, 1 + c*chp, 0);

        k_aggf2<<<chp*(KK1/8),256,0,stream>>>(XAb, s2rp, s2col, aliveIdx, nal, fvec, nbase, AGGb, chp*KK1);
        k_sage_m<<<chp*(KK1/64),256,0,stream>>>(AGGb, XAb, aliveIdx, fvec, Wb1, bl_s + 3*128, XAb, chp*KK1,
            p_wrel + 1*DD, p_wroot + 1*DD, gate_w + 4*DD, tbuf, rootd, gdot);
        k_topk2<<<chp,1024,0,stream>>>(s2rp, s2col, nbase, tbuf, rootd, gdot, p_brel, 1, 0,
                                       nal, fvec, gbuf, invp, aliveIdx, KK2);
        k_wsum_c<<<chp*(KK2/RB),128,0,stream>>>(XAb, gbuf, fvec, invp, aliveIdx, KK2, ro, 1 + c*chp, 128);

        k_aggf2<<<chp*(KK2/8),256,0,stream>>>(XAb, s2rp, s2col, aliveIdx, nal, fvec, nbase, AGGb, chp*KK2);
        k_sage_m<<<chp*(KK2/64),256,0,stream>>>(AGGb, XAb, aliveIdx, fvec, Wb2, bl_s + 4*128, XAb, chp*KK2,
            p_wrel + 2*DD, p_wroot + 2*DD, gate_w + 5*DD, tbuf, rootd, gdot);
        k_topk2<<<chp,1024,0,stream>>>(s2rp, s2col, nbase, tbuf, rootd, gdot, p_brel, 2, 0,
                                       nal, fvec, gbuf, invp, aliveIdx, KK3);
        k_wsum_c<<<chp*(KK3/RB),128,0,stream>>>(XAb, gbuf, fvec, invp, aliveIdx, KK3, ro, 1 + c*chp, 256);
    }

    // ---------- head ----------
    k_head<<<1,64,0,stream>>>(ro, lin_w, lin_b, m1w, m1b, m2w, m2b, m3w, m3b, out);
}

// Round 19
// 703.307 us; speedup vs baseline: 3.7363x; 1.0099x over previous
//
#include <hip/hip_runtime.h>
#include <math.h>

#define NN      8000
#define PP      32
#define EG      128000
#define ES_TOT  131072     // P * 4096
#define ES_P    4096
#define PN      256000     // P * NN
#define DI      16
#define DD      128
#define KK1     6400
#define KK2     5120
#define KK3     4096
#define RB      64
#define BPG     (NN / RB)

typedef __attribute__((ext_vector_type(8))) short short8;
typedef __attribute__((ext_vector_type(4))) float f32x4;

static __device__ __forceinline__ unsigned fkey(float f) {
    unsigned u = __float_as_uint(f);
    return (u & 0x80000000u) ? ~u : (u | 0x80000000u);
}
static __device__ __forceinline__ float fkey_inv(unsigned k) {
    unsigned u = (k & 0x80000000u) ? (k & 0x7FFFFFFFu) : ~k;
    return __uint_as_float(u);
}
static __device__ __forceinline__ unsigned short f2bf(float f) {
    unsigned u = __float_as_uint(f);
    u += 0x7FFFu + ((u >> 16) & 1u);   // RNE
    return (unsigned short)(u >> 16);
}
static __device__ __forceinline__ float bf2f(unsigned short b) {
    return __uint_as_float((unsigned)b << 16);
}
// tanh(x) = 1 - 2/(e^{2x}+1); hardware exp + rcp, abs err ~2e-7, correct limits.
static __device__ __forceinline__ float ftanh(float x) {
    float e = __expf(2.0f * x);
    return 1.0f - 2.0f / (e + 1.0f);
}

// ---------------- CSR build ----------------
__global__ void k_hist(const int* __restrict__ dst, int* __restrict__ cnt, int ne) {
    int e = blockIdx.x * 256 + threadIdx.x;
    if (e < ne) atomicAdd(&cnt[dst[e]], 1);
}

__global__ __launch_bounds__(1024) void k_scanA(const int* __restrict__ cnt,
                                                int* __restrict__ part,
                                                int* __restrict__ bsum, int n) {
    __shared__ int sh[1024];
    int t = threadIdx.x;
    int i = blockIdx.x * 1024 + t;
    int v = (i < n) ? cnt[i] : 0;
    sh[t] = v; __syncthreads();
    for (int off = 1; off < 1024; off <<= 1) {
        int u = (t >= off) ? sh[t - off] : 0;
        __syncthreads();
        sh[t] += u;
        __syncthreads();
    }
    if (i < n) part[i] = sh[t] - v;
    if (t == 1023) bsum[blockIdx.x] = sh[1023];
}

__global__ __launch_bounds__(1024) void k_scanB(int* __restrict__ bsum, int nb) {
    __shared__ int sh[1024];
    int t = threadIdx.x;
    int v = (t < nb) ? bsum[t] : 0;
    sh[t] = v; __syncthreads();
    for (int off = 1; off < 1024; off <<= 1) {
        int u = (t >= off) ? sh[t - off] : 0;
        __syncthreads();
        sh[t] += u;
        __syncthreads();
    }
    if (t < nb) bsum[t] = sh[t] - v;
}

__global__ void k_scanC(const int* __restrict__ part, const int* __restrict__ bsum,
                        int* __restrict__ rowptr, int* __restrict__ cursor, int n, int total) {
    int i = blockIdx.x * 256 + threadIdx.x;
    if (i < n) {
        int v = part[i] + bsum[i >> 10];
        rowptr[i] = v;
        cursor[i] = v;
    }
    if (i == 0) rowptr[n] = total;
}

__global__ void k_scatter(const int* __restrict__ src, const int* __restrict__ dst,
                          int* __restrict__ cursor, int* __restrict__ col, int ne) {
    int e = blockIdx.x * 256 + threadIdx.x;
    if (e >= ne) return;
    int pos = atomicAdd(&cursor[dst[e]], 1);
    col[pos] = src[e];
}

// ---------------- stage-1 layer a ----------------
__global__ __launch_bounds__(256) void k_agg16(const float* __restrict__ h,
                                               const int* __restrict__ rowptr,
                                               const int* __restrict__ col,
                                               float* __restrict__ agg, float* __restrict__ deg,
                                               int nrows) {
    int i = blockIdx.x * 256 + threadIdx.x;
    int r = i >> 4, j = i & 15;
    if (r >= nrows) return;
    int b = rowptr[r], e = rowptr[r + 1];
    float a = h[r * 16 + j];
    for (int q = b; q < e; ++q) a += h[col[q] * 16 + j];
    agg[r * 16 + j] = a;
    if (j == 0) deg[r] = 1.0f + (float)(e - b);
}

__global__ __launch_bounds__(256) void k_sage16(
    const float* __restrict__ h, const float* __restrict__ agg, const float* __restrict__ deg,
    const float* __restrict__ Wl, const float* __restrict__ Wr, const float* __restrict__ bl,
    float* __restrict__ y, int nrows)
{
    __shared__ float WlS[16][128], WrS[16][128];
    int tid = threadIdx.x;
    for (int i = tid; i < 16 * 128; i += 256) {
        WlS[i >> 7][i & 127] = Wl[i];
        WrS[i >> 7][i & 127] = Wr[i];
    }
    __syncthreads();
    long long o = (long long)blockIdx.x * 256 + tid;
    int row = (int)(o >> 7);
    if (row >= nrows) return;
    int d = (int)o & 127;
    float invd = 1.0f / fmaxf(deg[row], 1.0f);
    float s = bl[d];
    #pragma unroll
    for (int k = 0; k < 16; ++k)
        s += agg[row * 16 + k] * invd * WlS[k][d] + h[row * 16 + k] * WrS[k][d];
    y[(long long)row * 128 + d] = ftanh(s);
}

// ---------------- stage-1 CSR gather-aggregate (fp32 out) ----------------
__global__ __launch_bounds__(256) void k_aggf0(
    const float* __restrict__ x,
    const int* __restrict__ rowptr, const int* __restrict__ col,
    float* __restrict__ AGG, int nrowsC)
{
    int tid = threadIdx.x;
    int r = blockIdx.x * 8 + (tid >> 5);
    if (r >= nrowsC) return;
    int lane = tid & 31;
    int b = rowptr[r], e = rowptr[r + 1];
    float4 a = *reinterpret_cast<const float4*>(x + (long long)r * 128 + lane * 4);
    float dsum = 1.0f + (float)(e - b);
    for (int q = b; q < e; ++q) {
        int s = col[q];
        float4 v = *reinterpret_cast<const float4*>(x + (long long)s * 128 + lane * 4);
        a.x += v.x; a.y += v.y; a.z += v.z; a.w += v.w;
    }
    float invds = 1.0f / fmaxf(dsum, 1.0f);
    a.x *= invds; a.y *= invds; a.z *= invds; a.w *= invds;
    *reinterpret_cast<float4*>(AGG + (long long)r * 128 + lane * 4) = a;
}

// ---------------- stage-2 CSR gather-aggregate (bf16 in/out, alive-compacted) ----------------
__global__ __launch_bounds__(256) void k_aggf2(
    const unsigned short* __restrict__ x,
    const int* __restrict__ rowptr, const int* __restrict__ col,
    const int* __restrict__ aliveIdx, const float* __restrict__ nal, const float* __restrict__ fvec,
    int rowbase,
    unsigned short* __restrict__ AGGb, int nrowsC)
{
    int tid = threadIdx.x;
    int r = blockIdx.x * 8 + (tid >> 5);
    if (r >= nrowsC) return;
    int lane = tid & 31;
    int orig = aliveIdx[r];
    int grow = rowbase + orig;
    int b = rowptr[grow], e = rowptr[grow + 1];
    float4 a = make_float4(0.0f, 0.0f, 0.0f, 0.0f);
    float dsum = 0.0f;
    for (int q = b; q < e; ++q) {
        int fr = col[q] - rowbase;
        if (nal[fr] == 0.0f) continue;
        dsum += 1.0f;
        float fw = fvec[fr];
        if (fw == 0.0f) continue;
        ushort4 v = *reinterpret_cast<const ushort4*>(x + (long long)fr * 128 + lane * 4);
        a.x += bf2f(v.x) * fw; a.y += bf2f(v.y) * fw;
        a.z += bf2f(v.z) * fw; a.w += bf2f(v.w) * fw;
    }
    float invds = 1.0f / fmaxf(dsum, 1.0f);
    ushort4 o;
    o.x = f2bf(a.x * invds); o.y = f2bf(a.y * invds);
    o.z = f2bf(a.z * invds); o.w = f2bf(a.w * invds);
    *reinterpret_cast<ushort4*>(AGGb + (long long)r * 128 + lane * 4) = o;
}

// ---------------- dense SAGE GEMM (fp32 v2 tile) — stage-1 only ----------------
__global__ __launch_bounds__(256) void k_sage_d(
    const float* __restrict__ AGG, const float* __restrict__ xsrc,
    const float* __restrict__ Wl, const float* __restrict__ Wr, const float* __restrict__ bl,
    float* __restrict__ y, int nrowsC,
    const float* __restrict__ gw, float* __restrict__ gdot)
{
    __shared__ float Ws[32 * 128];
    __shared__ float Is[32][68];
    __shared__ float gwS[128];
    int tid = threadIdx.x;
    long long row0 = (long long)blockIdx.x * 64;
    if (tid < 128 && gw) gwS[tid] = gw[tid];
    __syncthreads();
    int tx = tid & 31, ty = tid >> 5;
    float gg4[4] = {0,0,0,0};
    if (gw) { gg4[0]=gwS[tx*4]; gg4[1]=gwS[tx*4+1]; gg4[2]=gwS[tx*4+2]; gg4[3]=gwS[tx*4+3]; }
    int srow = tid & 63;
    int koff = (tid >> 6) * 8;
    long long crow = row0 + srow;
    if (crow >= nrowsC) crow = nrowsC - 1;
    const float* selfp = xsrc + crow * 128;
    const float* aggp = AGG + crow * 128;

    float acc[8][4] = {};
    for (int kb = 0; kb < 8; ++kb) {
        __syncthreads();
        bool isAgg = (kb < 4);
        const float* Wsrc = isAgg ? (Wl + kb * 32 * 128) : (Wr + (kb - 4) * 32 * 128);
        #pragma unroll
        for (int j = 0; j < 4; ++j) {
            int fl = j * 1024 + tid * 4;
            *reinterpret_cast<float4*>(&Ws[fl]) = *reinterpret_cast<const float4*>(&Wsrc[fl]);
        }
        {
            const float* sp = (isAgg ? (aggp + kb * 32) : (selfp + (kb - 4) * 32)) + koff;
            float4 v0 = *reinterpret_cast<const float4*>(sp);
            float4 v1 = *reinterpret_cast<const float4*>(sp + 4);
            Is[koff + 0][srow] = v0.x; Is[koff + 1][srow] = v0.y;
            Is[koff + 2][srow] = v0.z; Is[koff + 3][srow] = v0.w;
            Is[koff + 4][srow] = v1.x; Is[koff + 5][srow] = v1.y;
            Is[koff + 6][srow] = v1.z; Is[koff + 7][srow] = v1.w;
        }
        __syncthreads();
        #pragma unroll
        for (int kk = 0; kk < 32; ++kk) {
            float4 wv = *reinterpret_cast<const float4*>(&Ws[kk * 128 + tx * 4]);
            float4 i0 = *reinterpret_cast<const float4*>(&Is[kk][ty * 8]);
            float4 i1 = *reinterpret_cast<const float4*>(&Is[kk][ty * 8 + 4]);
            float ia[8] = {i0.x, i0.y, i0.z, i0.w, i1.x, i1.y, i1.z, i1.w};
            float wa[4] = {wv.x, wv.y, wv.z, wv.w};
            #pragma unroll
            for (int i = 0; i < 8; ++i)
                #pragma unroll
                for (int j = 0; j < 4; ++j)
                    acc[i][j] += ia[i] * wa[j];
        }
    }
    float4 bl0 = *reinterpret_cast<const float4*>(&bl[tx * 4]);
    float br[4] = {bl0.x, bl0.y, bl0.z, bl0.w};
    #pragma unroll
    for (int i = 0; i < 8; ++i) {
        long long row = row0 + ty * 8 + i;
        bool valid = (row < nrowsC);
        float yv[4];
        #pragma unroll
        for (int j = 0; j < 4; ++j) yv[j] = ftanh(acc[i][j] + br[j]);
        if (valid)
            *reinterpret_cast<float4*>(&y[row * 128 + tx * 4]) = make_float4(yv[0], yv[1], yv[2], yv[3]);
        float gp = 0.0f;
        #pragma unroll
        for (int j = 0; j < 4; ++j) if (gdot) gp += yv[j] * gg4[j];
        #pragma unroll
        for (int m = 16; m >= 1; m >>= 1) if (gdot) gp += __shfl_xor(gp, m, 32);
        if (tx == 0 && valid && gdot) gdot[row] = gp;
    }
}

// ---------------- bf16 weight pack ----------------
__global__ void k_packW(const float* __restrict__ Wl, const float* __restrict__ Wr,
                        short* __restrict__ Wb) {
    int i = blockIdx.x * 256 + threadIdx.x;
    if (i >= 32768) return;
    int kt = i >> 12, rem = i & 4095;
    int ct = rem >> 9; rem &= 511;
    int lane = rem >> 3, e = rem & 7;
    int k = kt * 32 + (lane >> 4) * 8 + e;
    int c = ct * 16 + (lane & 15);
    float v = (k < 128) ? Wl[k * 128 + c] : Wr[(k - 128) * 128 + c];
    Wb[i] = (short)f2bf(v);
}

// ---------------- MFMA SAGE GEMM (stage-2 L1/L2): 16 rows/wave, 64 rows/block ----------------
__global__ __launch_bounds__(256) void k_sage_m(
    const unsigned short* __restrict__ AGGb, const unsigned short* __restrict__ X,
    const int* __restrict__ aliveIdx, const float* __restrict__ fvec,
    const short* __restrict__ Wb, const float* __restrict__ bl,
    unsigned short* __restrict__ y, int nrowsC,
    const float* __restrict__ wrel, const float* __restrict__ wroot, const float* __restrict__ gw,
    float* __restrict__ tbuf, float* __restrict__ rootd, float* __restrict__ gdot)
{
    __shared__ short8 lB[2048];
    int tid = threadIdx.x;
    int lane = tid & 63;
    int wv = tid >> 6;
    long long rows0 = (long long)blockIdx.x * 64 + wv * 16;
    int arow = lane & 15;
    int ksl = (lane >> 4) * 8;

    int growA = (int)(rows0 + arow);
    int origA = aliveIdx[growA];
    float fsA = fvec[origA];

    f32x4 acc[8] = {};
    const short8* Wbv = (const short8*)Wb;

    for (int half = 0; half < 2; ++half) {
        __syncthreads();
        #pragma unroll
        for (int i = 0; i < 8; ++i) {
            int idx = i * 256 + tid;
            lB[idx] = Wbv[half * 2048 + idx];
        }
        __syncthreads();
        #pragma unroll
        for (int ktl = 0; ktl < 4; ++ktl) {
            int kt = half * 4 + ktl;
            short8 afr;
            if (kt < 4) {
                afr = *reinterpret_cast<const short8*>(AGGb + (long long)growA * 128 + kt * 32 + ksl);
            } else {
                short8 xv = *reinterpret_cast<const short8*>(X + (long long)origA * 128 + (kt - 4) * 32 + ksl);
                #pragma unroll
                for (int e = 0; e < 8; ++e)
                    afr[e] = (short)f2bf(bf2f((unsigned short)xv[e]) * fsA);
            }
            #pragma unroll
            for (int ct = 0; ct < 8; ++ct) {
                short8 bfr = lB[(ktl * 8 + ct) * 64 + lane];
                acc[ct] = __builtin_amdgcn_mfma_f32_16x16x32_bf16(afr, bfr, acc[ct], 0, 0, 0);
            }
        }
    }

    int ocol = lane & 15;
    float blv[8], wrv[8], wov[8], ggv[8];
    #pragma unroll
    for (int ct = 0; ct < 8; ++ct) {
        int c = ct * 16 + ocol;
        blv[ct] = bl[c];
        wrv[ct] = wrel[c];
        wov[ct] = wroot[c];
        ggv[ct] = gw[c];
    }
    #pragma unroll
    for (int j = 0; j < 4; ++j) {
        int rloc = (lane >> 4) * 4 + j;
        long long grow = rows0 + rloc;
        int orig = aliveIdx[grow];
        float tp = 0.0f, rp = 0.0f, gp = 0.0f;
        #pragma unroll
        for (int ct = 0; ct < 8; ++ct) {
            float v = ftanh(acc[ct][j] + blv[ct]);
            y[(long long)orig * 128 + ct * 16 + ocol] = f2bf(v);
            tp += v * wrv[ct]; rp += v * wov[ct]; gp += v * ggv[ct];
        }
        #pragma unroll
        for (int mm = 8; mm >= 1; mm >>= 1) {
            tp += __shfl_xor(tp, mm, 16);
            rp += __shfl_xor(rp, mm, 16);
            gp += __shfl_xor(gp, mm, 16);
        }
        if (ocol == 0) { tbuf[orig] = tp; rootd[orig] = rp; gdot[orig] = gp; }
    }
}

// ---------------- plain GEMM: y = x@W (+ b), v2 tile ----------------
__global__ __launch_bounds__(256) void k_gemm_self(
    const float* __restrict__ x, const float* __restrict__ W, const float* __restrict__ b,
    float* __restrict__ y, int nrows)
{
    __shared__ float Ws[32 * 128];
    __shared__ float Is[32][68];
    int tid = threadIdx.x;
    long long row0 = (long long)blockIdx.x * 64;
    int tx = tid & 31, ty = tid >> 5;
    int srow = tid & 63;
    int koff = (tid >> 6) * 8;
    long long lrow = row0 + srow;
    if (lrow >= nrows) lrow = nrows - 1;
    const float* xrow = x + lrow * 128;
    float acc[8][4] = {};
    for (int kb = 0; kb < 4; ++kb) {
        __syncthreads();
        const float* Wsrc = W + kb * 32 * 128;
        #pragma unroll
        for (int j = 0; j < 4; ++j) {
            int fl = j * 1024 + tid * 4;
            *reinterpret_cast<float4*>(&Ws[fl]) = *reinterpret_cast<const float4*>(&Wsrc[fl]);
        }
        {
            const float* sp = xrow + kb * 32 + koff;
            float4 v0 = *reinterpret_cast<const float4*>(sp);
            float4 v1 = *reinterpret_cast<const float4*>(sp + 4);
            Is[koff + 0][srow] = v0.x; Is[koff + 1][srow] = v0.y;
            Is[koff + 2][srow] = v0.z; Is[koff + 3][srow] = v0.w;
            Is[koff + 4][srow] = v1.x; Is[koff + 5][srow] = v1.y;
            Is[koff + 6][srow] = v1.z; Is[koff + 7][srow] = v1.w;
        }
        __syncthreads();
        #pragma unroll
        for (int kk = 0; kk < 32; ++kk) {
            float4 wv = *reinterpret_cast<const float4*>(&Ws[kk * 128 + tx * 4]);
            float4 i0 = *reinterpret_cast<const float4*>(&Is[kk][ty * 8]);
            float4 i1 = *reinterpret_cast<const float4*>(&Is[kk][ty * 8 + 4]);
            float ia[8] = {i0.x, i0.y, i0.z, i0.w, i1.x, i1.y, i1.z, i1.w};
            float wa[4] = {wv.x, wv.y, wv.z, wv.w};
            #pragma unroll
            for (int i = 0; i < 8; ++i)
                #pragma unroll
                for (int j = 0; j < 4; ++j)
                    acc[i][j] += ia[i] * wa[j];
        }
    }
    float4 b0 = b ? *reinterpret_cast<const float4*>(&b[tx * 4]) : make_float4(0.f, 0.f, 0.f, 0.f);
    #pragma unroll
    for (int i = 0; i < 8; ++i) {
        long long row = row0 + ty * 8 + i;
        if (row >= nrows) continue;
        *reinterpret_cast<float4*>(&y[row * 128 + tx * 4]) =
            make_float4(acc[i][0] + b0.x, acc[i][1] + b0.y, acc[i][2] + b0.z, acc[i][3] + b0.w);
    }
}

// ---------------- stage-2 L0 combine (bf16 X out) ----------------
__global__ __launch_bounds__(256) void k_l0comb(
    const float* __restrict__ ZL0, const float* __restrict__ zself,
    const int* __restrict__ rowptr, const int* __restrict__ col, int rowbase,
    const float* __restrict__ wrel, const float* __restrict__ wroot, const float* __restrict__ gw,
    unsigned short* __restrict__ y, float* __restrict__ tbuf, float* __restrict__ rootd, float* __restrict__ gdot,
    int nrowsC)
{
    __shared__ float wrelS[128], wrootS[128], gwS[128];
    int tid = threadIdx.x;
    if (tid < 128) {
        wrelS[tid]  = wrel[tid];
        wrootS[tid] = wroot[tid];
        gwS[tid]    = gw[tid];
    }
    __syncthreads();
    int r = blockIdx.x * 8 + (tid >> 5);
    if (r >= nrowsC) return;
    int lane = tid & 31;
    int grow = rowbase + r;
    int b = rowptr[grow], e = rowptr[grow + 1];
    float4 a = make_float4(0.0f, 0.0f, 0.0f, 0.0f);
    for (int q = b; q < e; ++q) {
        int fr = col[q] % NN;
        float4 v = *reinterpret_cast<const float4*>(ZL0 + (long long)fr * 128 + lane * 4);
        a.x += v.x; a.y += v.y; a.z += v.z; a.w += v.w;
    }
    float invds = 1.0f / fmaxf((float)(e - b), 1.0f);
    const float4 z = *reinterpret_cast<const float4*>(zself + (long long)(r % NN) * 128 + lane * 4);
    float yv[4];
    yv[0] = ftanh(a.x * invds + z.x);
    yv[1] = ftanh(a.y * invds + z.y);
    yv[2] = ftanh(a.z * invds + z.z);
    yv[3] = ftanh(a.w * invds + z.w);
    ushort4 o;
    o.x = f2bf(yv[0]); o.y = f2bf(yv[1]); o.z = f2bf(yv[2]); o.w = f2bf(yv[3]);
    *reinterpret_cast<ushort4*>(y + (long long)r * 128 + lane * 4) = o;
    float tp = 0.0f, rp = 0.0f, gp = 0.0f;
    #pragma unroll
    for (int j = 0; j < 4; ++j) {
        tp += yv[j] * wrelS[lane*4 + j];
        rp += yv[j] * wrootS[lane*4 + j];
        gp += yv[j] * gwS[lane*4 + j];
    }
    #pragma unroll
    for (int m = 16; m >= 1; m >>= 1) {
        tp += __shfl_xor(tp, m, 32);
        rp += __shfl_xor(rp, m, 32);
        gp += __shfl_xor(gp, m, 32);
    }
    if (lane == 0) {
        tbuf[r]  = tp;
        rootd[r] = rp;
        gdot[r]  = gp;
    }
}

// ---------------- stage-1 readout pieces ----------------
__global__ __launch_bounds__(256) void k_gate(
    const float* __restrict__ X, const float* __restrict__ gw,
    float* __restrict__ g, int nrows)
{
    __shared__ float wS[128];
    if (threadIdx.x < 128) wS[threadIdx.x] = gw[threadIdx.x];
    __syncthreads();
    int i = blockIdx.x * 256 + threadIdx.x;
    if (i >= nrows) return;
    const float4* xrp = reinterpret_cast<const float4*>(X + (long long)i * 128);
    float s = 0.0f;
    #pragma unroll
    for (int k = 0; k < 32; ++k) {
        float4 v = xrp[k];
        s += v.x * wS[4*k] + v.y * wS[4*k+1] + v.z * wS[4*k+2] + v.w * wS[4*k+3];
    }
    g[i] = s;
}

__global__ __launch_bounds__(1024) void k_smstats(float* __restrict__ g, float* __restrict__ invp) {
    __shared__ float red[1024];
    int p = blockIdx.x, tid = threadIdx.x;
    float* gp = g + (long long)p * NN;
    float lmax = -INFINITY;
    for (int n = tid; n < NN; n += 1024) lmax = fmaxf(lmax, gp[n]);
    red[tid] = lmax; __syncthreads();
    for (int s = 512; s > 0; s >>= 1) { if (tid < s) red[tid] = fmaxf(red[tid], red[tid + s]); __syncthreads(); }
    float mx = red[0]; __syncthreads();
    float ls = 0.0f;
    for (int n = tid; n < NN; n += 1024) { float e = __expf(gp[n] - mx); gp[n] = e; ls += e; }
    red[tid] = ls; __syncthreads();
    for (int s = 512; s > 0; s >>= 1) { if (tid < s) red[tid] += red[tid + s]; __syncthreads(); }
    if (tid == 0) invp[p] = 1.0f / red[0];
}

__global__ __launch_bounds__(128) void k_wsum(
    const float* __restrict__ X, const float* __restrict__ a,
    const float* __restrict__ invp, float* __restrict__ ro, int rowbase, int colOff)
{
    int p = blockIdx.x / BPG;
    int chunk = blockIdx.x % BPG;
    int d = threadIdx.x;
    long long base = (long long)p * NN;
    int r0 = chunk * RB, r1 = r0 + RB;
    float s = 0.0f;
    for (int n = r0; n < r1; ++n) {
        float w = a[base + n];
        if (w != 0.0f) s += w * X[(base + n) * 128 + d];
    }
    atomicAdd(&ro[(long long)(rowbase + p) * 384 + colOff + d], s * invp[p]);
}

// stage-2 weighted sum over alive rows only (bf16 X)
__global__ __launch_bounds__(128) void k_wsum_c(
    const unsigned short* __restrict__ X, const float* __restrict__ gbuf, const float* __restrict__ fvec,
    const float* __restrict__ invp, const int* __restrict__ aliveIdx, int k,
    float* __restrict__ ro, int rowbaseRo, int colOff)
{
    int bpp = k / RB;
    int p = blockIdx.x / bpp;
    int chunk = blockIdx.x % bpp;
    int d = threadIdx.x;
    const int* ai = aliveIdx + (long long)p * k + chunk * RB;
    float s = 0.0f;
    for (int j = 0; j < RB; ++j) {
        int row = ai[j];
        float w = gbuf[row] * fvec[row];
        s += w * bf2f(X[(long long)row * 128 + d]);
    }
    atomicAdd(&ro[(long long)(rowbaseRo + p) * 384 + colOff + d], s * invp[p]);
}

// ---------------- GraphNorm ----------------
__global__ void k_colstat(const float* __restrict__ x, float* __restrict__ musum,
                          float* __restrict__ sqsum, int nrows) {
    int d = threadIdx.x;
    int r0 = blockIdx.x * 64;
    int r1 = min(r0 + 64, nrows);
    float s = 0.0f, q = 0.0f;
    for (int r = r0; r < r1; ++r) { float v = x[(long long)r * 128 + d]; s += v; q += v * v; }
    atomicAdd(&musum[d], s);
    atomicAdd(&sqsum[d], q);
}

__global__ void k_gnorm_apply(const float* __restrict__ x, float* __restrict__ y,
                              const float* __restrict__ musum, const float* __restrict__ sqsum,
                              const float* __restrict__ w, const float* __restrict__ b,
                              const float* __restrict__ ms, int nrows) {
    long long i = (long long)blockIdx.x * 256 + threadIdx.x;
    if (i >= (long long)nrows * 128) return;
    int d = (int)(i & 127);
    float inv_n = 1.0f / (float)nrows;
    float mu = musum[d] * inv_n;
    float c = mu * ms[d];
    float var = sqsum[d] * inv_n - 2.0f * c * mu + c * c;
    y[i] = w[d] * (x[i] - c) * rsqrtf(var + 1e-5f) + b[d];
}

// ---------------- mega top-k (1024 threads, parallel bucket select) ----------------
#define TCH 8
__global__ __launch_bounds__(1024) void k_topk2(
    const int* __restrict__ rowptr, const int* __restrict__ col, int rowbase,
    const float* __restrict__ tb, const float* __restrict__ rootd,
    const float* __restrict__ gdot, const float* __restrict__ brelp, int bi, int allAlive,
    float* __restrict__ nalive, float* __restrict__ fvec, float* __restrict__ gbuf,
    float* __restrict__ invp, int* __restrict__ aliveIdx, int k)
{
    __shared__ unsigned keys[NN];
    __shared__ int hist[256];
    __shared__ int scan[1024];
    __shared__ float redf[1024];
    __shared__ unsigned sh_pref;
    __shared__ int sh_kneed;
    int p = blockIdx.x, tid = threadIdx.x;
    float brel = brelp[bi];
    long long pbase = (long long)p * NN;
    for (int n = tid; n < NN; n += 1024) {
        long long gl = pbase + n;
        int grow = rowbase + (int)gl;
        float s = brel + rootd[gl];
        int b = rowptr[grow], e = rowptr[grow + 1];
        for (int q = b; q < e; ++q) {
            int sl = col[q] - rowbase;
            s += allAlive ? tb[sl] : (tb[sl] * nalive[sl]);
        }
        bool alive = allAlive || (nalive[gl] > 0.5f);
        keys[n] = alive ? fkey(s) : 0u;
    }
    if (tid == 0) { sh_pref = 0u; sh_kneed = k; }
    __syncthreads();
    for (int lvl = 3; lvl >= 0; --lvl) {
        int sh = lvl * 8;
        if (tid < 256) hist[tid] = 0;
        unsigned pref = sh_pref; int kneed = sh_kneed;
        unsigned pmask = (lvl == 3) ? 0u : (0xFFFFFFFFu << (8 * (lvl + 1)));
        __syncthreads();
        for (int n = tid; n < NN; n += 1024) {
            unsigned kv = keys[n];
            if ((kv & pmask) == pref) atomicAdd(&hist[(kv >> sh) & 255], 1);
        }
        __syncthreads();
        if (tid < 256) scan[tid] = hist[tid];
        __syncthreads();
        for (int off = 1; off < 256; off <<= 1) {
            int v = 0;
            if (tid < 256 && tid + off < 256) v = scan[tid + off];
            __syncthreads();
            if (tid < 256) scan[tid] += v;
            __syncthreads();
        }
        if (tid < 256) {
            int c = scan[tid];
            int cex = c - hist[tid];
            if (c >= kneed && cex < kneed) {
                sh_pref = pref | ((unsigned)tid << sh);
                sh_kneed = kneed - cex;
            }
        }
        __syncthreads();
    }
    unsigned V = sh_pref;
    int seleq = sh_kneed;
    int c0 = tid * TCH, c1 = min(c0 + TCH, NN);
    int ceq = 0;
    for (int n = c0; n < c1; ++n) ceq += (keys[n] == V) ? 1 : 0;
    scan[tid] = ceq; __syncthreads();
    for (int off = 1; off < 1024; off <<= 1) {
        int u = (tid >= off) ? scan[tid - off] : 0;
        __syncthreads();
        scan[tid] += u;
        __syncthreads();
    }
    int rank = scan[tid] - ceq;
    unsigned selmask = 0u;
    int nsel = 0;
    float lmax = -INFINITY;
    for (int n = c0; n < c1; ++n) {
        unsigned kk = keys[n];
        bool sel = (kk > V) || (kk == V && rank < seleq);
        if (kk == V) rank++;
        long long gl = pbase + n;
        nalive[gl] = sel ? 1.0f : 0.0f;
        float f = 0.0f;
        if (sel) {
            f = ftanh(fkey_inv(kk));
            lmax = fmaxf(lmax, f * gdot[gl]);
            selmask |= (1u << (n - c0));
            ++nsel;
        }
        fvec[gl] = f;
    }
    redf[tid] = lmax; __syncthreads();
    for (int s = 512; s > 0; s >>= 1) { if (tid < s) redf[tid] = fmaxf(redf[tid], redf[tid + s]); __syncthreads(); }
    float mx = redf[0]; __syncthreads();
    scan[tid] = nsel; __syncthreads();
    for (int off = 1; off < 1024; off <<= 1) {
        int u = (tid >= off) ? scan[tid - off] : 0;
        __syncthreads();
        scan[tid] += u;
        __syncthreads();
    }
    int pos = scan[tid] - nsel;
    float lsum = 0.0f;
    for (int n = c0; n < c1; ++n) {
        if (selmask & (1u << (n - c0))) {
            long long gl = pbase + n;
            float e = __expf(fvec[gl] * gdot[gl] - mx);
            gbuf[gl] = e;
            lsum += e;
            aliveIdx[(long long)p * k + pos] = (int)gl;
            ++pos;
        }
    }
    redf[tid] = lsum; __syncthreads();
    for (int s = 512; s > 0; s >>= 1) { if (tid < s) redf[tid] += redf[tid + s]; __syncthreads(); }
    if (tid == 0) invp[p] = 1.0f / redf[0];
}

// ---------------- head ----------------
__global__ __launch_bounds__(64) void k_head(
    const float* __restrict__ ro, const float* __restrict__ lin_w, const float* __restrict__ lin_b,
    const float* __restrict__ m1w, const float* __restrict__ m1b,
    const float* __restrict__ m2w, const float* __restrict__ m2b,
    const float* __restrict__ m3w, const float* __restrict__ m3b, float* __restrict__ out)
{
    __shared__ float v[33], h1[48], h2[16];
    int t = threadIdx.x;
    if (t < 33) {
        float s = lin_b[0];
        for (int k = 0; k < 384; ++k) s += ro[t * 384 + k] * lin_w[k];
        v[t] = tanhf(s);
    }
    __syncthreads();
    if (t < 48) {
        float s = m1b[t];
        for (int i = 0; i < 33; ++i) s += v[i] * m1w[i * 48 + t];
        h1[t] = tanhf(s);
    }
    __syncthreads();
    if (t < 16) {
        float s = m2b[t];
        for (int i = 0; i < 48; ++i) s += h1[i] * m2w[i * 16 + t];
        h2[t] = tanhf(s);
    }
    __syncthreads();
    if (t == 0) {
        float s = m3b[0];
        for (int i = 0; i < 16; ++i) s += h2[i] * m3w[i];
        float s1 = 1.0f / (1.0f + expf(-s));
        out[0] = 1.0f / (1.0f + expf(-s1));
    }
}

static inline int cdiv(long long a, long long b) { return (int)((a + b - 1) / b); }

extern "C" void kernel_launch(void* const* d_in, const int* in_sizes, int n_in,
                              void* d_out, int out_size, void* d_ws, size_t ws_size,
                              hipStream_t stream)
{
    (void)in_sizes; (void)n_in; (void)out_size;
    const float* h     = (const float*)d_in[0];
    const int*   eidx  = (const int*)d_in[1];
    const int*   seidx = (const int*)d_in[2];
    const float* Wl_a  = (const float*)d_in[3];
    const float* Wr_a  = (const float*)d_in[4];
    const float* bl_a  = (const float*)d_in[5];
    const float* Wl_s  = (const float*)d_in[6];
    const float* Wr_s  = (const float*)d_in[7];
    const float* bl_s  = (const float*)d_in[8];
    const float* gate_w = (const float*)d_in[9];
    const float* p_wrel = (const float*)d_in[11];
    const float* p_brel = (const float*)d_in[12];
    const float* p_wroot= (const float*)d_in[13];
    const float* nw    = (const float*)d_in[14];
    const float* nb    = (const float*)d_in[15];
    const float* nms   = (const float*)d_in[16];
    const float* lin_w = (const float*)d_in[17];
    const float* lin_b = (const float*)d_in[18];
    const float* m1w   = (const float*)d_in[19];
    const float* m1b   = (const float*)d_in[20];
    const float* m2w   = (const float*)d_in[21];
    const float* m2b   = (const float*)d_in[22];
    const float* m3w   = (const float*)d_in[23];
    const float* m3b   = (const float*)d_in[24];
    float* out = (float*)d_out;

    const int* esrc = eidx;
    const int* edst = eidx + EG;
    const int* ssrc = seidx;
    const int* sdst = seidx + ES_TOT;

    auto need_bytes = [](int chp) -> size_t {
        long long chn = (long long)chp * NN;
        long long f = chn * 64
                    + (long long)chp * KK1 * 64
                    + 2LL * NN * 128
                    + 5 * chn
                    + 64 + 33 * 384
                    + (long long)chp * KK1
                    + (PN + 1) + ES_TOT
                    + 2 * 16384
                    + 64 * 24;
        return (size_t)f * 4;
    };
    int chp = 8;
    if (ws_size >= need_bytes(32)) chp = 32;
    else if (ws_size >= need_bytes(16)) chp = 16;
    int nch = PP / chp;
    long long ch_n = (long long)chp * NN;

    float* W = (float*)d_ws;
    size_t off = 0;
    auto alloc = [&](size_t nf) { float* p = W + off; off += (nf + 63) & ~(size_t)63; return p; };
    unsigned short* XAb = (unsigned short*)alloc((size_t)ch_n * 64);
    unsigned short* AGGb = (unsigned short*)alloc((size_t)chp * KK1 * 64);
    float* ZL0   = alloc((size_t)NN * DD);
    float* zself = alloc((size_t)NN * DD);
    float* tbuf  = alloc(ch_n);
    float* rootd = alloc(ch_n);
    float* nal   = alloc(ch_n);
    float* fvec  = alloc(ch_n);
    float* gdot  = alloc(ch_n);
    float* invp  = alloc(64);
    float* ro    = alloc(33 * 384);
    int* aliveIdx = (int*)alloc((size_t)chp * KK1);
    int* s2rp    = (int*)alloc(PN + 1);
    int* s2col   = (int*)alloc(ES_TOT);
    short* Wb1   = (short*)alloc(16384);
    short* Wb2   = (short*)alloc(16384);
    float* gbuf = tbuf;

    // overlay inside XAb (dead before XAb's first write)
    float* XO = (float*)XAb;
    size_t ooff = 0;
    auto oalloc = [&](size_t nf) { float* p = XO + ooff; ooff += (nf + 63) & ~(size_t)63; return p; };
    float* xa    = oalloc((size_t)NN * DD);
    float* xb    = oalloc((size_t)NN * DD);
    float* AGGs  = oalloc((size_t)NN * DD);
    float* agg1  = oalloc((size_t)NN * 16);
    float* deg1  = oalloc(NN);
    float* musum = oalloc(128);
    float* sqsum = oalloc(128);
    int* s1cnt  = (int*)oalloc(NN);
    int* s1rp   = (int*)oalloc(NN + 1);
    int* s1cur  = (int*)oalloc(NN);
    int* s1col  = (int*)oalloc(EG);
    int* s1part = (int*)oalloc(NN);
    int* s1bsum = (int*)oalloc(1024);
    int* s2cnt  = (int*)oalloc(PN);
    int* s2cur  = (int*)oalloc(PN);
    int* s2part = (int*)oalloc(PN);
    int* s2bsum = (int*)oalloc(1024);

    // ---------- CSR builds ----------
    int nb1 = cdiv(NN, 1024), nb2 = cdiv(PN, 1024);
    hipMemsetAsync(s1cnt, 0, NN * sizeof(int), stream);
    k_hist<<<cdiv(EG,256),256,0,stream>>>(edst, s1cnt, EG);
    k_scanA<<<nb1,1024,0,stream>>>(s1cnt, s1part, s1bsum, NN);
    k_scanB<<<1,1024,0,stream>>>(s1bsum, nb1);
    k_scanC<<<cdiv(NN,256),256,0,stream>>>(s1part, s1bsum, s1rp, s1cur, NN, EG);
    k_scatter<<<cdiv(EG,256),256,0,stream>>>(esrc, edst, s1cur, s1col, EG);

    hipMemsetAsync(s2cnt, 0, (size_t)PN * sizeof(int), stream);
    k_hist<<<cdiv(ES_TOT,256),256,0,stream>>>(sdst, s2cnt, ES_TOT);
    k_scanA<<<nb2,1024,0,stream>>>(s2cnt, s2part, s2bsum, PN);
    k_scanB<<<1,1024,0,stream>>>(s2bsum, nb2);
    k_scanC<<<cdiv(PN,256),256,0,stream>>>(s2part, s2bsum, s2rp, s2cur, PN, ES_TOT);
    k_scatter<<<cdiv(ES_TOT,256),256,0,stream>>>(ssrc, sdst, s2cur, s2col, ES_TOT);

    hipMemsetAsync(ro, 0, 33 * 384 * sizeof(float), stream);

    k_packW<<<128,256,0,stream>>>(Wl_s + 3*16384, Wr_s + 3*16384, Wb1);
    k_packW<<<128,256,0,stream>>>(Wl_s + 4*16384, Wr_s + 4*16384, Wb2);

    // ---------- stage 1 ----------
    k_agg16<<<cdiv((long long)NN*16,256),256,0,stream>>>(h, s1rp, s1col, agg1, deg1, NN);
    k_sage16<<<cdiv((long long)NN*DD,256),256,0,stream>>>(h, agg1, deg1, Wl_a, Wr_a, bl_a, xa, NN);
    k_gate<<<cdiv(NN,256),256,0,stream>>>(xa, gate_w + 0*DD, gbuf, NN);
    k_smstats<<<1,1024,0,stream>>>(gbuf, invp);
    k_wsum<<<BPG,128,0,stream>>>(xa, gbuf, invp, ro, 0, 0);

    hipMemsetAsync(musum, 0, 128*sizeof(float), stream);
    hipMemsetAsync(sqsum, 0, 128*sizeof(float), stream);
    k_colstat<<<cdiv(NN,64),128,0,stream>>>(xa, musum, sqsum, NN);
    k_gnorm_apply<<<cdiv((long long)NN*DD,256),256,0,stream>>>(xa, xb, musum, sqsum, nw, nb, nms, NN);

    k_aggf0<<<cdiv(NN,8),256,0,stream>>>(xb, s1rp, s1col, AGGs, NN);
    k_sage_d<<<cdiv(NN,64),256,0,stream>>>(AGGs, xb,
        Wl_s + 0*16384, Wr_s + 0*16384, bl_s + 0*128, xa, NN,
        gate_w + 1*DD, gbuf);
    k_smstats<<<1,1024,0,stream>>>(gbuf, invp);
    k_wsum<<<BPG,128,0,stream>>>(xa, gbuf, invp, ro, 0, 128);

    hipMemsetAsync(musum, 0, 128*sizeof(float), stream);
    hipMemsetAsync(sqsum, 0, 128*sizeof(float), stream);
    k_colstat<<<cdiv(NN,64),128,0,stream>>>(xa, musum, sqsum, NN);
    k_gnorm_apply<<<cdiv((long long)NN*DD,256),256,0,stream>>>(xa, xb, musum, sqsum, nw, nb, nms, NN);

    k_aggf0<<<cdiv(NN,8),256,0,stream>>>(xb, s1rp, s1col, AGGs, NN);
    k_sage_d<<<cdiv(NN,64),256,0,stream>>>(AGGs, xb,
        Wl_s + 1*16384, Wr_s + 1*16384, bl_s + 1*128, xa, NN,
        gate_w + 2*DD, gbuf);
    k_smstats<<<1,1024,0,stream>>>(gbuf, invp);
    k_wsum<<<BPG,128,0,stream>>>(xa, gbuf, invp, ro, 0, 256);

    // ---------- stage 2 ----------
    k_gemm_self<<<cdiv(NN,64),256,0,stream>>>(xa, Wl_s + 2*16384, nullptr, ZL0, NN);
    k_gemm_self<<<cdiv(NN,64),256,0,stream>>>(xa, Wr_s + 2*16384, bl_s + 2*128, zself, NN);

    for (int c = 0; c < nch; ++c) {
        int nbase = (int)(c * ch_n);

        k_l0comb<<<(int)(ch_n/8),256,0,stream>>>(ZL0, zself, s2rp, s2col, nbase,
            p_wrel + 0*DD, p_wroot + 0*DD, gate_w + 3*DD,
            XAb, tbuf, rootd, gdot, (int)ch_n);
        k_topk2<<<chp,1024,0,stream>>>(s2rp, s2col, nbase, tbuf, rootd, gdot, p_brel, 0, 1,
                                       nal, fvec, gbuf, invp, aliveIdx, KK1);
        k_wsum_c<<<chp*(KK1/RB),128,0,stream>>>(XAb, gbuf, fvec, invp, aliveIdx, KK1, ro, 1 + c*chp, 0);

        k_aggf2<<<chp*(KK1/8),256,0,stream>>>(XAb, s2rp, s2col, aliveIdx, nal, fvec, nbase, AGGb, chp*KK1);
        k_sage_m<<<chp*(KK1/64),256,0,stream>>>(AGGb, XAb, aliveIdx, fvec, Wb1, bl_s + 3*128, XAb, chp*KK1,
            p_wrel + 1*DD, p_wroot + 1*DD, gate_w + 4*DD, tbuf, rootd, gdot);
        k_topk2<<<chp,1024,0,stream>>>(s2rp, s2col, nbase, tbuf, rootd, gdot, p_brel, 1, 0,
                                       nal, fvec, gbuf, invp, aliveIdx, KK2);
        k_wsum_c<<<chp*(KK2/RB),128,0,stream>>>(XAb, gbuf, fvec, invp, aliveIdx, KK2, ro, 1 + c*chp, 128);

        k_aggf2<<<chp*(KK2/8),256,0,stream>>>(XAb, s2rp, s2col, aliveIdx, nal, fvec, nbase, AGGb, chp*KK2);
        k_sage_m<<<chp*(KK2/64),256,0,stream>>>(AGGb, XAb, aliveIdx, fvec, Wb2, bl_s + 4*128, XAb, chp*KK2,
            p_wrel + 2*DD, p_wroot + 2*DD, gate_w + 5*DD, tbuf, rootd, gdot);
        k_topk2<<<chp,1024,0,stream>>>(s2rp, s2col, nbase, tbuf, rootd, gdot, p_brel, 2, 0,
                                       nal, fvec, gbuf, invp, aliveIdx, KK3);
        k_wsum_c<<<chp*(KK3/RB),128,0,stream>>>(XAb, gbuf, fvec, invp, aliveIdx, KK3, ro, 1 + c*chp, 256);
    }

    // ---------- head ----------
    k_head<<<1,64,0,stream>>>(ro, lin_w, lin_b, m1w, m1b, m2w, m2b, m3w, m3b, out);
}

// Round 20
// 657.054 us; speedup vs baseline: 3.9993x; 1.0704x over previous
//
#include <hip/hip_runtime.h>
#include <math.h>

#define NN      8000
#define PP      32
#define EG      128000
#define ES_TOT  131072     // P * 4096
#define ES_P    4096
#define PN      256000     // P * NN
#define DI      16
#define DD      128
#define KK1     6400
#define KK2     5120
#define KK3     4096
#define RB      64
#define BPG     (NN / RB)

typedef __attribute__((ext_vector_type(8))) short short8;
typedef __attribute__((ext_vector_type(4))) float f32x4;

static __device__ __forceinline__ unsigned fkey(float f) {
    unsigned u = __float_as_uint(f);
    return (u & 0x80000000u) ? ~u : (u | 0x80000000u);
}
static __device__ __forceinline__ float fkey_inv(unsigned k) {
    unsigned u = (k & 0x80000000u) ? (k & 0x7FFFFFFFu) : ~k;
    return __uint_as_float(u);
}
static __device__ __forceinline__ unsigned short f2bf(float f) {
    unsigned u = __float_as_uint(f);
    u += 0x7FFFu + ((u >> 16) & 1u);   // RNE
    return (unsigned short)(u >> 16);
}
static __device__ __forceinline__ float bf2f(unsigned short b) {
    return __uint_as_float((unsigned)b << 16);
}
// tanh(x) = 1 - 2/(e^{2x}+1); hardware exp + rcp, abs err ~2e-7, correct limits.
static __device__ __forceinline__ float ftanh(float x) {
    float e = __expf(2.0f * x);
    return 1.0f - 2.0f / (e + 1.0f);
}

// ---------------- CSR build ----------------
__global__ void k_hist(const int* __restrict__ dst, int* __restrict__ cnt, int ne) {
    int e = blockIdx.x * 256 + threadIdx.x;
    if (e < ne) atomicAdd(&cnt[dst[e]], 1);
}

__global__ __launch_bounds__(1024) void k_scanA(const int* __restrict__ cnt,
                                                int* __restrict__ part,
                                                int* __restrict__ bsum, int n) {
    __shared__ int sh[1024];
    int t = threadIdx.x;
    int i = blockIdx.x * 1024 + t;
    int v = (i < n) ? cnt[i] : 0;
    sh[t] = v; __syncthreads();
    for (int off = 1; off < 1024; off <<= 1) {
        int u = (t >= off) ? sh[t - off] : 0;
        __syncthreads();
        sh[t] += u;
        __syncthreads();
    }
    if (i < n) part[i] = sh[t] - v;
    if (t == 1023) bsum[blockIdx.x] = sh[1023];
}

__global__ __launch_bounds__(1024) void k_scanB(int* __restrict__ bsum, int nb) {
    __shared__ int sh[1024];
    int t = threadIdx.x;
    int v = (t < nb) ? bsum[t] : 0;
    sh[t] = v; __syncthreads();
    for (int off = 1; off < 1024; off <<= 1) {
        int u = (t >= off) ? sh[t - off] : 0;
        __syncthreads();
        sh[t] += u;
        __syncthreads();
    }
    if (t < nb) bsum[t] = sh[t] - v;
}

__global__ void k_scanC(const int* __restrict__ part, const int* __restrict__ bsum,
                        int* __restrict__ rowptr, int* __restrict__ cursor, int n, int total) {
    int i = blockIdx.x * 256 + threadIdx.x;
    if (i < n) {
        int v = part[i] + bsum[i >> 10];
        rowptr[i] = v;
        cursor[i] = v;
    }
    if (i == 0) rowptr[n] = total;
}

__global__ void k_scatter(const int* __restrict__ src, const int* __restrict__ dst,
                          int* __restrict__ cursor, int* __restrict__ col, int ne) {
    int e = blockIdx.x * 256 + threadIdx.x;
    if (e >= ne) return;
    int pos = atomicAdd(&cursor[dst[e]], 1);
    col[pos] = src[e];
}

// ---------------- stage-1 layer a ----------------
__global__ __launch_bounds__(256) void k_agg16(const float* __restrict__ h,
                                               const int* __restrict__ rowptr,
                                               const int* __restrict__ col,
                                               float* __restrict__ agg, float* __restrict__ deg,
                                               int nrows) {
    int i = blockIdx.x * 256 + threadIdx.x;
    int r = i >> 4, j = i & 15;
    if (r >= nrows) return;
    int b = rowptr[r], e = rowptr[r + 1];
    float a = h[r * 16 + j];
    for (int q = b; q < e; ++q) a += h[col[q] * 16 + j];
    agg[r * 16 + j] = a;
    if (j == 0) deg[r] = 1.0f + (float)(e - b);
}

__global__ __launch_bounds__(256) void k_sage16(
    const float* __restrict__ h, const float* __restrict__ agg, const float* __restrict__ deg,
    const float* __restrict__ Wl, const float* __restrict__ Wr, const float* __restrict__ bl,
    float* __restrict__ y, int nrows)
{
    __shared__ float WlS[16][128], WrS[16][128];
    int tid = threadIdx.x;
    for (int i = tid; i < 16 * 128; i += 256) {
        WlS[i >> 7][i & 127] = Wl[i];
        WrS[i >> 7][i & 127] = Wr[i];
    }
    __syncthreads();
    long long o = (long long)blockIdx.x * 256 + tid;
    int row = (int)(o >> 7);
    if (row >= nrows) return;
    int d = (int)o & 127;
    float invd = 1.0f / fmaxf(deg[row], 1.0f);
    float s = bl[d];
    #pragma unroll
    for (int k = 0; k < 16; ++k)
        s += agg[row * 16 + k] * invd * WlS[k][d] + h[row * 16 + k] * WrS[k][d];
    y[(long long)row * 128 + d] = ftanh(s);
}

// ---------------- stage-1 CSR gather-aggregate (fp32 out) ----------------
__global__ __launch_bounds__(256) void k_aggf0(
    const float* __restrict__ x,
    const int* __restrict__ rowptr, const int* __restrict__ col,
    float* __restrict__ AGG, int nrowsC)
{
    int tid = threadIdx.x;
    int r = blockIdx.x * 8 + (tid >> 5);
    if (r >= nrowsC) return;
    int lane = tid & 31;
    int b = rowptr[r], e = rowptr[r + 1];
    float4 a = *reinterpret_cast<const float4*>(x + (long long)r * 128 + lane * 4);
    float dsum = 1.0f + (float)(e - b);
    for (int q = b; q < e; ++q) {
        int s = col[q];
        float4 v = *reinterpret_cast<const float4*>(x + (long long)s * 128 + lane * 4);
        a.x += v.x; a.y += v.y; a.z += v.z; a.w += v.w;
    }
    float invds = 1.0f / fmaxf(dsum, 1.0f);
    a.x *= invds; a.y *= invds; a.z *= invds; a.w *= invds;
    *reinterpret_cast<float4*>(AGG + (long long)r * 128 + lane * 4) = a;
}

// ---------------- stage-2 CSR gather-aggregate (bf16 in/out, alive-compacted) ----------------
__global__ __launch_bounds__(256) void k_aggf2(
    const unsigned short* __restrict__ x,
    const int* __restrict__ rowptr, const int* __restrict__ col,
    const int* __restrict__ aliveIdx, const float* __restrict__ nal, const float* __restrict__ fvec,
    int rowbase,
    unsigned short* __restrict__ AGGb, int nrowsC)
{
    int tid = threadIdx.x;
    int r = blockIdx.x * 8 + (tid >> 5);
    if (r >= nrowsC) return;
    int lane = tid & 31;
    int orig = aliveIdx[r];
    int grow = rowbase + orig;
    int b = rowptr[grow], e = rowptr[grow + 1];
    float4 a = make_float4(0.0f, 0.0f, 0.0f, 0.0f);
    float dsum = 0.0f;
    for (int q = b; q < e; ++q) {
        int fr = col[q] - rowbase;
        if (nal[fr] == 0.0f) continue;
        dsum += 1.0f;
        float fw = fvec[fr];
        if (fw == 0.0f) continue;
        ushort4 v = *reinterpret_cast<const ushort4*>(x + (long long)fr * 128 + lane * 4);
        a.x += bf2f(v.x) * fw; a.y += bf2f(v.y) * fw;
        a.z += bf2f(v.z) * fw; a.w += bf2f(v.w) * fw;
    }
    float invds = 1.0f / fmaxf(dsum, 1.0f);
    ushort4 o;
    o.x = f2bf(a.x * invds); o.y = f2bf(a.y * invds);
    o.z = f2bf(a.z * invds); o.w = f2bf(a.w * invds);
    *reinterpret_cast<ushort4*>(AGGb + (long long)r * 128 + lane * 4) = o;
}

// ---------------- dense SAGE GEMM (fp32 v2 tile) — stage-1 only ----------------
__global__ __launch_bounds__(256) void k_sage_d(
    const float* __restrict__ AGG, const float* __restrict__ xsrc,
    const float* __restrict__ Wl, const float* __restrict__ Wr, const float* __restrict__ bl,
    float* __restrict__ y, int nrowsC,
    const float* __restrict__ gw, float* __restrict__ gdot)
{
    __shared__ float Ws[32 * 128];
    __shared__ float Is[32][68];
    __shared__ float gwS[128];
    int tid = threadIdx.x;
    long long row0 = (long long)blockIdx.x * 64;
    if (tid < 128 && gw) gwS[tid] = gw[tid];
    __syncthreads();
    int tx = tid & 31, ty = tid >> 5;
    float gg4[4] = {0,0,0,0};
    if (gw) { gg4[0]=gwS[tx*4]; gg4[1]=gwS[tx*4+1]; gg4[2]=gwS[tx*4+2]; gg4[3]=gwS[tx*4+3]; }
    int srow = tid & 63;
    int koff = (tid >> 6) * 8;
    long long crow = row0 + srow;
    if (crow >= nrowsC) crow = nrowsC - 1;
    const float* selfp = xsrc + crow * 128;
    const float* aggp = AGG + crow * 128;

    float acc[8][4] = {};
    for (int kb = 0; kb < 8; ++kb) {
        __syncthreads();
        bool isAgg = (kb < 4);
        const float* Wsrc = isAgg ? (Wl + kb * 32 * 128) : (Wr + (kb - 4) * 32 * 128);
        #pragma unroll
        for (int j = 0; j < 4; ++j) {
            int fl = j * 1024 + tid * 4;
            *reinterpret_cast<float4*>(&Ws[fl]) = *reinterpret_cast<const float4*>(&Wsrc[fl]);
        }
        {
            const float* sp = (isAgg ? (aggp + kb * 32) : (selfp + (kb - 4) * 32)) + koff;
            float4 v0 = *reinterpret_cast<const float4*>(sp);
            float4 v1 = *reinterpret_cast<const float4*>(sp + 4);
            Is[koff + 0][srow] = v0.x; Is[koff + 1][srow] = v0.y;
            Is[koff + 2][srow] = v0.z; Is[koff + 3][srow] = v0.w;
            Is[koff + 4][srow] = v1.x; Is[koff + 5][srow] = v1.y;
            Is[koff + 6][srow] = v1.z; Is[koff + 7][srow] = v1.w;
        }
        __syncthreads();
        #pragma unroll
        for (int kk = 0; kk < 32; ++kk) {
            float4 wv = *reinterpret_cast<const float4*>(&Ws[kk * 128 + tx * 4]);
            float4 i0 = *reinterpret_cast<const float4*>(&Is[kk][ty * 8]);
            float4 i1 = *reinterpret_cast<const float4*>(&Is[kk][ty * 8 + 4]);
            float ia[8] = {i0.x, i0.y, i0.z, i0.w, i1.x, i1.y, i1.z, i1.w};
            float wa[4] = {wv.x, wv.y, wv.z, wv.w};
            #pragma unroll
            for (int i = 0; i < 8; ++i)
                #pragma unroll
                for (int j = 0; j < 4; ++j)
                    acc[i][j] += ia[i] * wa[j];
        }
    }
    float4 bl0 = *reinterpret_cast<const float4*>(&bl[tx * 4]);
    float br[4] = {bl0.x, bl0.y, bl0.z, bl0.w};
    #pragma unroll
    for (int i = 0; i < 8; ++i) {
        long long row = row0 + ty * 8 + i;
        bool valid = (row < nrowsC);
        float yv[4];
        #pragma unroll
        for (int j = 0; j < 4; ++j) yv[j] = ftanh(acc[i][j] + br[j]);
        if (valid)
            *reinterpret_cast<float4*>(&y[row * 128 + tx * 4]) = make_float4(yv[0], yv[1], yv[2], yv[3]);
        float gp = 0.0f;
        #pragma unroll
        for (int j = 0; j < 4; ++j) if (gdot) gp += yv[j] * gg4[j];
        #pragma unroll
        for (int m = 16; m >= 1; m >>= 1) if (gdot) gp += __shfl_xor(gp, m, 32);
        if (tx == 0 && valid && gdot) gdot[row] = gp;
    }
}

// ---------------- bf16 weight pack ----------------
__global__ void k_packW(const float* __restrict__ Wl, const float* __restrict__ Wr,
                        short* __restrict__ Wb) {
    int i = blockIdx.x * 256 + threadIdx.x;
    if (i >= 32768) return;
    int kt = i >> 12, rem = i & 4095;
    int ct = rem >> 9; rem &= 511;
    int lane = rem >> 3, e = rem & 7;
    int k = kt * 32 + (lane >> 4) * 8 + e;
    int c = ct * 16 + (lane & 15);
    float v = (k < 128) ? Wl[k * 128 + c] : Wr[(k - 128) * 128 + c];
    Wb[i] = (short)f2bf(v);
}

// ---------------- MFMA SAGE GEMM (stage-2 L1/L2): 16 rows/wave, 64 rows/block ----------------
__global__ __launch_bounds__(256) void k_sage_m(
    const unsigned short* __restrict__ AGGb, const unsigned short* __restrict__ X,
    const int* __restrict__ aliveIdx, const float* __restrict__ fvec,
    const short* __restrict__ Wb, const float* __restrict__ bl,
    unsigned short* __restrict__ y, int nrowsC,
    const float* __restrict__ wrel, const float* __restrict__ wroot, const float* __restrict__ gw,
    float* __restrict__ tbuf, float* __restrict__ rootd, float* __restrict__ gdot)
{
    __shared__ short8 lB[2048];
    int tid = threadIdx.x;
    int lane = tid & 63;
    int wv = tid >> 6;
    long long rows0 = (long long)blockIdx.x * 64 + wv * 16;
    int arow = lane & 15;
    int ksl = (lane >> 4) * 8;

    int growA = (int)(rows0 + arow);
    int origA = aliveIdx[growA];
    float fsA = fvec[origA];

    f32x4 acc[8] = {};
    const short8* Wbv = (const short8*)Wb;

    for (int half = 0; half < 2; ++half) {
        __syncthreads();
        #pragma unroll
        for (int i = 0; i < 8; ++i) {
            int idx = i * 256 + tid;
            lB[idx] = Wbv[half * 2048 + idx];
        }
        __syncthreads();
        #pragma unroll
        for (int ktl = 0; ktl < 4; ++ktl) {
            int kt = half * 4 + ktl;
            short8 afr;
            if (kt < 4) {
                afr = *reinterpret_cast<const short8*>(AGGb + (long long)growA * 128 + kt * 32 + ksl);
            } else {
                short8 xv = *reinterpret_cast<const short8*>(X + (long long)origA * 128 + (kt - 4) * 32 + ksl);
                #pragma unroll
                for (int e = 0; e < 8; ++e)
                    afr[e] = (short)f2bf(bf2f((unsigned short)xv[e]) * fsA);
            }
            #pragma unroll
            for (int ct = 0; ct < 8; ++ct) {
                short8 bfr = lB[(ktl * 8 + ct) * 64 + lane];
                acc[ct] = __builtin_amdgcn_mfma_f32_16x16x32_bf16(afr, bfr, acc[ct], 0, 0, 0);
            }
        }
    }

    int ocol = lane & 15;
    float blv[8], wrv[8], wov[8], ggv[8];
    #pragma unroll
    for (int ct = 0; ct < 8; ++ct) {
        int c = ct * 16 + ocol;
        blv[ct] = bl[c];
        wrv[ct] = wrel[c];
        wov[ct] = wroot[c];
        ggv[ct] = gw[c];
    }
    #pragma unroll
    for (int j = 0; j < 4; ++j) {
        int rloc = (lane >> 4) * 4 + j;
        long long grow = rows0 + rloc;
        int orig = aliveIdx[grow];
        float tp = 0.0f, rp = 0.0f, gp = 0.0f;
        #pragma unroll
        for (int ct = 0; ct < 8; ++ct) {
            float v = ftanh(acc[ct][j] + blv[ct]);
            y[(long long)orig * 128 + ct * 16 + ocol] = f2bf(v);
            tp += v * wrv[ct]; rp += v * wov[ct]; gp += v * ggv[ct];
        }
        #pragma unroll
        for (int mm = 8; mm >= 1; mm >>= 1) {
            tp += __shfl_xor(tp, mm, 16);
            rp += __shfl_xor(rp, mm, 16);
            gp += __shfl_xor(gp, mm, 16);
        }
        if (ocol == 0) { tbuf[orig] = tp; rootd[orig] = rp; gdot[orig] = gp; }
    }
}

// ---------------- plain GEMM: y = x@W (+ b), v2 tile ----------------
__global__ __launch_bounds__(256) void k_gemm_self(
    const float* __restrict__ x, const float* __restrict__ W, const float* __restrict__ b,
    float* __restrict__ y, int nrows)
{
    __shared__ float Ws[32 * 128];
    __shared__ float Is[32][68];
    int tid = threadIdx.x;
    long long row0 = (long long)blockIdx.x * 64;
    int tx = tid & 31, ty = tid >> 5;
    int srow = tid & 63;
    int koff = (tid >> 6) * 8;
    long long lrow = row0 + srow;
    if (lrow >= nrows) lrow = nrows - 1;
    const float* xrow = x + lrow * 128;
    float acc[8][4] = {};
    for (int kb = 0; kb < 4; ++kb) {
        __syncthreads();
        const float* Wsrc = W + kb * 32 * 128;
        #pragma unroll
        for (int j = 0; j < 4; ++j) {
            int fl = j * 1024 + tid * 4;
            *reinterpret_cast<float4*>(&Ws[fl]) = *reinterpret_cast<const float4*>(&Wsrc[fl]);
        }
        {
            const float* sp = xrow + kb * 32 + koff;
            float4 v0 = *reinterpret_cast<const float4*>(sp);
            float4 v1 = *reinterpret_cast<const float4*>(sp + 4);
            Is[koff + 0][srow] = v0.x; Is[koff + 1][srow] = v0.y;
            Is[koff + 2][srow] = v0.z; Is[koff + 3][srow] = v0.w;
            Is[koff + 4][srow] = v1.x; Is[koff + 5][srow] = v1.y;
            Is[koff + 6][srow] = v1.z; Is[koff + 7][srow] = v1.w;
        }
        __syncthreads();
        #pragma unroll
        for (int kk = 0; kk < 32; ++kk) {
            float4 wv = *reinterpret_cast<const float4*>(&Ws[kk * 128 + tx * 4]);
            float4 i0 = *reinterpret_cast<const float4*>(&Is[kk][ty * 8]);
            float4 i1 = *reinterpret_cast<const float4*>(&Is[kk][ty * 8 + 4]);
            float ia[8] = {i0.x, i0.y, i0.z, i0.w, i1.x, i1.y, i1.z, i1.w};
            float wa[4] = {wv.x, wv.y, wv.z, wv.w};
            #pragma unroll
            for (int i = 0; i < 8; ++i)
                #pragma unroll
                for (int j = 0; j < 4; ++j)
                    acc[i][j] += ia[i] * wa[j];
        }
    }
    float4 b0 = b ? *reinterpret_cast<const float4*>(&b[tx * 4]) : make_float4(0.f, 0.f, 0.f, 0.f);
    #pragma unroll
    for (int i = 0; i < 8; ++i) {
        long long row = row0 + ty * 8 + i;
        if (row >= nrows) continue;
        *reinterpret_cast<float4*>(&y[row * 128 + tx * 4]) =
            make_float4(acc[i][0] + b0.x, acc[i][1] + b0.y, acc[i][2] + b0.z, acc[i][3] + b0.w);
    }
}

// ---------------- stage-2 L0 combine (bf16 X out) ----------------
__global__ __launch_bounds__(256) void k_l0comb(
    const float* __restrict__ ZL0, const float* __restrict__ zself,
    const int* __restrict__ rowptr, const int* __restrict__ col, int rowbase,
    const float* __restrict__ wrel, const float* __restrict__ wroot, const float* __restrict__ gw,
    unsigned short* __restrict__ y, float* __restrict__ tbuf, float* __restrict__ rootd, float* __restrict__ gdot,
    int nrowsC)
{
    __shared__ float wrelS[128], wrootS[128], gwS[128];
    int tid = threadIdx.x;
    if (tid < 128) {
        wrelS[tid]  = wrel[tid];
        wrootS[tid] = wroot[tid];
        gwS[tid]    = gw[tid];
    }
    __syncthreads();
    int r = blockIdx.x * 8 + (tid >> 5);
    if (r >= nrowsC) return;
    int lane = tid & 31;
    int grow = rowbase + r;
    int b = rowptr[grow], e = rowptr[grow + 1];
    float4 a = make_float4(0.0f, 0.0f, 0.0f, 0.0f);
    for (int q = b; q < e; ++q) {
        int fr = col[q] % NN;
        float4 v = *reinterpret_cast<const float4*>(ZL0 + (long long)fr * 128 + lane * 4);
        a.x += v.x; a.y += v.y; a.z += v.z; a.w += v.w;
    }
    float invds = 1.0f / fmaxf((float)(e - b), 1.0f);
    const float4 z = *reinterpret_cast<const float4*>(zself + (long long)(r % NN) * 128 + lane * 4);
    float yv[4];
    yv[0] = ftanh(a.x * invds + z.x);
    yv[1] = ftanh(a.y * invds + z.y);
    yv[2] = ftanh(a.z * invds + z.z);
    yv[3] = ftanh(a.w * invds + z.w);
    ushort4 o;
    o.x = f2bf(yv[0]); o.y = f2bf(yv[1]); o.z = f2bf(yv[2]); o.w = f2bf(yv[3]);
    *reinterpret_cast<ushort4*>(y + (long long)r * 128 + lane * 4) = o;
    float tp = 0.0f, rp = 0.0f, gp = 0.0f;
    #pragma unroll
    for (int j = 0; j < 4; ++j) {
        tp += yv[j] * wrelS[lane*4 + j];
        rp += yv[j] * wrootS[lane*4 + j];
        gp += yv[j] * gwS[lane*4 + j];
    }
    #pragma unroll
    for (int m = 16; m >= 1; m >>= 1) {
        tp += __shfl_xor(tp, m, 32);
        rp += __shfl_xor(rp, m, 32);
        gp += __shfl_xor(gp, m, 32);
    }
    if (lane == 0) {
        tbuf[r]  = tp;
        rootd[r] = rp;
        gdot[r]  = gp;
    }
}

// ---------------- stage-1 readout pieces ----------------
__global__ __launch_bounds__(256) void k_gate(
    const float* __restrict__ X, const float* __restrict__ gw,
    float* __restrict__ g, int nrows)
{
    __shared__ float wS[128];
    if (threadIdx.x < 128) wS[threadIdx.x] = gw[threadIdx.x];
    __syncthreads();
    int i = blockIdx.x * 256 + threadIdx.x;
    if (i >= nrows) return;
    const float4* xrp = reinterpret_cast<const float4*>(X + (long long)i * 128);
    float s = 0.0f;
    #pragma unroll
    for (int k = 0; k < 32; ++k) {
        float4 v = xrp[k];
        s += v.x * wS[4*k] + v.y * wS[4*k+1] + v.z * wS[4*k+2] + v.w * wS[4*k+3];
    }
    g[i] = s;
}

__global__ __launch_bounds__(1024) void k_smstats(float* __restrict__ g, float* __restrict__ invp) {
    __shared__ float red[1024];
    int p = blockIdx.x, tid = threadIdx.x;
    float* gp = g + (long long)p * NN;
    float lmax = -INFINITY;
    for (int n = tid; n < NN; n += 1024) lmax = fmaxf(lmax, gp[n]);
    red[tid] = lmax; __syncthreads();
    for (int s = 512; s > 0; s >>= 1) { if (tid < s) red[tid] = fmaxf(red[tid], red[tid + s]); __syncthreads(); }
    float mx = red[0]; __syncthreads();
    float ls = 0.0f;
    for (int n = tid; n < NN; n += 1024) { float e = __expf(gp[n] - mx); gp[n] = e; ls += e; }
    red[tid] = ls; __syncthreads();
    for (int s = 512; s > 0; s >>= 1) { if (tid < s) red[tid] += red[tid + s]; __syncthreads(); }
    if (tid == 0) invp[p] = 1.0f / red[0];
}

__global__ __launch_bounds__(128) void k_wsum(
    const float* __restrict__ X, const float* __restrict__ a,
    const float* __restrict__ invp, float* __restrict__ ro, int rowbase, int colOff)
{
    int p = blockIdx.x / BPG;
    int chunk = blockIdx.x % BPG;
    int d = threadIdx.x;
    long long base = (long long)p * NN;
    int r0 = chunk * RB, r1 = r0 + RB;
    float s = 0.0f;
    for (int n = r0; n < r1; ++n) {
        float w = a[base + n];
        if (w != 0.0f) s += w * X[(base + n) * 128 + d];
    }
    atomicAdd(&ro[(long long)(rowbase + p) * 384 + colOff + d], s * invp[p]);
}

// stage-2 weighted sum over alive rows only (bf16 X)
__global__ __launch_bounds__(128) void k_wsum_c(
    const unsigned short* __restrict__ X, const float* __restrict__ gbuf, const float* __restrict__ fvec,
    const float* __restrict__ invp, const int* __restrict__ aliveIdx, int k,
    float* __restrict__ ro, int rowbaseRo, int colOff)
{
    int bpp = k / RB;
    int p = blockIdx.x / bpp;
    int chunk = blockIdx.x % bpp;
    int d = threadIdx.x;
    const int* ai = aliveIdx + (long long)p * k + chunk * RB;
    float s = 0.0f;
    for (int j = 0; j < RB; ++j) {
        int row = ai[j];
        float w = gbuf[row] * fvec[row];
        s += w * bf2f(X[(long long)row * 128 + d]);
    }
    atomicAdd(&ro[(long long)(rowbaseRo + p) * 384 + colOff + d], s * invp[p]);
}

// ---------------- GraphNorm ----------------
__global__ void k_colstat(const float* __restrict__ x, float* __restrict__ musum,
                          float* __restrict__ sqsum, int nrows) {
    int d = threadIdx.x;
    int r0 = blockIdx.x * 64;
    int r1 = min(r0 + 64, nrows);
    float s = 0.0f, q = 0.0f;
    for (int r = r0; r < r1; ++r) { float v = x[(long long)r * 128 + d]; s += v; q += v * v; }
    atomicAdd(&musum[d], s);
    atomicAdd(&sqsum[d], q);
}

__global__ void k_gnorm_apply(const float* __restrict__ x, float* __restrict__ y,
                              const float* __restrict__ musum, const float* __restrict__ sqsum,
                              const float* __restrict__ w, const float* __restrict__ b,
                              const float* __restrict__ ms, int nrows) {
    long long i = (long long)blockIdx.x * 256 + threadIdx.x;
    if (i >= (long long)nrows * 128) return;
    int d = (int)(i & 127);
    float inv_n = 1.0f / (float)nrows;
    float mu = musum[d] * inv_n;
    float c = mu * ms[d];
    float var = sqsum[d] * inv_n - 2.0f * c * mu + c * c;
    y[i] = w[d] * (x[i] - c) * rsqrtf(var + 1e-5f) + b[d];
}

// ---------------- parallel score+key ----------------
__global__ __launch_bounds__(256) void k_score2(
    const int* __restrict__ rowptr, const int* __restrict__ col, int rowbase,
    const float* __restrict__ tb, const float* __restrict__ rootd,
    const float* __restrict__ brelp, int bi, int allAlive,
    const float* __restrict__ nalive, unsigned* __restrict__ keysG, int n)
{
    int r = blockIdx.x * 256 + threadIdx.x;
    if (r >= n) return;
    int grow = rowbase + r;
    float s = brelp[bi] + rootd[r];
    int b = rowptr[grow], e = rowptr[grow + 1];
    for (int q = b; q < e; ++q) {
        int sl = col[q] - rowbase;
        s += allAlive ? tb[sl] : (tb[sl] * nalive[sl]);
    }
    bool alive = allAlive || (nalive[r] > 0.5f);
    keysG[r] = alive ? fkey(s) : 0u;
}

// ---------------- barrier-light top-k (keys precomputed) ----------------
__global__ __launch_bounds__(1024) void k_topk3(
    const unsigned* __restrict__ keysG, const float* __restrict__ gdot,
    float* __restrict__ nalive, float* __restrict__ fvec, float* __restrict__ gbuf,
    float* __restrict__ invp, int* __restrict__ aliveIdx, int k)
{
    __shared__ unsigned keys[NN];
    __shared__ int hist[256];
    __shared__ int wred[16];
    __shared__ float wredf[16];
    __shared__ unsigned sh_pref;
    __shared__ int sh_kneed;
    int p = blockIdx.x, tid = threadIdx.x;
    int lane = tid & 63, wid = tid >> 6;
    long long pbase = (long long)p * NN;
    const uint4* kg = reinterpret_cast<const uint4*>(keysG + pbase);
    for (int i = tid; i < NN / 4; i += 1024)
        *reinterpret_cast<uint4*>(&keys[i * 4]) = kg[i];
    if (tid == 0) { sh_pref = 0u; sh_kneed = k; }
    __syncthreads();

    for (int lvl = 3; lvl >= 0; --lvl) {
        int sh = lvl * 8;
        if (tid < 256) hist[tid] = 0;
        unsigned pref = sh_pref; int kneed = sh_kneed;
        unsigned pmask = (lvl == 3) ? 0u : (0xFFFFFFFFu << (8 * (lvl + 1)));
        __syncthreads();
        for (int n = tid; n < NN; n += 1024) {
            unsigned kv = keys[n];
            if ((kv & pmask) == pref) atomicAdd(&hist[(kv >> sh) & 255], 1);
        }
        __syncthreads();
        if (wid == 0) {
            // lane owns 4 bins in descending order: b0 = 252 - 4*lane
            int b0 = 252 - 4 * lane;
            int h0 = hist[b0], h1 = hist[b0 + 1], h2 = hist[b0 + 2], h3 = hist[b0 + 3];
            int s3 = h3, s2 = h2 + s3, s1 = h1 + s2, s0 = h0 + s1;
            int gs = s0;
            #pragma unroll
            for (int d = 1; d < 64; d <<= 1) {
                int u = __shfl_up(gs, d, 64);
                if (lane >= d) gs += u;
            }
            int above = gs - s0;   // sum of higher bins
            int suf0 = above + s0, suf1 = above + s1, suf2 = above + s2, suf3 = above + s3;
            if (suf0 >= kneed && suf0 - h0 < kneed) { sh_pref = pref | ((unsigned)b0 << sh); sh_kneed = kneed - (suf0 - h0); }
            if (suf1 >= kneed && suf1 - h1 < kneed) { sh_pref = pref | ((unsigned)(b0+1) << sh); sh_kneed = kneed - (suf1 - h1); }
            if (suf2 >= kneed && suf2 - h2 < kneed) { sh_pref = pref | ((unsigned)(b0+2) << sh); sh_kneed = kneed - (suf2 - h2); }
            if (suf3 >= kneed && suf3 - h3 < kneed) { sh_pref = pref | ((unsigned)(b0+3) << sh); sh_kneed = kneed - (suf3 - h3); }
        }
        __syncthreads();
    }

    unsigned V = sh_pref;
    int seleq = sh_kneed;
    int c0 = tid * 8;
    int ceq = 0;
    #pragma unroll
    for (int j = 0; j < 8; ++j) {
        int n = c0 + j;
        if (n < NN) ceq += (keys[n] == V) ? 1 : 0;
    }
    // exclusive rank scan across 1024 threads (wave shfl + cross-wave)
    int vv = ceq;
    #pragma unroll
    for (int d = 1; d < 64; d <<= 1) {
        int u = __shfl_up(vv, d, 64);
        if (lane >= d) vv += u;
    }
    if (lane == 63) wred[wid] = vv;
    __syncthreads();
    if (tid < 16) {
        int w = wred[tid];
        #pragma unroll
        for (int d = 1; d < 16; d <<= 1) {
            int u = __shfl_up(w, d, 16);
            if (tid >= d) w += u;
        }
        wred[tid] = w;
    }
    __syncthreads();
    int rank = vv - ceq + (wid > 0 ? wred[wid - 1] : 0);

    unsigned selmask = 0u;
    int nsel = 0;
    float lmax = -INFINITY;
    #pragma unroll
    for (int j = 0; j < 8; ++j) {
        int n = c0 + j;
        if (n >= NN) break;
        unsigned kk = keys[n];
        bool sel = (kk > V) || (kk == V && rank < seleq);
        if (kk == V) rank++;
        long long gl = pbase + n;
        nalive[gl] = sel ? 1.0f : 0.0f;
        float f = 0.0f;
        if (sel) {
            f = ftanh(fkey_inv(kk));
            lmax = fmaxf(lmax, f * gdot[gl]);
            selmask |= (1u << j);
            ++nsel;
        }
        fvec[gl] = f;
    }
    // max reduce
    #pragma unroll
    for (int d = 32; d >= 1; d >>= 1) lmax = fmaxf(lmax, __shfl_xor(lmax, d, 64));
    if (lane == 0) wredf[wid] = lmax;
    __syncthreads();
    if (tid < 16) {
        float m = wredf[tid];
        #pragma unroll
        for (int d = 8; d >= 1; d >>= 1) m = fmaxf(m, __shfl_xor(m, d, 16));
        if (tid == 0) wredf[0] = m;
    }
    __syncthreads();
    float mx = wredf[0];
    __syncthreads();
    // nsel scan
    int v2 = nsel;
    #pragma unroll
    for (int d = 1; d < 64; d <<= 1) {
        int u = __shfl_up(v2, d, 64);
        if (lane >= d) v2 += u;
    }
    if (lane == 63) wred[wid] = v2;
    __syncthreads();
    if (tid < 16) {
        int w = wred[tid];
        #pragma unroll
        for (int d = 1; d < 16; d <<= 1) {
            int u = __shfl_up(w, d, 16);
            if (tid >= d) w += u;
        }
        wred[tid] = w;
    }
    __syncthreads();
    int pos = v2 - nsel + (wid > 0 ? wred[wid - 1] : 0);

    float lsum = 0.0f;
    #pragma unroll
    for (int j = 0; j < 8; ++j) {
        if (selmask & (1u << j)) {
            int n = c0 + j;
            long long gl = pbase + n;
            float e = __expf(fvec[gl] * gdot[gl] - mx);
            gbuf[gl] = e;
            lsum += e;
            aliveIdx[(long long)p * k + pos] = (int)gl;
            ++pos;
        }
    }
    #pragma unroll
    for (int d = 32; d >= 1; d >>= 1) lsum += __shfl_xor(lsum, d, 64);
    if (lane == 0) wredf[wid] = lsum;
    __syncthreads();
    if (tid < 16) {
        float s = wredf[tid];
        #pragma unroll
        for (int d = 8; d >= 1; d >>= 1) s += __shfl_xor(s, d, 16);
        if (tid == 0) invp[p] = 1.0f / s;
    }
}

// ---------------- head ----------------
__global__ __launch_bounds__(64) void k_head(
    const float* __restrict__ ro, const float* __restrict__ lin_w, const float* __restrict__ lin_b,
    const float* __restrict__ m1w, const float* __restrict__ m1b,
    const float* __restrict__ m2w, const float* __restrict__ m2b,
    const float* __restrict__ m3w, const float* __restrict__ m3b, float* __restrict__ out)
{
    __shared__ float v[33], h1[48], h2[16];
    int t = threadIdx.x;
    if (t < 33) {
        float s = lin_b[0];
        for (int k = 0; k < 384; ++k) s += ro[t * 384 + k] * lin_w[k];
        v[t] = tanhf(s);
    }
    __syncthreads();
    if (t < 48) {
        float s = m1b[t];
        for (int i = 0; i < 33; ++i) s += v[i] * m1w[i * 48 + t];
        h1[t] = tanhf(s);
    }
    __syncthreads();
    if (t < 16) {
        float s = m2b[t];
        for (int i = 0; i < 48; ++i) s += h1[i] * m2w[i * 16 + t];
        h2[t] = tanhf(s);
    }
    __syncthreads();
    if (t == 0) {
        float s = m3b[0];
        for (int i = 0; i < 16; ++i) s += h2[i] * m3w[i];
        float s1 = 1.0f / (1.0f + expf(-s));
        out[0] = 1.0f / (1.0f + expf(-s1));
    }
}

static inline int cdiv(long long a, long long b) { return (int)((a + b - 1) / b); }

extern "C" void kernel_launch(void* const* d_in, const int* in_sizes, int n_in,
                              void* d_out, int out_size, void* d_ws, size_t ws_size,
                              hipStream_t stream)
{
    (void)in_sizes; (void)n_in; (void)out_size;
    const float* h     = (const float*)d_in[0];
    const int*   eidx  = (const int*)d_in[1];
    const int*   seidx = (const int*)d_in[2];
    const float* Wl_a  = (const float*)d_in[3];
    const float* Wr_a  = (const float*)d_in[4];
    const float* bl_a  = (const float*)d_in[5];
    const float* Wl_s  = (const float*)d_in[6];
    const float* Wr_s  = (const float*)d_in[7];
    const float* bl_s  = (const float*)d_in[8];
    const float* gate_w = (const float*)d_in[9];
    const float* p_wrel = (const float*)d_in[11];
    const float* p_brel = (const float*)d_in[12];
    const float* p_wroot= (const float*)d_in[13];
    const float* nw    = (const float*)d_in[14];
    const float* nb    = (const float*)d_in[15];
    const float* nms   = (const float*)d_in[16];
    const float* lin_w = (const float*)d_in[17];
    const float* lin_b = (const float*)d_in[18];
    const float* m1w   = (const float*)d_in[19];
    const float* m1b   = (const float*)d_in[20];
    const float* m2w   = (const float*)d_in[21];
    const float* m2b   = (const float*)d_in[22];
    const float* m3w   = (const float*)d_in[23];
    const float* m3b   = (const float*)d_in[24];
    float* out = (float*)d_out;

    const int* esrc = eidx;
    const int* edst = eidx + EG;
    const int* ssrc = seidx;
    const int* sdst = seidx + ES_TOT;

    auto need_bytes = [](int chp) -> size_t {
        long long chn = (long long)chp * NN;
        long long f = chn * 64
                    + (long long)chp * KK1 * 64
                    + 2LL * NN * 128
                    + 5 * chn
                    + chn                       // keysG
                    + 64 + 33 * 384
                    + (long long)chp * KK1
                    + (PN + 1) + ES_TOT
                    + 2 * 16384
                    + 64 * 28;
        return (size_t)f * 4;
    };
    int chp = 8;
    if (ws_size >= need_bytes(32)) chp = 32;
    else if (ws_size >= need_bytes(16)) chp = 16;
    int nch = PP / chp;
    long long ch_n = (long long)chp * NN;

    float* W = (float*)d_ws;
    size_t off = 0;
    auto alloc = [&](size_t nf) { float* p = W + off; off += (nf + 63) & ~(size_t)63; return p; };
    unsigned short* XAb = (unsigned short*)alloc((size_t)ch_n * 64);
    unsigned short* AGGb = (unsigned short*)alloc((size_t)chp * KK1 * 64);
    float* ZL0   = alloc((size_t)NN * DD);
    float* zself = alloc((size_t)NN * DD);
    float* tbuf  = alloc(ch_n);
    float* rootd = alloc(ch_n);
    float* nal   = alloc(ch_n);
    float* fvec  = alloc(ch_n);
    float* gdot  = alloc(ch_n);
    unsigned* keysG = (unsigned*)alloc(ch_n);
    float* invp  = alloc(64);
    float* ro    = alloc(33 * 384);
    int* aliveIdx = (int*)alloc((size_t)chp * KK1);
    int* s2rp    = (int*)alloc(PN + 1);
    int* s2col   = (int*)alloc(ES_TOT);
    short* Wb1   = (short*)alloc(16384);
    short* Wb2   = (short*)alloc(16384);
    float* gbuf = tbuf;

    // overlay inside XAb (dead before XAb's first write)
    float* XO = (float*)XAb;
    size_t ooff = 0;
    auto oalloc = [&](size_t nf) { float* p = XO + ooff; ooff += (nf + 63) & ~(size_t)63; return p; };
    float* xa    = oalloc((size_t)NN * DD);
    float* xb    = oalloc((size_t)NN * DD);
    float* AGGs  = oalloc((size_t)NN * DD);
    float* agg1  = oalloc((size_t)NN * 16);
    float* deg1  = oalloc(NN);
    float* musum = oalloc(128);
    float* sqsum = oalloc(128);
    int* s1cnt  = (int*)oalloc(NN);
    int* s1rp   = (int*)oalloc(NN + 1);
    int* s1cur  = (int*)oalloc(NN);
    int* s1col  = (int*)oalloc(EG);
    int* s1part = (int*)oalloc(NN);
    int* s1bsum = (int*)oalloc(1024);
    int* s2cnt  = (int*)oalloc(PN);
    int* s2cur  = (int*)oalloc(PN);
    int* s2part = (int*)oalloc(PN);
    int* s2bsum = (int*)oalloc(1024);

    // ---------- CSR builds ----------
    int nb1 = cdiv(NN, 1024), nb2 = cdiv(PN, 1024);
    hipMemsetAsync(s1cnt, 0, NN * sizeof(int), stream);
    k_hist<<<cdiv(EG,256),256,0,stream>>>(edst, s1cnt, EG);
    k_scanA<<<nb1,1024,0,stream>>>(s1cnt, s1part, s1bsum, NN);
    k_scanB<<<1,1024,0,stream>>>(s1bsum, nb1);
    k_scanC<<<cdiv(NN,256),256,0,stream>>>(s1part, s1bsum, s1rp, s1cur, NN, EG);
    k_scatter<<<cdiv(EG,256),256,0,stream>>>(esrc, edst, s1cur, s1col, EG);

    hipMemsetAsync(s2cnt, 0, (size_t)PN * sizeof(int), stream);
    k_hist<<<cdiv(ES_TOT,256),256,0,stream>>>(sdst, s2cnt, ES_TOT);
    k_scanA<<<nb2,1024,0,stream>>>(s2cnt, s2part, s2bsum, PN);
    k_scanB<<<1,1024,0,stream>>>(s2bsum, nb2);
    k_scanC<<<cdiv(PN,256),256,0,stream>>>(s2part, s2bsum, s2rp, s2cur, PN, ES_TOT);
    k_scatter<<<cdiv(ES_TOT,256),256,0,stream>>>(ssrc, sdst, s2cur, s2col, ES_TOT);

    hipMemsetAsync(ro, 0, 33 * 384 * sizeof(float), stream);

    k_packW<<<128,256,0,stream>>>(Wl_s + 3*16384, Wr_s + 3*16384, Wb1);
    k_packW<<<128,256,0,stream>>>(Wl_s + 4*16384, Wr_s + 4*16384, Wb2);

    // ---------- stage 1 ----------
    k_agg16<<<cdiv((long long)NN*16,256),256,0,stream>>>(h, s1rp, s1col, agg1, deg1, NN);
    k_sage16<<<cdiv((long long)NN*DD,256),256,0,stream>>>(h, agg1, deg1, Wl_a, Wr_a, bl_a, xa, NN);
    k_gate<<<cdiv(NN,256),256,0,stream>>>(xa, gate_w + 0*DD, gbuf, NN);
    k_smstats<<<1,1024,0,stream>>>(gbuf, invp);
    k_wsum<<<BPG,128,0,stream>>>(xa, gbuf, invp, ro, 0, 0);

    hipMemsetAsync(musum, 0, 128*sizeof(float), stream);
    hipMemsetAsync(sqsum, 0, 128*sizeof(float), stream);
    k_colstat<<<cdiv(NN,64),128,0,stream>>>(xa, musum, sqsum, NN);
    k_gnorm_apply<<<cdiv((long long)NN*DD,256),256,0,stream>>>(xa, xb, musum, sqsum, nw, nb, nms, NN);

    k_aggf0<<<cdiv(NN,8),256,0,stream>>>(xb, s1rp, s1col, AGGs, NN);
    k_sage_d<<<cdiv(NN,64),256,0,stream>>>(AGGs, xb,
        Wl_s + 0*16384, Wr_s + 0*16384, bl_s + 0*128, xa, NN,
        gate_w + 1*DD, gbuf);
    k_smstats<<<1,1024,0,stream>>>(gbuf, invp);
    k_wsum<<<BPG,128,0,stream>>>(xa, gbuf, invp, ro, 0, 128);

    hipMemsetAsync(musum, 0, 128*sizeof(float), stream);
    hipMemsetAsync(sqsum, 0, 128*sizeof(float), stream);
    k_colstat<<<cdiv(NN,64),128,0,stream>>>(xa, musum, sqsum, NN);
    k_gnorm_apply<<<cdiv((long long)NN*DD,256),256,0,stream>>>(xa, xb, musum, sqsum, nw, nb, nms, NN);

    k_aggf0<<<cdiv(NN,8),256,0,stream>>>(xb, s1rp, s1col, AGGs, NN);
    k_sage_d<<<cdiv(NN,64),256,0,stream>>>(AGGs, xb,
        Wl_s + 1*16384, Wr_s + 1*16384, bl_s + 1*128, xa, NN,
        gate_w + 2*DD, gbuf);
    k_smstats<<<1,1024,0,stream>>>(gbuf, invp);
    k_wsum<<<BPG,128,0,stream>>>(xa, gbuf, invp, ro, 0, 256);

    // ---------- stage 2 ----------
    k_gemm_self<<<cdiv(NN,64),256,0,stream>>>(xa, Wl_s + 2*16384, nullptr, ZL0, NN);
    k_gemm_self<<<cdiv(NN,64),256,0,stream>>>(xa, Wr_s + 2*16384, bl_s + 2*128, zself, NN);

    for (int c = 0; c < nch; ++c) {
        int nbase = (int)(c * ch_n);

        k_l0comb<<<(int)(ch_n/8),256,0,stream>>>(ZL0, zself, s2rp, s2col, nbase,
            p_wrel + 0*DD, p_wroot + 0*DD, gate_w + 3*DD,
            XAb, tbuf, rootd, gdot, (int)ch_n);
        k_score2<<<(int)(ch_n/256),256,0,stream>>>(s2rp, s2col, nbase, tbuf, rootd, p_brel, 0, 1,
                                                   nal, keysG, (int)ch_n);
        k_topk3<<<chp,1024,0,stream>>>(keysG, gdot, nal, fvec, gbuf, invp, aliveIdx, KK1);
        k_wsum_c<<<chp*(KK1/RB),128,0,stream>>>(XAb, gbuf, fvec, invp, aliveIdx, KK1, ro, 1 + c*chp, 0);

        k_aggf2<<<chp*(KK1/8),256,0,stream>>>(XAb, s2rp, s2col, aliveIdx, nal, fvec, nbase, AGGb, chp*KK1);
        k_sage_m<<<chp*(KK1/64),256,0,stream>>>(AGGb, XAb, aliveIdx, fvec, Wb1, bl_s + 3*128, XAb, chp*KK1,
            p_wrel + 1*DD, p_wroot + 1*DD, gate_w + 4*DD, tbuf, rootd, gdot);
        k_score2<<<(int)(ch_n/256),256,0,stream>>>(s2rp, s2col, nbase, tbuf, rootd, p_brel, 1, 0,
                                                   nal, keysG, (int)ch_n);
        k_topk3<<<chp,1024,0,stream>>>(keysG, gdot, nal, fvec, gbuf, invp, aliveIdx, KK2);
        k_wsum_c<<<chp*(KK2/RB),128,0,stream>>>(XAb, gbuf, fvec, invp, aliveIdx, KK2, ro, 1 + c*chp, 128);

        k_aggf2<<<chp*(KK2/8),256,0,stream>>>(XAb, s2rp, s2col, aliveIdx, nal, fvec, nbase, AGGb, chp*KK2);
        k_sage_m<<<chp*(KK2/64),256,0,stream>>>(AGGb, XAb, aliveIdx, fvec, Wb2, bl_s + 4*128, XAb, chp*KK2,
            p_wrel + 2*DD, p_wroot + 2*DD, gate_w + 5*DD, tbuf, rootd, gdot);
        k_score2<<<(int)(ch_n/256),256,0,stream>>>(s2rp, s2col, nbase, tbuf, rootd, p_brel, 2, 0,
                                                   nal, keysG, (int)ch_n);
        k_topk3<<<chp,1024,0,stream>>>(keysG, gdot, nal, fvec, gbuf, invp, aliveIdx, KK3);
        k_wsum_c<<<chp*(KK3/RB),128,0,stream>>>(XAb, gbuf, fvec, invp, aliveIdx, KK3, ro, 1 + c*chp, 256);
    }

    // ---------- head ----------
    k_head<<<1,64,0,stream>>>(ro, lin_w, lin_b, m1w, m1b, m2w, m2b, m3w, m3b, out);
}

// Round 21
// 642.824 us; speedup vs baseline: 4.0879x; 1.0221x over previous
//
#include <hip/hip_runtime.h>
#include <math.h>

#define NN      8000
#define PP      32
#define EG      128000
#define ES_TOT  131072     // P * 4096
#define ES_P    4096
#define PN      256000     // P * NN
#define DI      16
#define DD      128
#define KK1     6400
#define KK2     5120
#define KK3     4096
#define RB      64
#define BPG     (NN / RB)

typedef __attribute__((ext_vector_type(8))) short short8;
typedef __attribute__((ext_vector_type(4))) float f32x4;

#define FNAN __int_as_float(0x7FC00000)

static __device__ __forceinline__ unsigned fkey(float f) {
    unsigned u = __float_as_uint(f);
    return (u & 0x80000000u) ? ~u : (u | 0x80000000u);
}
static __device__ __forceinline__ float fkey_inv(unsigned k) {
    unsigned u = (k & 0x80000000u) ? (k & 0x7FFFFFFFu) : ~k;
    return __uint_as_float(u);
}
static __device__ __forceinline__ unsigned short f2bf(float f) {
    unsigned u = __float_as_uint(f);
    u += 0x7FFFu + ((u >> 16) & 1u);   // RNE
    return (unsigned short)(u >> 16);
}
static __device__ __forceinline__ float bf2f(unsigned short b) {
    return __uint_as_float((unsigned)b << 16);
}
// tanh(x) = 1 - 2/(e^{2x}+1); hardware exp + rcp, abs err ~2e-7, correct limits.
static __device__ __forceinline__ float ftanh(float x) {
    float e = __expf(2.0f * x);
    return 1.0f - 2.0f / (e + 1.0f);
}

// ---------------- CSR build ----------------
__global__ void k_hist(const int* __restrict__ dst, int* __restrict__ cnt, int ne) {
    int e = blockIdx.x * 256 + threadIdx.x;
    if (e < ne) atomicAdd(&cnt[dst[e]], 1);
}

__global__ __launch_bounds__(1024) void k_scanA(const int* __restrict__ cnt,
                                                int* __restrict__ part,
                                                int* __restrict__ bsum, int n) {
    __shared__ int sh[1024];
    int t = threadIdx.x;
    int i = blockIdx.x * 1024 + t;
    int v = (i < n) ? cnt[i] : 0;
    sh[t] = v; __syncthreads();
    for (int off = 1; off < 1024; off <<= 1) {
        int u = (t >= off) ? sh[t - off] : 0;
        __syncthreads();
        sh[t] += u;
        __syncthreads();
    }
    if (i < n) part[i] = sh[t] - v;
    if (t == 1023) bsum[blockIdx.x] = sh[1023];
}

__global__ __launch_bounds__(1024) void k_scanB(int* __restrict__ bsum, int nb) {
    __shared__ int sh[1024];
    int t = threadIdx.x;
    int v = (t < nb) ? bsum[t] : 0;
    sh[t] = v; __syncthreads();
    for (int off = 1; off < 1024; off <<= 1) {
        int u = (t >= off) ? sh[t - off] : 0;
        __syncthreads();
        sh[t] += u;
        __syncthreads();
    }
    if (t < nb) bsum[t] = sh[t] - v;
}

__global__ void k_scanC(const int* __restrict__ part, const int* __restrict__ bsum,
                        int* __restrict__ rowptr, int* __restrict__ cursor, int n, int total) {
    int i = blockIdx.x * 256 + threadIdx.x;
    if (i < n) {
        int v = part[i] + bsum[i >> 10];
        rowptr[i] = v;
        cursor[i] = v;
    }
    if (i == 0) rowptr[n] = total;
}

// scatter; optionally also emits colm[pos] = src % NN (for stage-2 L0 gather)
__global__ void k_scatter(const int* __restrict__ src, const int* __restrict__ dst,
                          int* __restrict__ cursor, int* __restrict__ col,
                          int* __restrict__ colm, int ne) {
    int e = blockIdx.x * 256 + threadIdx.x;
    if (e >= ne) return;
    int s = src[e];
    int pos = atomicAdd(&cursor[dst[e]], 1);
    col[pos] = s;
    if (colm) colm[pos] = s % NN;
}

// ---------------- stage-1 layer a ----------------
__global__ __launch_bounds__(256) void k_agg16(const float* __restrict__ h,
                                               const int* __restrict__ rowptr,
                                               const int* __restrict__ col,
                                               float* __restrict__ agg, float* __restrict__ deg,
                                               int nrows) {
    int i = blockIdx.x * 256 + threadIdx.x;
    int r = i >> 4, j = i & 15;
    if (r >= nrows) return;
    int b = rowptr[r], e = rowptr[r + 1];
    float a = h[r * 16 + j];
    for (int q = b; q < e; ++q) a += h[col[q] * 16 + j];
    agg[r * 16 + j] = a;
    if (j == 0) deg[r] = 1.0f + (float)(e - b);
}

__global__ __launch_bounds__(256) void k_sage16(
    const float* __restrict__ h, const float* __restrict__ agg, const float* __restrict__ deg,
    const float* __restrict__ Wl, const float* __restrict__ Wr, const float* __restrict__ bl,
    float* __restrict__ y, int nrows)
{
    __shared__ float WlS[16][128], WrS[16][128];
    int tid = threadIdx.x;
    for (int i = tid; i < 16 * 128; i += 256) {
        WlS[i >> 7][i & 127] = Wl[i];
        WrS[i >> 7][i & 127] = Wr[i];
    }
    __syncthreads();
    long long o = (long long)blockIdx.x * 256 + tid;
    int row = (int)(o >> 7);
    if (row >= nrows) return;
    int d = (int)o & 127;
    float invd = 1.0f / fmaxf(deg[row], 1.0f);
    float s = bl[d];
    #pragma unroll
    for (int k = 0; k < 16; ++k)
        s += agg[row * 16 + k] * invd * WlS[k][d] + h[row * 16 + k] * WrS[k][d];
    y[(long long)row * 128 + d] = ftanh(s);
}

// ---------------- stage-1 CSR gather-aggregate (fp32 out) ----------------
__global__ __launch_bounds__(256) void k_aggf0(
    const float* __restrict__ x,
    const int* __restrict__ rowptr, const int* __restrict__ col,
    float* __restrict__ AGG, int nrowsC)
{
    int tid = threadIdx.x;
    int r = blockIdx.x * 8 + (tid >> 5);
    if (r >= nrowsC) return;
    int lane = tid & 31;
    int b = rowptr[r], e = rowptr[r + 1];
    float4 a = *reinterpret_cast<const float4*>(x + (long long)r * 128 + lane * 4);
    float dsum = 1.0f + (float)(e - b);
    for (int q = b; q < e; ++q) {
        int s = col[q];
        float4 v = *reinterpret_cast<const float4*>(x + (long long)s * 128 + lane * 4);
        a.x += v.x; a.y += v.y; a.z += v.z; a.w += v.w;
    }
    float invds = 1.0f / fmaxf(dsum, 1.0f);
    a.x *= invds; a.y *= invds; a.z *= invds; a.w *= invds;
    *reinterpret_cast<float4*>(AGG + (long long)r * 128 + lane * 4) = a;
}

// ---------------- stage-2 CSR gather-aggregate (bf16 in/out; fvec NaN = dead) ----------------
__global__ __launch_bounds__(256) void k_aggf2(
    const unsigned short* __restrict__ x,
    const int* __restrict__ rowptr, const int* __restrict__ col,
    const int* __restrict__ aliveIdx, const float* __restrict__ fvec,
    int rowbase,
    unsigned short* __restrict__ AGGb, int nrowsC)
{
    int tid = threadIdx.x;
    int r = blockIdx.x * 8 + (tid >> 5);
    if (r >= nrowsC) return;
    int lane = tid & 31;
    int orig = aliveIdx[r];
    int grow = rowbase + orig;
    int b = rowptr[grow], e = rowptr[grow + 1];
    float4 a = make_float4(0.0f, 0.0f, 0.0f, 0.0f);
    float dsum = 0.0f;
    for (int q = b; q < e; ++q) {
        int fr = col[q] - rowbase;
        float fw = fvec[fr];
        if (fw != fw) continue;      // NaN = dead
        dsum += 1.0f;
        if (fw == 0.0f) continue;
        ushort4 v = *reinterpret_cast<const ushort4*>(x + (long long)fr * 128 + lane * 4);
        a.x += bf2f(v.x) * fw; a.y += bf2f(v.y) * fw;
        a.z += bf2f(v.z) * fw; a.w += bf2f(v.w) * fw;
    }
    float invds = 1.0f / fmaxf(dsum, 1.0f);
    ushort4 o;
    o.x = f2bf(a.x * invds); o.y = f2bf(a.y * invds);
    o.z = f2bf(a.z * invds); o.w = f2bf(a.w * invds);
    *reinterpret_cast<ushort4*>(AGGb + (long long)r * 128 + lane * 4) = o;
}

// ---------------- dense SAGE GEMM (fp32 v2 tile) — stage-1 only ----------------
__global__ __launch_bounds__(256) void k_sage_d(
    const float* __restrict__ AGG, const float* __restrict__ xsrc,
    const float* __restrict__ Wl, const float* __restrict__ Wr, const float* __restrict__ bl,
    float* __restrict__ y, int nrowsC,
    const float* __restrict__ gw, float* __restrict__ gdot)
{
    __shared__ float Ws[32 * 128];
    __shared__ float Is[32][68];
    __shared__ float gwS[128];
    int tid = threadIdx.x;
    long long row0 = (long long)blockIdx.x * 64;
    if (tid < 128 && gw) gwS[tid] = gw[tid];
    __syncthreads();
    int tx = tid & 31, ty = tid >> 5;
    float gg4[4] = {0,0,0,0};
    if (gw) { gg4[0]=gwS[tx*4]; gg4[1]=gwS[tx*4+1]; gg4[2]=gwS[tx*4+2]; gg4[3]=gwS[tx*4+3]; }
    int srow = tid & 63;
    int koff = (tid >> 6) * 8;
    long long crow = row0 + srow;
    if (crow >= nrowsC) crow = nrowsC - 1;
    const float* selfp = xsrc + crow * 128;
    const float* aggp = AGG + crow * 128;

    float acc[8][4] = {};
    for (int kb = 0; kb < 8; ++kb) {
        __syncthreads();
        bool isAgg = (kb < 4);
        const float* Wsrc = isAgg ? (Wl + kb * 32 * 128) : (Wr + (kb - 4) * 32 * 128);
        #pragma unroll
        for (int j = 0; j < 4; ++j) {
            int fl = j * 1024 + tid * 4;
            *reinterpret_cast<float4*>(&Ws[fl]) = *reinterpret_cast<const float4*>(&Wsrc[fl]);
        }
        {
            const float* sp = (isAgg ? (aggp + kb * 32) : (selfp + (kb - 4) * 32)) + koff;
            float4 v0 = *reinterpret_cast<const float4*>(sp);
            float4 v1 = *reinterpret_cast<const float4*>(sp + 4);
            Is[koff + 0][srow] = v0.x; Is[koff + 1][srow] = v0.y;
            Is[koff + 2][srow] = v0.z; Is[koff + 3][srow] = v0.w;
            Is[koff + 4][srow] = v1.x; Is[koff + 5][srow] = v1.y;
            Is[koff + 6][srow] = v1.z; Is[koff + 7][srow] = v1.w;
        }
        __syncthreads();
        #pragma unroll
        for (int kk = 0; kk < 32; ++kk) {
            float4 wv = *reinterpret_cast<const float4*>(&Ws[kk * 128 + tx * 4]);
            float4 i0 = *reinterpret_cast<const float4*>(&Is[kk][ty * 8]);
            float4 i1 = *reinterpret_cast<const float4*>(&Is[kk][ty * 8 + 4]);
            float ia[8] = {i0.x, i0.y, i0.z, i0.w, i1.x, i1.y, i1.z, i1.w};
            float wa[4] = {wv.x, wv.y, wv.z, wv.w};
            #pragma unroll
            for (int i = 0; i < 8; ++i)
                #pragma unroll
                for (int j = 0; j < 4; ++j)
                    acc[i][j] += ia[i] * wa[j];
        }
    }
    float4 bl0 = *reinterpret_cast<const float4*>(&bl[tx * 4]);
    float br[4] = {bl0.x, bl0.y, bl0.z, bl0.w};
    #pragma unroll
    for (int i = 0; i < 8; ++i) {
        long long row = row0 + ty * 8 + i;
        bool valid = (row < nrowsC);
        float yv[4];
        #pragma unroll
        for (int j = 0; j < 4; ++j) yv[j] = ftanh(acc[i][j] + br[j]);
        if (valid)
            *reinterpret_cast<float4*>(&y[row * 128 + tx * 4]) = make_float4(yv[0], yv[1], yv[2], yv[3]);
        float gp = 0.0f;
        #pragma unroll
        for (int j = 0; j < 4; ++j) if (gdot) gp += yv[j] * gg4[j];
        #pragma unroll
        for (int m = 16; m >= 1; m >>= 1) if (gdot) gp += __shfl_xor(gp, m, 32);
        if (tx == 0 && valid && gdot) gdot[row] = gp;
    }
}

// ---------------- bf16 weight pack ----------------
__global__ void k_packW(const float* __restrict__ Wl, const float* __restrict__ Wr,
                        short* __restrict__ Wb) {
    int i = blockIdx.x * 256 + threadIdx.x;
    if (i >= 32768) return;
    int kt = i >> 12, rem = i & 4095;
    int ct = rem >> 9; rem &= 511;
    int lane = rem >> 3, e = rem & 7;
    int k = kt * 32 + (lane >> 4) * 8 + e;
    int c = ct * 16 + (lane & 15);
    float v = (k < 128) ? Wl[k * 128 + c] : Wr[(k - 128) * 128 + c];
    Wb[i] = (short)f2bf(v);
}

// ---------------- MFMA SAGE GEMM (stage-2 L1/L2): 16 rows/wave, 64 rows/block ----------------
__global__ __launch_bounds__(256) void k_sage_m(
    const unsigned short* __restrict__ AGGb, const unsigned short* __restrict__ X,
    const int* __restrict__ aliveIdx, const float* __restrict__ fvec,
    const short* __restrict__ Wb, const float* __restrict__ bl,
    unsigned short* __restrict__ y, int nrowsC,
    const float* __restrict__ wrel, const float* __restrict__ wroot, const float* __restrict__ gw,
    float* __restrict__ tbuf, float* __restrict__ rootd, float* __restrict__ gdot)
{
    __shared__ short8 lB[2048];
    int tid = threadIdx.x;
    int lane = tid & 63;
    int wv = tid >> 6;
    long long rows0 = (long long)blockIdx.x * 64 + wv * 16;
    int arow = lane & 15;
    int ksl = (lane >> 4) * 8;

    int growA = (int)(rows0 + arow);
    int origA = aliveIdx[growA];
    float fsA = fvec[origA];

    f32x4 acc[8] = {};
    const short8* Wbv = (const short8*)Wb;

    for (int half = 0; half < 2; ++half) {
        __syncthreads();
        #pragma unroll
        for (int i = 0; i < 8; ++i) {
            int idx = i * 256 + tid;
            lB[idx] = Wbv[half * 2048 + idx];
        }
        __syncthreads();
        #pragma unroll
        for (int ktl = 0; ktl < 4; ++ktl) {
            int kt = half * 4 + ktl;
            short8 afr;
            if (kt < 4) {
                afr = *reinterpret_cast<const short8*>(AGGb + (long long)growA * 128 + kt * 32 + ksl);
            } else {
                short8 xv = *reinterpret_cast<const short8*>(X + (long long)origA * 128 + (kt - 4) * 32 + ksl);
                #pragma unroll
                for (int e = 0; e < 8; ++e)
                    afr[e] = (short)f2bf(bf2f((unsigned short)xv[e]) * fsA);
            }
            #pragma unroll
            for (int ct = 0; ct < 8; ++ct) {
                short8 bfr = lB[(ktl * 8 + ct) * 64 + lane];
                acc[ct] = __builtin_amdgcn_mfma_f32_16x16x32_bf16(afr, bfr, acc[ct], 0, 0, 0);
            }
        }
    }

    int ocol = lane & 15;
    float blv[8], wrv[8], wov[8], ggv[8];
    #pragma unroll
    for (int ct = 0; ct < 8; ++ct) {
        int c = ct * 16 + ocol;
        blv[ct] = bl[c];
        wrv[ct] = wrel[c];
        wov[ct] = wroot[c];
        ggv[ct] = gw[c];
    }
    #pragma unroll
    for (int j = 0; j < 4; ++j) {
        int rloc = (lane >> 4) * 4 + j;
        long long grow = rows0 + rloc;
        int orig = aliveIdx[grow];
        float tp = 0.0f, rp = 0.0f, gp = 0.0f;
        #pragma unroll
        for (int ct = 0; ct < 8; ++ct) {
            float v = ftanh(acc[ct][j] + blv[ct]);
            y[(long long)orig * 128 + ct * 16 + ocol] = f2bf(v);
            tp += v * wrv[ct]; rp += v * wov[ct]; gp += v * ggv[ct];
        }
        #pragma unroll
        for (int mm = 8; mm >= 1; mm >>= 1) {
            tp += __shfl_xor(tp, mm, 16);
            rp += __shfl_xor(rp, mm, 16);
            gp += __shfl_xor(gp, mm, 16);
        }
        if (ocol == 0) { tbuf[orig] = tp; rootd[orig] = rp; gdot[orig] = gp; }
    }
}

// ---------------- plain GEMM: y = x@W (+ b), v2 tile ----------------
__global__ __launch_bounds__(256) void k_gemm_self(
    const float* __restrict__ x, const float* __restrict__ W, const float* __restrict__ b,
    float* __restrict__ y, int nrows)
{
    __shared__ float Ws[32 * 128];
    __shared__ float Is[32][68];
    int tid = threadIdx.x;
    long long row0 = (long long)blockIdx.x * 64;
    int tx = tid & 31, ty = tid >> 5;
    int srow = tid & 63;
    int koff = (tid >> 6) * 8;
    long long lrow = row0 + srow;
    if (lrow >= nrows) lrow = nrows - 1;
    const float* xrow = x + lrow * 128;
    float acc[8][4] = {};
    for (int kb = 0; kb < 4; ++kb) {
        __syncthreads();
        const float* Wsrc = W + kb * 32 * 128;
        #pragma unroll
        for (int j = 0; j < 4; ++j) {
            int fl = j * 1024 + tid * 4;
            *reinterpret_cast<float4*>(&Ws[fl]) = *reinterpret_cast<const float4*>(&Wsrc[fl]);
        }
        {
            const float* sp = xrow + kb * 32 + koff;
            float4 v0 = *reinterpret_cast<const float4*>(sp);
            float4 v1 = *reinterpret_cast<const float4*>(sp + 4);
            Is[koff + 0][srow] = v0.x; Is[koff + 1][srow] = v0.y;
            Is[koff + 2][srow] = v0.z; Is[koff + 3][srow] = v0.w;
            Is[koff + 4][srow] = v1.x; Is[koff + 5][srow] = v1.y;
            Is[koff + 6][srow] = v1.z; Is[koff + 7][srow] = v1.w;
        }
        __syncthreads();
        #pragma unroll
        for (int kk = 0; kk < 32; ++kk) {
            float4 wv = *reinterpret_cast<const float4*>(&Ws[kk * 128 + tx * 4]);
            float4 i0 = *reinterpret_cast<const float4*>(&Is[kk][ty * 8]);
            float4 i1 = *reinterpret_cast<const float4*>(&Is[kk][ty * 8 + 4]);
            float ia[8] = {i0.x, i0.y, i0.z, i0.w, i1.x, i1.y, i1.z, i1.w};
            float wa[4] = {wv.x, wv.y, wv.z, wv.w};
            #pragma unroll
            for (int i = 0; i < 8; ++i)
                #pragma unroll
                for (int j = 0; j < 4; ++j)
                    acc[i][j] += ia[i] * wa[j];
        }
    }
    float4 b0 = b ? *reinterpret_cast<const float4*>(&b[tx * 4]) : make_float4(0.f, 0.f, 0.f, 0.f);
    #pragma unroll
    for (int i = 0; i < 8; ++i) {
        long long row = row0 + ty * 8 + i;
        if (row >= nrows) continue;
        *reinterpret_cast<float4*>(&y[row * 128 + tx * 4]) =
            make_float4(acc[i][0] + b0.x, acc[i][1] + b0.y, acc[i][2] + b0.z, acc[i][3] + b0.w);
    }
}

// ---------------- stage-2 L0 combine (bf16 X out; colm pre-modded) ----------------
__global__ __launch_bounds__(256) void k_l0comb(
    const float* __restrict__ ZL0, const float* __restrict__ zself,
    const int* __restrict__ rowptr, const int* __restrict__ colm, int rowbase,
    const float* __restrict__ wrel, const float* __restrict__ wroot, const float* __restrict__ gw,
    unsigned short* __restrict__ y, float* __restrict__ tbuf, float* __restrict__ rootd, float* __restrict__ gdot,
    int nrowsC)
{
    __shared__ float wrelS[128], wrootS[128], gwS[128];
    int tid = threadIdx.x;
    if (tid < 128) {
        wrelS[tid]  = wrel[tid];
        wrootS[tid] = wroot[tid];
        gwS[tid]    = gw[tid];
    }
    __syncthreads();
    int r = blockIdx.x * 8 + (tid >> 5);
    if (r >= nrowsC) return;
    int lane = tid & 31;
    int grow = rowbase + r;
    int b = rowptr[grow], e = rowptr[grow + 1];
    float4 a = make_float4(0.0f, 0.0f, 0.0f, 0.0f);
    for (int q = b; q < e; ++q) {
        int fr = colm[q];
        float4 v = *reinterpret_cast<const float4*>(ZL0 + (long long)fr * 128 + lane * 4);
        a.x += v.x; a.y += v.y; a.z += v.z; a.w += v.w;
    }
    float invds = 1.0f / fmaxf((float)(e - b), 1.0f);
    const float4 z = *reinterpret_cast<const float4*>(zself + (long long)(r % NN) * 128 + lane * 4);
    float yv[4];
    yv[0] = ftanh(a.x * invds + z.x);
    yv[1] = ftanh(a.y * invds + z.y);
    yv[2] = ftanh(a.z * invds + z.z);
    yv[3] = ftanh(a.w * invds + z.w);
    ushort4 o;
    o.x = f2bf(yv[0]); o.y = f2bf(yv[1]); o.z = f2bf(yv[2]); o.w = f2bf(yv[3]);
    *reinterpret_cast<ushort4*>(y + (long long)r * 128 + lane * 4) = o;
    float tp = 0.0f, rp = 0.0f, gp = 0.0f;
    #pragma unroll
    for (int j = 0; j < 4; ++j) {
        tp += yv[j] * wrelS[lane*4 + j];
        rp += yv[j] * wrootS[lane*4 + j];
        gp += yv[j] * gwS[lane*4 + j];
    }
    #pragma unroll
    for (int m = 16; m >= 1; m >>= 1) {
        tp += __shfl_xor(tp, m, 32);
        rp += __shfl_xor(rp, m, 32);
        gp += __shfl_xor(gp, m, 32);
    }
    if (lane == 0) {
        tbuf[r]  = tp;
        rootd[r] = rp;
        gdot[r]  = gp;
    }
}

// ---------------- stage-1 readout pieces ----------------
__global__ __launch_bounds__(256) void k_gate(
    const float* __restrict__ X, const float* __restrict__ gw,
    float* __restrict__ g, int nrows)
{
    __shared__ float wS[128];
    if (threadIdx.x < 128) wS[threadIdx.x] = gw[threadIdx.x];
    __syncthreads();
    int i = blockIdx.x * 256 + threadIdx.x;
    if (i >= nrows) return;
    const float4* xrp = reinterpret_cast<const float4*>(X + (long long)i * 128);
    float s = 0.0f;
    #pragma unroll
    for (int k = 0; k < 32; ++k) {
        float4 v = xrp[k];
        s += v.x * wS[4*k] + v.y * wS[4*k+1] + v.z * wS[4*k+2] + v.w * wS[4*k+3];
    }
    g[i] = s;
}

__global__ __launch_bounds__(1024) void k_smstats(float* __restrict__ g, float* __restrict__ invp) {
    __shared__ float red[1024];
    int p = blockIdx.x, tid = threadIdx.x;
    float* gp = g + (long long)p * NN;
    float lmax = -INFINITY;
    for (int n = tid; n < NN; n += 1024) lmax = fmaxf(lmax, gp[n]);
    red[tid] = lmax; __syncthreads();
    for (int s = 512; s > 0; s >>= 1) { if (tid < s) red[tid] = fmaxf(red[tid], red[tid + s]); __syncthreads(); }
    float mx = red[0]; __syncthreads();
    float ls = 0.0f;
    for (int n = tid; n < NN; n += 1024) { float e = __expf(gp[n] - mx); gp[n] = e; ls += e; }
    red[tid] = ls; __syncthreads();
    for (int s = 512; s > 0; s >>= 1) { if (tid < s) red[tid] += red[tid + s]; __syncthreads(); }
    if (tid == 0) invp[p] = 1.0f / red[0];
}

__global__ __launch_bounds__(128) void k_wsum(
    const float* __restrict__ X, const float* __restrict__ a,
    const float* __restrict__ invp, float* __restrict__ ro, int rowbase, int colOff)
{
    int p = blockIdx.x / BPG;
    int chunk = blockIdx.x % BPG;
    int d = threadIdx.x;
    long long base = (long long)p * NN;
    int r0 = chunk * RB, r1 = r0 + RB;
    float s = 0.0f;
    for (int n = r0; n < r1; ++n) {
        float w = a[base + n];
        if (w != 0.0f) s += w * X[(base + n) * 128 + d];
    }
    atomicAdd(&ro[(long long)(rowbase + p) * 384 + colOff + d], s * invp[p]);
}

// stage-2 weighted sum over alive rows only (bf16 X)
__global__ __launch_bounds__(128) void k_wsum_c(
    const unsigned short* __restrict__ X, const float* __restrict__ gbuf, const float* __restrict__ fvec,
    const float* __restrict__ invp, const int* __restrict__ aliveIdx, int k,
    float* __restrict__ ro, int rowbaseRo, int colOff)
{
    int bpp = k / RB;
    int p = blockIdx.x / bpp;
    int chunk = blockIdx.x % bpp;
    int d = threadIdx.x;
    const int* ai = aliveIdx + (long long)p * k + chunk * RB;
    float s = 0.0f;
    for (int j = 0; j < RB; ++j) {
        int row = ai[j];
        float w = gbuf[row] * fvec[row];
        s += w * bf2f(X[(long long)row * 128 + d]);
    }
    atomicAdd(&ro[(long long)(rowbaseRo + p) * 384 + colOff + d], s * invp[p]);
}

// ---------------- GraphNorm ----------------
__global__ void k_colstat(const float* __restrict__ x, float* __restrict__ musum,
                          float* __restrict__ sqsum, int nrows) {
    int d = threadIdx.x;
    int r0 = blockIdx.x * 64;
    int r1 = min(r0 + 64, nrows);
    float s = 0.0f, q = 0.0f;
    for (int r = r0; r < r1; ++r) { float v = x[(long long)r * 128 + d]; s += v; q += v * v; }
    atomicAdd(&musum[d], s);
    atomicAdd(&sqsum[d], q);
}

__global__ void k_gnorm_apply(const float* __restrict__ x, float* __restrict__ y,
                              const float* __restrict__ musum, const float* __restrict__ sqsum,
                              const float* __restrict__ w, const float* __restrict__ b,
                              const float* __restrict__ ms, int nrows) {
    long long i = (long long)blockIdx.x * 256 + threadIdx.x;
    if (i >= (long long)nrows * 128) return;
    int d = (int)(i & 127);
    float inv_n = 1.0f / (float)nrows;
    float mu = musum[d] * inv_n;
    float c = mu * ms[d];
    float var = sqsum[d] * inv_n - 2.0f * c * mu + c * c;
    y[i] = w[d] * (x[i] - c) * rsqrtf(var + 1e-5f) + b[d];
}

// ---------------- parallel score+key (fvec NaN = dead) ----------------
__global__ __launch_bounds__(256) void k_score2(
    const int* __restrict__ rowptr, const int* __restrict__ col, int rowbase,
    const float* __restrict__ tb, const float* __restrict__ rootd,
    const float* __restrict__ brelp, int bi, int allAlive,
    const float* __restrict__ fvec, unsigned* __restrict__ keysG, int n)
{
    int r = blockIdx.x * 256 + threadIdx.x;
    if (r >= n) return;
    int grow = rowbase + r;
    float s = brelp[bi] + rootd[r];
    int b = rowptr[grow], e = rowptr[grow + 1];
    if (allAlive) {
        for (int q = b; q < e; ++q) s += tb[col[q] - rowbase];
        keysG[r] = fkey(s);
    } else {
        for (int q = b; q < e; ++q) {
            int sl = col[q] - rowbase;
            float fw = fvec[sl];
            if (fw == fw) s += tb[sl];
        }
        float fs = fvec[r];
        keysG[r] = (fs == fs) ? fkey(s) : 0u;
    }
}

// ---------------- barrier-light top-k (keys precomputed; writes fvec NaN-coded) ----------------
__global__ __launch_bounds__(1024) void k_topk3(
    const unsigned* __restrict__ keysG, const float* __restrict__ gdot,
    float* __restrict__ fvec, float* __restrict__ gbuf,
    float* __restrict__ invp, int* __restrict__ aliveIdx, int k)
{
    __shared__ unsigned keys[NN];
    __shared__ int hist[256];
    __shared__ int wred[16];
    __shared__ float wredf[16];
    __shared__ unsigned sh_pref;
    __shared__ int sh_kneed;
    int p = blockIdx.x, tid = threadIdx.x;
    int lane = tid & 63, wid = tid >> 6;
    long long pbase = (long long)p * NN;
    const uint4* kg = reinterpret_cast<const uint4*>(keysG + pbase);
    for (int i = tid; i < NN / 4; i += 1024)
        *reinterpret_cast<uint4*>(&keys[i * 4]) = kg[i];
    if (tid == 0) { sh_pref = 0u; sh_kneed = k; }
    __syncthreads();

    for (int lvl = 3; lvl >= 0; --lvl) {
        int sh = lvl * 8;
        if (tid < 256) hist[tid] = 0;
        unsigned pref = sh_pref; int kneed = sh_kneed;
        unsigned pmask = (lvl == 3) ? 0u : (0xFFFFFFFFu << (8 * (lvl + 1)));
        __syncthreads();
        for (int n = tid; n < NN; n += 1024) {
            unsigned kv = keys[n];
            if ((kv & pmask) == pref) atomicAdd(&hist[(kv >> sh) & 255], 1);
        }
        __syncthreads();
        if (wid == 0) {
            int b0 = 252 - 4 * lane;
            int h0 = hist[b0], h1 = hist[b0 + 1], h2 = hist[b0 + 2], h3 = hist[b0 + 3];
            int s3 = h3, s2 = h2 + s3, s1 = h1 + s2, s0 = h0 + s1;
            int gs = s0;
            #pragma unroll
            for (int d = 1; d < 64; d <<= 1) {
                int u = __shfl_up(gs, d, 64);
                if (lane >= d) gs += u;
            }
            int above = gs - s0;
            int suf0 = above + s0, suf1 = above + s1, suf2 = above + s2, suf3 = above + s3;
            if (suf0 >= kneed && suf0 - h0 < kneed) { sh_pref = pref | ((unsigned)b0 << sh); sh_kneed = kneed - (suf0 - h0); }
            if (suf1 >= kneed && suf1 - h1 < kneed) { sh_pref = pref | ((unsigned)(b0+1) << sh); sh_kneed = kneed - (suf1 - h1); }
            if (suf2 >= kneed && suf2 - h2 < kneed) { sh_pref = pref | ((unsigned)(b0+2) << sh); sh_kneed = kneed - (suf2 - h2); }
            if (suf3 >= kneed && suf3 - h3 < kneed) { sh_pref = pref | ((unsigned)(b0+3) << sh); sh_kneed = kneed - (suf3 - h3); }
        }
        __syncthreads();
    }

    unsigned V = sh_pref;
    int seleq = sh_kneed;
    int c0 = tid * 8;
    int ceq = 0;
    #pragma unroll
    for (int j = 0; j < 8; ++j) {
        int n = c0 + j;
        if (n < NN) ceq += (keys[n] == V) ? 1 : 0;
    }
    int vv = ceq;
    #pragma unroll
    for (int d = 1; d < 64; d <<= 1) {
        int u = __shfl_up(vv, d, 64);
        if (lane >= d) vv += u;
    }
    if (lane == 63) wred[wid] = vv;
    __syncthreads();
    if (tid < 16) {
        int w = wred[tid];
        #pragma unroll
        for (int d = 1; d < 16; d <<= 1) {
            int u = __shfl_up(w, d, 16);
            if (tid >= d) w += u;
        }
        wred[tid] = w;
    }
    __syncthreads();
    int rank = vv - ceq + (wid > 0 ? wred[wid - 1] : 0);

    unsigned selmask = 0u;
    int nsel = 0;
    float lmax = -INFINITY;
    #pragma unroll
    for (int j = 0; j < 8; ++j) {
        int n = c0 + j;
        if (n >= NN) break;
        unsigned kk = keys[n];
        bool sel = (kk > V) || (kk == V && rank < seleq);
        if (kk == V) rank++;
        long long gl = pbase + n;
        float f = FNAN;
        if (sel) {
            f = ftanh(fkey_inv(kk));
            lmax = fmaxf(lmax, f * gdot[gl]);
            selmask |= (1u << j);
            ++nsel;
        }
        fvec[gl] = f;
    }
    #pragma unroll
    for (int d = 32; d >= 1; d >>= 1) lmax = fmaxf(lmax, __shfl_xor(lmax, d, 64));
    if (lane == 0) wredf[wid] = lmax;
    __syncthreads();
    if (tid < 16) {
        float m = wredf[tid];
        #pragma unroll
        for (int d = 8; d >= 1; d >>= 1) m = fmaxf(m, __shfl_xor(m, d, 16));
        if (tid == 0) wredf[0] = m;
    }
    __syncthreads();
    float mx = wredf[0];
    __syncthreads();
    int v2 = nsel;
    #pragma unroll
    for (int d = 1; d < 64; d <<= 1) {
        int u = __shfl_up(v2, d, 64);
        if (lane >= d) v2 += u;
    }
    if (lane == 63) wred[wid] = v2;
    __syncthreads();
    if (tid < 16) {
        int w = wred[tid];
        #pragma unroll
        for (int d = 1; d < 16; d <<= 1) {
            int u = __shfl_up(w, d, 16);
            if (tid >= d) w += u;
        }
        wred[tid] = w;
    }
    __syncthreads();
    int pos = v2 - nsel + (wid > 0 ? wred[wid - 1] : 0);

    float lsum = 0.0f;
    #pragma unroll
    for (int j = 0; j < 8; ++j) {
        if (selmask & (1u << j)) {
            int n = c0 + j;
            long long gl = pbase + n;
            float e = __expf(fvec[gl] * gdot[gl] - mx);
            gbuf[gl] = e;
            lsum += e;
            aliveIdx[(long long)p * k + pos] = (int)gl;
            ++pos;
        }
    }
    #pragma unroll
    for (int d = 32; d >= 1; d >>= 1) lsum += __shfl_xor(lsum, d, 64);
    if (lane == 0) wredf[wid] = lsum;
    __syncthreads();
    if (tid < 16) {
        float s = wredf[tid];
        #pragma unroll
        for (int d = 8; d >= 1; d >>= 1) s += __shfl_xor(s, d, 16);
        if (tid == 0) invp[p] = 1.0f / s;
    }
}

// ---------------- head ----------------
__global__ __launch_bounds__(64) void k_head(
    const float* __restrict__ ro, const float* __restrict__ lin_w, const float* __restrict__ lin_b,
    const float* __restrict__ m1w, const float* __restrict__ m1b,
    const float* __restrict__ m2w, const float* __restrict__ m2b,
    const float* __restrict__ m3w, const float* __restrict__ m3b, float* __restrict__ out)
{
    __shared__ float v[33], h1[48], h2[16];
    int t = threadIdx.x;
    if (t < 33) {
        float s = lin_b[0];
        for (int k = 0; k < 384; ++k) s += ro[t * 384 + k] * lin_w[k];
        v[t] = tanhf(s);
    }
    __syncthreads();
    if (t < 48) {
        float s = m1b[t];
        for (int i = 0; i < 33; ++i) s += v[i] * m1w[i * 48 + t];
        h1[t] = tanhf(s);
    }
    __syncthreads();
    if (t < 16) {
        float s = m2b[t];
        for (int i = 0; i < 48; ++i) s += h1[i] * m2w[i * 16 + t];
        h2[t] = tanhf(s);
    }
    __syncthreads();
    if (t == 0) {
        float s = m3b[0];
        for (int i = 0; i < 16; ++i) s += h2[i] * m3w[i];
        float s1 = 1.0f / (1.0f + expf(-s));
        out[0] = 1.0f / (1.0f + expf(-s1));
    }
}

static inline int cdiv(long long a, long long b) { return (int)((a + b - 1) / b); }

extern "C" void kernel_launch(void* const* d_in, const int* in_sizes, int n_in,
                              void* d_out, int out_size, void* d_ws, size_t ws_size,
                              hipStream_t stream)
{
    (void)in_sizes; (void)n_in; (void)out_size;
    const float* h     = (const float*)d_in[0];
    const int*   eidx  = (const int*)d_in[1];
    const int*   seidx = (const int*)d_in[2];
    const float* Wl_a  = (const float*)d_in[3];
    const float* Wr_a  = (const float*)d_in[4];
    const float* bl_a  = (const float*)d_in[5];
    const float* Wl_s  = (const float*)d_in[6];
    const float* Wr_s  = (const float*)d_in[7];
    const float* bl_s  = (const float*)d_in[8];
    const float* gate_w = (const float*)d_in[9];
    const float* p_wrel = (const float*)d_in[11];
    const float* p_brel = (const float*)d_in[12];
    const float* p_wroot= (const float*)d_in[13];
    const float* nw    = (const float*)d_in[14];
    const float* nb    = (const float*)d_in[15];
    const float* nms   = (const float*)d_in[16];
    const float* lin_w = (const float*)d_in[17];
    const float* lin_b = (const float*)d_in[18];
    const float* m1w   = (const float*)d_in[19];
    const float* m1b   = (const float*)d_in[20];
    const float* m2w   = (const float*)d_in[21];
    const float* m2b   = (const float*)d_in[22];
    const float* m3w   = (const float*)d_in[23];
    const float* m3b   = (const float*)d_in[24];
    float* out = (float*)d_out;

    const int* esrc = eidx;
    const int* edst = eidx + EG;
    const int* ssrc = seidx;
    const int* sdst = seidx + ES_TOT;

    auto need_bytes = [](int chp) -> size_t {
        long long chn = (long long)chp * NN;
        long long f = chn * 64
                    + (long long)chp * KK1 * 64
                    + 2LL * NN * 128
                    + 4 * chn                   // tbuf, rootd, fvec, gdot
                    + chn                       // keysG
                    + 64 + 33 * 384
                    + (long long)chp * KK1
                    + (PN + 1) + 2 * ES_TOT     // s2rp, s2col, s2colm
                    + 2 * 16384
                    + 64 * 28;
        return (size_t)f * 4;
    };
    int chp = 8;
    if (ws_size >= need_bytes(32)) chp = 32;
    else if (ws_size >= need_bytes(16)) chp = 16;
    int nch = PP / chp;
    long long ch_n = (long long)chp * NN;

    float* W = (float*)d_ws;
    size_t off = 0;
    auto alloc = [&](size_t nf) { float* p = W + off; off += (nf + 63) & ~(size_t)63; return p; };
    unsigned short* XAb = (unsigned short*)alloc((size_t)ch_n * 64);
    unsigned short* AGGb = (unsigned short*)alloc((size_t)chp * KK1 * 64);
    float* ZL0   = alloc((size_t)NN * DD);
    float* zself = alloc((size_t)NN * DD);
    float* tbuf  = alloc(ch_n);
    float* rootd = alloc(ch_n);
    float* fvec  = alloc(ch_n);
    float* gdot  = alloc(ch_n);
    unsigned* keysG = (unsigned*)alloc(ch_n);
    float* invp  = alloc(64);
    float* ro    = alloc(33 * 384);
    int* aliveIdx = (int*)alloc((size_t)chp * KK1);
    int* s2rp    = (int*)alloc(PN + 1);
    int* s2col   = (int*)alloc(ES_TOT);
    int* s2colm  = (int*)alloc(ES_TOT);
    short* Wb1   = (short*)alloc(16384);
    short* Wb2   = (short*)alloc(16384);
    float* gbuf = tbuf;

    // overlay inside XAb (dead before XAb's first write)
    float* XO = (float*)XAb;
    size_t ooff = 0;
    auto oalloc = [&](size_t nf) { float* p = XO + ooff; ooff += (nf + 63) & ~(size_t)63; return p; };
    float* xa    = oalloc((size_t)NN * DD);
    float* xb    = oalloc((size_t)NN * DD);
    float* AGGs  = oalloc((size_t)NN * DD);
    float* agg1  = oalloc((size_t)NN * 16);
    float* deg1  = oalloc(NN);
    float* musum = oalloc(128);
    float* sqsum = oalloc(128);
    int* s1cnt  = (int*)oalloc(NN);
    int* s1rp   = (int*)oalloc(NN + 1);
    int* s1cur  = (int*)oalloc(NN);
    int* s1col  = (int*)oalloc(EG);
    int* s1part = (int*)oalloc(NN);
    int* s1bsum = (int*)oalloc(1024);
    int* s2cnt  = (int*)oalloc(PN);
    int* s2cur  = (int*)oalloc(PN);
    int* s2part = (int*)oalloc(PN);
    int* s2bsum = (int*)oalloc(1024);

    // ---------- CSR builds ----------
    int nb1 = cdiv(NN, 1024), nb2 = cdiv(PN, 1024);
    hipMemsetAsync(s1cnt, 0, NN * sizeof(int), stream);
    k_hist<<<cdiv(EG,256),256,0,stream>>>(edst, s1cnt, EG);
    k_scanA<<<nb1,1024,0,stream>>>(s1cnt, s1part, s1bsum, NN);
    k_scanB<<<1,1024,0,stream>>>(s1bsum, nb1);
    k_scanC<<<cdiv(NN,256),256,0,stream>>>(s1part, s1bsum, s1rp, s1cur, NN, EG);
    k_scatter<<<cdiv(EG,256),256,0,stream>>>(esrc, edst, s1cur, s1col, (int*)nullptr, EG);

    hipMemsetAsync(s2cnt, 0, (size_t)PN * sizeof(int), stream);
    k_hist<<<cdiv(ES_TOT,256),256,0,stream>>>(sdst, s2cnt, ES_TOT);
    k_scanA<<<nb2,1024,0,stream>>>(s2cnt, s2part, s2bsum, PN);
    k_scanB<<<1,1024,0,stream>>>(s2bsum, nb2);
    k_scanC<<<cdiv(PN,256),256,0,stream>>>(s2part, s2bsum, s2rp, s2cur, PN, ES_TOT);
    k_scatter<<<cdiv(ES_TOT,256),256,0,stream>>>(ssrc, sdst, s2cur, s2col, s2colm, ES_TOT);

    hipMemsetAsync(ro, 0, 33 * 384 * sizeof(float), stream);

    k_packW<<<128,256,0,stream>>>(Wl_s + 3*16384, Wr_s + 3*16384, Wb1);
    k_packW<<<128,256,0,stream>>>(Wl_s + 4*16384, Wr_s + 4*16384, Wb2);

    // ---------- stage 1 ----------
    k_agg16<<<cdiv((long long)NN*16,256),256,0,stream>>>(h, s1rp, s1col, agg1, deg1, NN);
    k_sage16<<<cdiv((long long)NN*DD,256),256,0,stream>>>(h, agg1, deg1, Wl_a, Wr_a, bl_a, xa, NN);
    k_gate<<<cdiv(NN,256),256,0,stream>>>(xa, gate_w + 0*DD, gbuf, NN);
    k_smstats<<<1,1024,0,stream>>>(gbuf, invp);
    k_wsum<<<BPG,128,0,stream>>>(xa, gbuf, invp, ro, 0, 0);

    hipMemsetAsync(musum, 0, 128*sizeof(float), stream);
    hipMemsetAsync(sqsum, 0, 128*sizeof(float), stream);
    k_colstat<<<cdiv(NN,64),128,0,stream>>>(xa, musum, sqsum, NN);
    k_gnorm_apply<<<cdiv((long long)NN*DD,256),256,0,stream>>>(xa, xb, musum, sqsum, nw, nb, nms, NN);

    k_aggf0<<<cdiv(NN,8),256,0,stream>>>(xb, s1rp, s1col, AGGs, NN);
    k_sage_d<<<cdiv(NN,64),256,0,stream>>>(AGGs, xb,
        Wl_s + 0*16384, Wr_s + 0*16384, bl_s + 0*128, xa, NN,
        gate_w + 1*DD, gbuf);
    k_smstats<<<1,1024,0,stream>>>(gbuf, invp);
    k_wsum<<<BPG,128,0,stream>>>(xa, gbuf, invp, ro, 0, 128);

    hipMemsetAsync(musum, 0, 128*sizeof(float), stream);
    hipMemsetAsync(sqsum, 0, 128*sizeof(float), stream);
    k_colstat<<<cdiv(NN,64),128,0,stream>>>(xa, musum, sqsum, NN);
    k_gnorm_apply<<<cdiv((long long)NN*DD,256),256,0,stream>>>(xa, xb, musum, sqsum, nw, nb, nms, NN);

    k_aggf0<<<cdiv(NN,8),256,0,stream>>>(xb, s1rp, s1col, AGGs, NN);
    k_sage_d<<<cdiv(NN,64),256,0,stream>>>(AGGs, xb,
        Wl_s + 1*16384, Wr_s + 1*16384, bl_s + 1*128, xa, NN,
        gate_w + 2*DD, gbuf);
    k_smstats<<<1,1024,0,stream>>>(gbuf, invp);
    k_wsum<<<BPG,128,0,stream>>>(xa, gbuf, invp, ro, 0, 256);

    // ---------- stage 2 ----------
    k_gemm_self<<<cdiv(NN,64),256,0,stream>>>(xa, Wl_s + 2*16384, nullptr, ZL0, NN);
    k_gemm_self<<<cdiv(NN,64),256,0,stream>>>(xa, Wr_s + 2*16384, bl_s + 2*128, zself, NN);

    for (int c = 0; c < nch; ++c) {
        int nbase = (int)(c * ch_n);

        k_l0comb<<<(int)(ch_n/8),256,0,stream>>>(ZL0, zself, s2rp, s2colm, nbase,
            p_wrel + 0*DD, p_wroot + 0*DD, gate_w + 3*DD,
            XAb, tbuf, rootd, gdot, (int)ch_n);
        k_score2<<<(int)(ch_n/256),256,0,stream>>>(s2rp, s2col, nbase, tbuf, rootd, p_brel, 0, 1,
                                                   fvec, keysG, (int)ch_n);
        k_topk3<<<chp,1024,0,stream>>>(keysG, gdot, fvec, gbuf, invp, aliveIdx, KK1);
        k_wsum_c<<<chp*(KK1/RB),128,0,stream>>>(XAb, gbuf, fvec, invp, aliveIdx, KK1, ro, 1 + c*chp, 0);

        k_aggf2<<<chp*(KK1/8),256,0,stream>>>(XAb, s2rp, s2col, aliveIdx, fvec, nbase, AGGb, chp*KK1);
        k_sage_m<<<chp*(KK1/64),256,0,stream>>>(AGGb, XAb, aliveIdx, fvec, Wb1, bl_s + 3*128, XAb, chp*KK1,
            p_wrel + 1*DD, p_wroot + 1*DD, gate_w + 4*DD, tbuf, rootd, gdot);
        k_score2<<<(int)(ch_n/256),256,0,stream>>>(s2rp, s2col, nbase, tbuf, rootd, p_brel, 1, 0,
                                                   fvec, keysG, (int)ch_n);
        k_topk3<<<chp,1024,0,stream>>>(keysG, gdot, fvec, gbuf, invp, aliveIdx, KK2);
        k_wsum_c<<<chp*(KK2/RB),128,0,stream>>>(XAb, gbuf, fvec, invp, aliveIdx, KK2, ro, 1 + c*chp, 128);

        k_aggf2<<<chp*(KK2/8),256,0,stream>>>(XAb, s2rp, s2col, aliveIdx, fvec, nbase, AGGb, chp*KK2);
        k_sage_m<<<chp*(KK2/64),256,0,stream>>>(AGGb, XAb, aliveIdx, fvec, Wb2, bl_s + 4*128, XAb, chp*KK2,
            p_wrel + 2*DD, p_wroot + 2*DD, gate_w + 5*DD, tbuf, rootd, gdot);
        k_score2<<<(int)(ch_n/256),256,0,stream>>>(s2rp, s2col, nbase, tbuf, rootd, p_brel, 2, 0,
                                                   fvec, keysG, (int)ch_n);
        k_topk3<<<chp,1024,0,stream>>>(keysG, gdot, fvec, gbuf, invp, aliveIdx, KK3);
        k_wsum_c<<<chp*(KK3/RB),128,0,stream>>>(XAb, gbuf, fvec, invp, aliveIdx, KK3, ro, 1 + c*chp, 256);
    }

    // ---------- head ----------
    k_head<<<1,64,0,stream>>>(ro, lin_w, lin_b, m1w, m1b, m2w, m2b, m3w, m3b, out);
}